// Round 1
// baseline (527.199 us; speedup 1.0000x reference)
//
#include <hip/hip_runtime.h>
#include <hip/hip_bf16.h>

typedef __attribute__((ext_vector_type(8))) __bf16 bf16x8;
typedef __attribute__((ext_vector_type(4))) __bf16 bf16x4;
typedef __attribute__((ext_vector_type(4))) float  f32x4;

// ---------------------------------------------------------------------------
// Weight transpose + fp32->bf16 convert:  in [K][N] f32  ->  out [N][K] bf16
// ---------------------------------------------------------------------------
__global__ void transpose_convert(const float* __restrict__ in,
                                  __bf16* __restrict__ out, int K, int N) {
    __shared__ float t[32][33];
    const int nb = blockIdx.x * 32, kb = blockIdx.y * 32;
    const int tx = threadIdx.x & 31, ty = threadIdx.x >> 5;  // 256 thr: ty 0..7
#pragma unroll
    for (int i = 0; i < 32; i += 8)
        t[ty + i][tx] = in[(size_t)(kb + ty + i) * N + nb + tx];
    __syncthreads();
#pragma unroll
    for (int i = 0; i < 32; i += 8)
        out[(size_t)(nb + ty + i) * K + kb + tx] = (__bf16)t[tx][ty + i];
}

__global__ void concat3(const float* __restrict__ a, const float* __restrict__ b,
                        const float* __restrict__ c, float* __restrict__ o, int n) {
    int i = blockIdx.x * 256 + threadIdx.x;
    if (i < n) { o[i] = a[i]; o[n + i] = b[i]; o[2 * n + i] = c[i]; }
}

// ---------------------------------------------------------------------------
// LayerNorm over D=1024, one block per row, fp32 in -> bf16 out
// ---------------------------------------------------------------------------
__global__ __launch_bounds__(256) void ln_to_bf16(const float* __restrict__ x,
                                                  const float* __restrict__ g,
                                                  const float* __restrict__ bb,
                                                  __bf16* __restrict__ out) {
    const int row = blockIdx.x, t = threadIdx.x;
    const float4 v = ((const float4*)(x + (size_t)row * 1024))[t];
    float s  = v.x + v.y + v.z + v.w;
    float ss = v.x * v.x + v.y * v.y + v.z * v.z + v.w * v.w;
#pragma unroll
    for (int off = 32; off; off >>= 1) {
        s  += __shfl_down(s, off);
        ss += __shfl_down(ss, off);
    }
    __shared__ float ps[4], pss[4];
    if ((t & 63) == 0) { ps[t >> 6] = s; pss[t >> 6] = ss; }
    __syncthreads();
    s  = ps[0] + ps[1] + ps[2] + ps[3];
    ss = pss[0] + pss[1] + pss[2] + pss[3];
    const float mu   = s * (1.0f / 1024.0f);
    const float var  = ss * (1.0f / 1024.0f) - mu * mu;
    const float rinv = rsqrtf(var + 1e-5f);
    const float4 gv = ((const float4*)g)[t];
    const float4 bv = ((const float4*)bb)[t];
    bf16x4 o;
    o[0] = (__bf16)((v.x - mu) * rinv * gv.x + bv.x);
    o[1] = (__bf16)((v.y - mu) * rinv * gv.y + bv.y);
    o[2] = (__bf16)((v.z - mu) * rinv * gv.z + bv.z);
    o[3] = (__bf16)((v.w - mu) * rinv * gv.w + bv.w);
    *(bf16x4*)(out + (size_t)row * 1024 + 4 * t) = o;
}

// ---------------------------------------------------------------------------
// GEMM: C[M,N] = A[M,K](bf16) * BT[N,K](bf16)^T + bias
// MODE 0: bf16 out | MODE 1: bf16 relu out | MODE 2: f32 out + residual
// 128x128 tile, BK=32, 4 waves (each 64x64 = 4x4 frags of 16x16x32)
// ---------------------------------------------------------------------------
template <int MODE>
__global__ __launch_bounds__(256) void gemm_bt(const __bf16* __restrict__ A,
                                               const __bf16* __restrict__ BT,
                                               const float* __restrict__ bias,
                                               const float* __restrict__ resid,
                                               void* __restrict__ outp,
                                               int M, int N, int K) {
    __shared__ __align__(16) __bf16 As[128][40];
    __shared__ __align__(16) __bf16 Bs[128][40];
    const int bm = blockIdx.y * 128, bn = blockIdx.x * 128;
    const int tid = threadIdx.x, l = tid & 63, wid = tid >> 6;
    const int wr = (wid >> 1) * 64, wc = (wid & 1) * 64;
    const int lg = l >> 4, lm = l & 15;

    f32x4 acc[4][4];
#pragma unroll
    for (int m = 0; m < 4; ++m)
#pragma unroll
        for (int n = 0; n < 4; ++n) acc[m][n] = f32x4{0.f, 0.f, 0.f, 0.f};

    const int arow = tid >> 2, ac = (tid & 3) * 8;  // staging: 16B per thread x2 rows
    for (int k0 = 0; k0 < K; k0 += 32) {
        *(uint4*)&As[arow][ac]      = *(const uint4*)&A [(size_t)(bm + arow)      * K + k0 + ac];
        *(uint4*)&As[arow + 64][ac] = *(const uint4*)&A [(size_t)(bm + arow + 64) * K + k0 + ac];
        *(uint4*)&Bs[arow][ac]      = *(const uint4*)&BT[(size_t)(bn + arow)      * K + k0 + ac];
        *(uint4*)&Bs[arow + 64][ac] = *(const uint4*)&BT[(size_t)(bn + arow + 64) * K + k0 + ac];
        __syncthreads();
        bf16x8 af[4], bfr[4];
#pragma unroll
        for (int m = 0; m < 4; ++m) af[m]  = *(const bf16x8*)&As[wr + m * 16 + lm][lg * 8];
#pragma unroll
        for (int n = 0; n < 4; ++n) bfr[n] = *(const bf16x8*)&Bs[wc + n * 16 + lm][lg * 8];
#pragma unroll
        for (int m = 0; m < 4; ++m)
#pragma unroll
            for (int n = 0; n < 4; ++n)
                acc[m][n] = __builtin_amdgcn_mfma_f32_16x16x32_bf16(af[m], bfr[n], acc[m][n], 0, 0, 0);
        __syncthreads();
    }
    // epilogue: C/D layout col=lane&15, row=(lane>>4)*4+reg
#pragma unroll
    for (int m = 0; m < 4; ++m) {
        const int row = bm + wr + m * 16 + lg * 4;
#pragma unroll
        for (int n = 0; n < 4; ++n) {
            const int col = bn + wc + n * 16 + lm;
            const float bv = bias[col];
#pragma unroll
            for (int r = 0; r < 4; ++r) {
                const float v = acc[m][n][r] + bv;
                const size_t idx = (size_t)(row + r) * N + col;
                if (MODE == 0)      ((__bf16*)outp)[idx] = (__bf16)v;
                else if (MODE == 1) ((__bf16*)outp)[idx] = (__bf16)fmaxf(v, 0.f);
                else                ((float*)outp)[idx]  = resid[idx] + v;
            }
        }
    }
}

// ---------------------------------------------------------------------------
// Flash attention fwd. qkv: [B*S][3072] bf16 (q|k|v, head-major inside each).
// Grid (qt=16, h=16, b=8); 256 thr = 4 waves; wave w owns 16 q rows.
// D_K=64, KV tiles of 64. Online softmax. Out ctx [B*S][1024] bf16.
// ---------------------------------------------------------------------------
__global__ __launch_bounds__(256) void attn_kernel(const __bf16* __restrict__ qkv,
                                                   const int* __restrict__ mask,
                                                   __bf16* __restrict__ ctx) {
    const int qt = blockIdx.x, h = blockIdx.y, b = blockIdx.z;
    const int tid = threadIdx.x, w = tid >> 6, l = tid & 63;
    const int lg = l >> 4, lm = l & 15;

    __shared__ __align__(16) __bf16 Ks[64][72];
    __shared__ __align__(16) __bf16 Vt[64][72];
    __shared__ __align__(16) __bf16 Ps[4][16][72];
    __shared__ int smask[64];

    // Q fragments held in registers (A-operand: row=l%16, k contiguous per lane)
    const int qrow = qt * 64 + w * 16 + lm;
    const __bf16* qp = qkv + (size_t)(b * 1024 + qrow) * 3072 + h * 64 + lg * 8;
    bf16x8 aq[2];
    aq[0] = *(const bf16x8*)qp;
    aq[1] = *(const bf16x8*)(qp + 32);

    float mrun[4] = {-1e30f, -1e30f, -1e30f, -1e30f};
    float lsum[4] = {0.f, 0.f, 0.f, 0.f};
    f32x4 oacc[4];
#pragma unroll
    for (int n = 0; n < 4; ++n) oacc[n] = f32x4{0.f, 0.f, 0.f, 0.f};

    for (int kt = 0; kt < 16; ++kt) {
#pragma unroll
        for (int it = 0; it < 2; ++it) {
            const int c = tid + it * 256;
            const int r = c >> 3, kc = (c & 7) * 8;
            const __bf16* kp = qkv + (size_t)(b * 1024 + kt * 64 + r) * 3072 + 1024 + h * 64 + kc;
            *(uint4*)&Ks[r][kc] = *(const uint4*)kp;
            union { uint4 u; __bf16 e[8]; } vv;
            vv.u = *(const uint4*)(kp + 1024);
#pragma unroll
            for (int j = 0; j < 8; ++j) Vt[kc + j][r] = vv.e[j];  // V transposed
        }
        if (tid < 64) smask[tid] = mask[b * 1024 + kt * 64 + tid];
        __syncthreads();

        // S = Q K^T  (per wave: 16 q-rows x 64 keys)
        f32x4 sacc[4];
#pragma unroll
        for (int n = 0; n < 4; ++n) {
            sacc[n] = f32x4{0.f, 0.f, 0.f, 0.f};
#pragma unroll
            for (int kk = 0; kk < 2; ++kk) {
                bf16x8 bk = *(const bf16x8*)&Ks[n * 16 + lm][lg * 8 + kk * 32];
                sacc[n] = __builtin_amdgcn_mfma_f32_16x16x32_bf16(aq[kk], bk, sacc[n], 0, 0, 0);
            }
        }
        // online softmax: lane holds S[q=lg*4+r][key=n*16+lm]
        float p[4][4], tmax[4] = {-1e30f, -1e30f, -1e30f, -1e30f};
#pragma unroll
        for (int n = 0; n < 4; ++n) {
            const int mk = smask[n * 16 + lm];
#pragma unroll
            for (int r = 0; r < 4; ++r) {
                float sv = sacc[n][r] * 0.125f;
                if (mk == 0) sv = -1e9f;
                p[n][r] = sv;
                tmax[r] = fmaxf(tmax[r], sv);
            }
        }
#pragma unroll
        for (int off = 1; off < 16; off <<= 1)
#pragma unroll
            for (int r = 0; r < 4; ++r) tmax[r] = fmaxf(tmax[r], __shfl_xor(tmax[r], off));
        float scale[4];
#pragma unroll
        for (int r = 0; r < 4; ++r) {
            const float mnew = fmaxf(mrun[r], tmax[r]);
            scale[r] = __expf(mrun[r] - mnew);
            mrun[r] = mnew;
        }
#pragma unroll
        for (int n = 0; n < 4; ++n)
#pragma unroll
            for (int r = 0; r < 4; ++r) p[n][r] = __expf(p[n][r] - mrun[r]);
        float rsum[4];
#pragma unroll
        for (int r = 0; r < 4; ++r) rsum[r] = p[0][r] + p[1][r] + p[2][r] + p[3][r];
#pragma unroll
        for (int off = 1; off < 16; off <<= 1)
#pragma unroll
            for (int r = 0; r < 4; ++r) rsum[r] += __shfl_xor(rsum[r], off);
#pragma unroll
        for (int r = 0; r < 4; ++r) lsum[r] = lsum[r] * scale[r] + rsum[r];
#pragma unroll
        for (int n = 0; n < 4; ++n)
#pragma unroll
            for (int r = 0; r < 4; ++r) oacc[n][r] *= scale[r];
        // P -> LDS (per-wave region), reread in A-fragment layout
#pragma unroll
        for (int n = 0; n < 4; ++n)
#pragma unroll
            for (int r = 0; r < 4; ++r) Ps[w][lg * 4 + r][n * 16 + lm] = (__bf16)p[n][r];
        bf16x8 ap[2];
        ap[0] = *(const bf16x8*)&Ps[w][lm][lg * 8];
        ap[1] = *(const bf16x8*)&Ps[w][lm][lg * 8 + 32];
#pragma unroll
        for (int n = 0; n < 4; ++n)
#pragma unroll
            for (int kk = 0; kk < 2; ++kk) {
                bf16x8 bv = *(const bf16x8*)&Vt[n * 16 + lm][lg * 8 + kk * 32];
                oacc[n] = __builtin_amdgcn_mfma_f32_16x16x32_bf16(ap[kk], bv, oacc[n], 0, 0, 0);
            }
        __syncthreads();
    }
    // epilogue
#pragma unroll
    for (int n = 0; n < 4; ++n)
#pragma unroll
        for (int r = 0; r < 4; ++r) {
            const float val = oacc[n][r] / lsum[r];
            const int row = qt * 64 + w * 16 + lg * 4 + r;
            ctx[(size_t)(b * 1024 + row) * 1024 + h * 64 + n * 16 + lm] = (__bf16)val;
        }
}

// ---------------------------------------------------------------------------
extern "C" void kernel_launch(void* const* d_in, const int* in_sizes, int n_in,
                              void* d_out, int out_size, void* d_ws, size_t ws_size,
                              hipStream_t stream) {
    const float* x    = (const float*)d_in[0];
    const int*   mask = (const int*)d_in[1];
    const float* wq   = (const float*)d_in[2];
    const float* bq   = (const float*)d_in[3];
    const float* wk   = (const float*)d_in[4];
    const float* bk   = (const float*)d_in[5];
    const float* wv   = (const float*)d_in[6];
    const float* bv   = (const float*)d_in[7];
    const float* wo   = (const float*)d_in[8];
    const float* bo   = (const float*)d_in[9];
    const float* w1   = (const float*)d_in[10];
    const float* b1   = (const float*)d_in[11];
    const float* w2   = (const float*)d_in[12];
    const float* b2   = (const float*)d_in[13];
    const float* ln1g = (const float*)d_in[14];
    const float* ln1b = (const float*)d_in[15];
    const float* ln2g = (const float*)d_in[16];
    const float* ln2b = (const float*)d_in[17];
    float* out = (float*)d_out;
    char* ws = (char*)d_ws;

    // workspace layout (bytes)
    __bf16* wqkvT = (__bf16*)(ws + 0);          //  [3072][1024]  6 MB
    __bf16* woT   = (__bf16*)(ws + 6291456);    //  [1024][1024]  2 MB
    __bf16* w1T   = (__bf16*)(ws + 8388608);    //  [4096][1024]  8 MB
    __bf16* w2T   = (__bf16*)(ws + 16777216);   //  [1024][4096]  8 MB
    float*  bqkv  = (float*)(ws + 25165824);    //  [3072]
    __bf16* hb    = (__bf16*)(ws + 25178112);   //  [8192][1024] 16 MB (h, then h2)
    __bf16* qkvb  = (__bf16*)(ws + 41955328);   //  [8192][3072] 48 MB
    __bf16* ctxb  = (__bf16*)(ws + 92286976);   //  [8192][1024] 16 MB
    __bf16* ff1b  = qkvb;                       //  [8192][4096] 64 MB (reuses qkv+ctx)

    // weights -> bf16, transposed to [N][K]
    transpose_convert<<<dim3(32, 32),  256, 0, stream>>>(wq, wqkvT,               1024, 1024);
    transpose_convert<<<dim3(32, 32),  256, 0, stream>>>(wk, wqkvT + 1024 * 1024, 1024, 1024);
    transpose_convert<<<dim3(32, 32),  256, 0, stream>>>(wv, wqkvT + 2048 * 1024, 1024, 1024);
    transpose_convert<<<dim3(32, 32),  256, 0, stream>>>(wo, woT,                 1024, 1024);
    transpose_convert<<<dim3(128, 32), 256, 0, stream>>>(w1, w1T,                 1024, 4096);
    transpose_convert<<<dim3(32, 128), 256, 0, stream>>>(w2, w2T,                 4096, 1024);
    concat3<<<4, 256, 0, stream>>>(bq, bk, bv, bqkv, 1024);

    // LN1 -> h (bf16)
    ln_to_bf16<<<8192, 256, 0, stream>>>(x, ln1g, ln1b, hb);
    // fused QKV GEMM: [8192,1024] x [1024,3072]
    gemm_bt<0><<<dim3(24, 64), 256, 0, stream>>>(hb, wqkvT, bqkv, nullptr, qkvb, 8192, 3072, 1024);
    // attention
    attn_kernel<<<dim3(16, 16, 8), 256, 0, stream>>>(qkvb, mask, ctxb);
    // output proj + residual -> d_out (fp32)
    gemm_bt<2><<<dim3(8, 64), 256, 0, stream>>>(ctxb, woT, bo, x, out, 8192, 1024, 1024);
    // LN2 -> h2 (bf16, reuse hb)
    ln_to_bf16<<<8192, 256, 0, stream>>>(out, ln2g, ln2b, hb);
    // FFN
    gemm_bt<1><<<dim3(32, 64), 256, 0, stream>>>(hb, w1T, b1, nullptr, ff1b, 8192, 4096, 1024);
    gemm_bt<2><<<dim3(8, 64), 256, 0, stream>>>(ff1b, w2T, b2, out, out, 8192, 1024, 4096);
}

// Round 2
// 510.185 us; speedup vs baseline: 1.0333x; 1.0333x over previous
//
#include <hip/hip_runtime.h>
#include <hip/hip_bf16.h>

typedef __attribute__((ext_vector_type(8))) __bf16 bf16x8;
typedef __attribute__((ext_vector_type(4))) __bf16 bf16x4;
typedef __attribute__((ext_vector_type(4))) float  f32x4;

__device__ __forceinline__ void gload_lds16(const __bf16* g, __bf16* l) {
    __builtin_amdgcn_global_load_lds(
        (const __attribute__((address_space(1))) void*)g,
        (__attribute__((address_space(3))) void*)l, 16, 0, 0);
}

// ---------------------------------------------------------------------------
// Weight transpose + fp32->bf16 convert:  in [K][N] f32  ->  out [N][K] bf16
// ---------------------------------------------------------------------------
__global__ void transpose_convert(const float* __restrict__ in,
                                  __bf16* __restrict__ out, int K, int N) {
    __shared__ float t[32][33];
    const int nb = blockIdx.x * 32, kb = blockIdx.y * 32;
    const int tx = threadIdx.x & 31, ty = threadIdx.x >> 5;  // 256 thr: ty 0..7
#pragma unroll
    for (int i = 0; i < 32; i += 8)
        t[ty + i][tx] = in[(size_t)(kb + ty + i) * N + nb + tx];
    __syncthreads();
#pragma unroll
    for (int i = 0; i < 32; i += 8)
        out[(size_t)(nb + ty + i) * K + kb + tx] = (__bf16)t[tx][ty + i];
}

__global__ void concat2(const float* __restrict__ a, const float* __restrict__ b,
                        float* __restrict__ o, int n) {
    int i = blockIdx.x * 256 + threadIdx.x;
    if (i < n) { o[i] = a[i]; o[n + i] = b[i]; }
}

// ---------------------------------------------------------------------------
// LayerNorm over D=1024, one block per row, fp32 in -> bf16 out
// ---------------------------------------------------------------------------
__global__ __launch_bounds__(256) void ln_to_bf16(const float* __restrict__ x,
                                                  const float* __restrict__ g,
                                                  const float* __restrict__ bb,
                                                  __bf16* __restrict__ out) {
    const int row = blockIdx.x, t = threadIdx.x;
    const float4 v = ((const float4*)(x + (size_t)row * 1024))[t];
    float s  = v.x + v.y + v.z + v.w;
    float ss = v.x * v.x + v.y * v.y + v.z * v.z + v.w * v.w;
#pragma unroll
    for (int off = 32; off; off >>= 1) {
        s  += __shfl_down(s, off);
        ss += __shfl_down(ss, off);
    }
    __shared__ float ps[4], pss[4];
    if ((t & 63) == 0) { ps[t >> 6] = s; pss[t >> 6] = ss; }
    __syncthreads();
    s  = ps[0] + ps[1] + ps[2] + ps[3];
    ss = pss[0] + pss[1] + pss[2] + pss[3];
    const float mu   = s * (1.0f / 1024.0f);
    const float var  = ss * (1.0f / 1024.0f) - mu * mu;
    const float rinv = rsqrtf(var + 1e-5f);
    const float4 gv = ((const float4*)g)[t];
    const float4 bv = ((const float4*)bb)[t];
    bf16x4 o;
    o[0] = (__bf16)((v.x - mu) * rinv * gv.x + bv.x);
    o[1] = (__bf16)((v.y - mu) * rinv * gv.y + bv.y);
    o[2] = (__bf16)((v.z - mu) * rinv * gv.z + bv.z);
    o[3] = (__bf16)((v.w - mu) * rinv * gv.w + bv.w);
    *(bf16x4*)(out + (size_t)row * 1024 + 4 * t) = o;
}

// ---------------------------------------------------------------------------
// GEMM: C[M,N] = A[M,K](bf16) * BT[N,K](bf16)^T + bias. m97 structure:
// 128x128 tile, BK=32, linear LDS, global_load_lds width=16, 2 barriers/step.
// MODE 0: bf16 out | MODE 1: bf16 relu | MODE 2: f32 + residual
// MODE 3: bf16 transposed-V out: vT[(row>>10)*1024 + col][row&1023]
// ---------------------------------------------------------------------------
template <int MODE>
__global__ __launch_bounds__(256) void gemm_bt(const __bf16* __restrict__ A,
                                               const __bf16* __restrict__ BT,
                                               const float* __restrict__ bias,
                                               const float* __restrict__ resid,
                                               void* __restrict__ outp,
                                               int M, int N, int K) {
    __shared__ __align__(16) __bf16 As[128][32];   // linear, no pad (gload_lds)
    __shared__ __align__(16) __bf16 Bs[128][32];
    const int bm = blockIdx.y * 128, bn = blockIdx.x * 128;
    const int tid = threadIdx.x, l = tid & 63, wid = tid >> 6;
    const int wr = (wid >> 1) * 64, wc = (wid & 1) * 64;
    const int lg = l >> 4, lm = l & 15;

    // staging: wave wid fills rows [wid*32, wid*32+32); lane covers 16B
    const int srow = wid * 32 + (l >> 2);
    const int scol = (l & 3) * 8;
    const __bf16* Ag = A  + (size_t)(bm + srow) * K + scol;
    const __bf16* Bg = BT + (size_t)(bn + srow) * K + scol;
    __bf16* AsD = &As[wid * 32][0];
    __bf16* BsD = &Bs[wid * 32][0];

    f32x4 acc[4][4];
#pragma unroll
    for (int m = 0; m < 4; ++m)
#pragma unroll
        for (int n = 0; n < 4; ++n) acc[m][n] = f32x4{0.f, 0.f, 0.f, 0.f};

    for (int k0 = 0; k0 < K; k0 += 32) {
        gload_lds16(Ag + k0,                   AsD);
        gload_lds16(Ag + (size_t)16 * K + k0,  AsD + 512);
        gload_lds16(Bg + k0,                   BsD);
        gload_lds16(Bg + (size_t)16 * K + k0,  BsD + 512);
        __syncthreads();
        bf16x8 af[4], bfr[4];
#pragma unroll
        for (int m = 0; m < 4; ++m) af[m]  = *(const bf16x8*)&As[wr + m * 16 + lm][lg * 8];
#pragma unroll
        for (int n = 0; n < 4; ++n) bfr[n] = *(const bf16x8*)&Bs[wc + n * 16 + lm][lg * 8];
#pragma unroll
        for (int m = 0; m < 4; ++m)
#pragma unroll
            for (int n = 0; n < 4; ++n)
                acc[m][n] = __builtin_amdgcn_mfma_f32_16x16x32_bf16(af[m], bfr[n], acc[m][n], 0, 0, 0);
        __syncthreads();
    }
    // epilogue: C/D layout col=lane&15, row=(lane>>4)*4+reg
#pragma unroll
    for (int m = 0; m < 4; ++m) {
        const int row = bm + wr + m * 16 + lg * 4;
#pragma unroll
        for (int n = 0; n < 4; ++n) {
            const int col = bn + wc + n * 16 + lm;
            const float bv = bias[col];
            if (MODE == 3) {
                bf16x4 o;
#pragma unroll
                for (int r = 0; r < 4; ++r) o[r] = (__bf16)(acc[m][n][r] + bv);
                *(bf16x4*)((__bf16*)outp +
                           (size_t)((row >> 10) * 1024 + col) * 1024 + (row & 1023)) = o;
            } else {
#pragma unroll
                for (int r = 0; r < 4; ++r) {
                    const float v = acc[m][n][r] + bv;
                    const size_t idx = (size_t)(row + r) * N + col;
                    if (MODE == 0)      ((__bf16*)outp)[idx] = (__bf16)v;
                    else if (MODE == 1) ((__bf16*)outp)[idx] = (__bf16)fmaxf(v, 0.f);
                    else                ((float*)outp)[idx]  = resid[idx] + v;
                }
            }
        }
    }
}

// ---------------------------------------------------------------------------
// Flash attention fwd. qk: [B*S][2048] bf16 (q|k per head). vT: [B*H*64][S].
// Grid (qt=16, h=16, b=8); 256 thr = 4 waves; wave w owns 16 q rows.
// ---------------------------------------------------------------------------
__global__ __launch_bounds__(256) void attn_kernel(const __bf16* __restrict__ qk,
                                                   const __bf16* __restrict__ vT,
                                                   const int* __restrict__ mask,
                                                   __bf16* __restrict__ ctx) {
    const int qt = blockIdx.x, h = blockIdx.y, b = blockIdx.z;
    const int tid = threadIdx.x, w = tid >> 6, l = tid & 63;
    const int lg = l >> 4, lm = l & 15;

    __shared__ __align__(16) __bf16 Ks[64][76];   // keys x d_k, stride 152B (6 mod 32 dw)
    __shared__ __align__(16) __bf16 Vt[64][76];   // d_k  x keys
    __shared__ __align__(16) __bf16 Ps[4][16][76];
    __shared__ int smask[64];

    const int qrow = qt * 64 + w * 16 + lm;
    const __bf16* qp = qk + (size_t)(b * 1024 + qrow) * 2048 + h * 64 + lg * 8;
    bf16x8 aq[2];
    aq[0] = *(const bf16x8*)qp;
    aq[1] = *(const bf16x8*)(qp + 32);

    float mrun[4] = {-1e30f, -1e30f, -1e30f, -1e30f};
    float lsum[4] = {0.f, 0.f, 0.f, 0.f};
    f32x4 oacc[4];
#pragma unroll
    for (int n = 0; n < 4; ++n) oacc[n] = f32x4{0.f, 0.f, 0.f, 0.f};

    for (int kt = 0; kt < 16; ++kt) {
#pragma unroll
        for (int it = 0; it < 2; ++it) {
            const int c = tid + it * 256;
            const int r = c >> 3, cc = (c & 7) * 8;
            *(uint4*)&Ks[r][cc] =
                *(const uint4*)&qk[(size_t)(b * 1024 + kt * 64 + r) * 2048 + 1024 + h * 64 + cc];
            *(uint4*)&Vt[r][cc] =
                *(const uint4*)&vT[(size_t)(b * 1024 + h * 64 + r) * 1024 + kt * 64 + cc];
        }
        if (tid < 64) smask[tid] = mask[b * 1024 + kt * 64 + tid];
        __syncthreads();

        // S = Q K^T  (per wave: 16 q-rows x 64 keys)
        f32x4 sacc[4];
#pragma unroll
        for (int n = 0; n < 4; ++n) {
            sacc[n] = f32x4{0.f, 0.f, 0.f, 0.f};
#pragma unroll
            for (int kk = 0; kk < 2; ++kk) {
                bf16x8 bk = *(const bf16x8*)&Ks[n * 16 + lm][lg * 8 + kk * 32];
                sacc[n] = __builtin_amdgcn_mfma_f32_16x16x32_bf16(aq[kk], bk, sacc[n], 0, 0, 0);
            }
        }
        // online softmax: lane holds S[q=lg*4+r][key=n*16+lm]
        float p[4][4], tmax[4] = {-1e30f, -1e30f, -1e30f, -1e30f};
#pragma unroll
        for (int n = 0; n < 4; ++n) {
            const int mk = smask[n * 16 + lm];
#pragma unroll
            for (int r = 0; r < 4; ++r) {
                float sv = sacc[n][r] * 0.125f;
                if (mk == 0) sv = -1e9f;
                p[n][r] = sv;
                tmax[r] = fmaxf(tmax[r], sv);
            }
        }
#pragma unroll
        for (int off = 1; off < 16; off <<= 1)
#pragma unroll
            for (int r = 0; r < 4; ++r) tmax[r] = fmaxf(tmax[r], __shfl_xor(tmax[r], off));
        float scale[4];
#pragma unroll
        for (int r = 0; r < 4; ++r) {
            const float mnew = fmaxf(mrun[r], tmax[r]);
            scale[r] = __expf(mrun[r] - mnew);
            mrun[r] = mnew;
        }
#pragma unroll
        for (int n = 0; n < 4; ++n)
#pragma unroll
            for (int r = 0; r < 4; ++r) p[n][r] = __expf(p[n][r] - mrun[r]);
        float rsum[4];
#pragma unroll
        for (int r = 0; r < 4; ++r) rsum[r] = p[0][r] + p[1][r] + p[2][r] + p[3][r];
#pragma unroll
        for (int off = 1; off < 16; off <<= 1)
#pragma unroll
            for (int r = 0; r < 4; ++r) rsum[r] += __shfl_xor(rsum[r], off);
#pragma unroll
        for (int r = 0; r < 4; ++r) lsum[r] = lsum[r] * scale[r] + rsum[r];
#pragma unroll
        for (int n = 0; n < 4; ++n)
#pragma unroll
            for (int r = 0; r < 4; ++r) oacc[n][r] *= scale[r];
        // P -> per-wave LDS, reread in A-fragment layout
#pragma unroll
        for (int n = 0; n < 4; ++n)
#pragma unroll
            for (int r = 0; r < 4; ++r) Ps[w][lg * 4 + r][n * 16 + lm] = (__bf16)p[n][r];
        bf16x8 ap[2];
        ap[0] = *(const bf16x8*)&Ps[w][lm][lg * 8];
        ap[1] = *(const bf16x8*)&Ps[w][lm][lg * 8 + 32];
#pragma unroll
        for (int n = 0; n < 4; ++n)
#pragma unroll
            for (int kk = 0; kk < 2; ++kk) {
                bf16x8 bv = *(const bf16x8*)&Vt[n * 16 + lm][lg * 8 + kk * 32];
                oacc[n] = __builtin_amdgcn_mfma_f32_16x16x32_bf16(ap[kk], bv, oacc[n], 0, 0, 0);
            }
        __syncthreads();
    }
    // epilogue
#pragma unroll
    for (int n = 0; n < 4; ++n)
#pragma unroll
        for (int r = 0; r < 4; ++r) {
            const float val = oacc[n][r] / lsum[r];
            const int row = qt * 64 + w * 16 + lg * 4 + r;
            ctx[(size_t)(b * 1024 + row) * 1024 + h * 64 + n * 16 + lm] = (__bf16)val;
        }
}

// ---------------------------------------------------------------------------
extern "C" void kernel_launch(void* const* d_in, const int* in_sizes, int n_in,
                              void* d_out, int out_size, void* d_ws, size_t ws_size,
                              hipStream_t stream) {
    const float* x    = (const float*)d_in[0];
    const int*   mask = (const int*)d_in[1];
    const float* wq   = (const float*)d_in[2];
    const float* bq   = (const float*)d_in[3];
    const float* wk   = (const float*)d_in[4];
    const float* bk   = (const float*)d_in[5];
    const float* wv   = (const float*)d_in[6];
    const float* bv   = (const float*)d_in[7];
    const float* wo   = (const float*)d_in[8];
    const float* bo   = (const float*)d_in[9];
    const float* w1   = (const float*)d_in[10];
    const float* b1   = (const float*)d_in[11];
    const float* w2   = (const float*)d_in[12];
    const float* b2   = (const float*)d_in[13];
    const float* ln1g = (const float*)d_in[14];
    const float* ln1b = (const float*)d_in[15];
    const float* ln2g = (const float*)d_in[16];
    const float* ln2b = (const float*)d_in[17];
    float* out = (float*)d_out;
    char* ws = (char*)d_ws;

    // workspace layout (bytes)
    __bf16* wqkT = (__bf16*)(ws + 0);           // [2048][1024]  4 MB
    __bf16* wvT  = (__bf16*)(ws + 4194304);     // [1024][1024]  2 MB
    __bf16* woT  = (__bf16*)(ws + 6291456);     // [1024][1024]  2 MB
    __bf16* w1T  = (__bf16*)(ws + 8388608);     // [4096][1024]  8 MB
    __bf16* w2T  = (__bf16*)(ws + 16777216);    // [1024][4096]  8 MB
    float*  bqk  = (float*)(ws + 25165824);     // [2048]
    __bf16* hb   = (__bf16*)(ws + 25182208);    // [8192][1024] 16 MB (LN1 out, LN2 out)
    __bf16* ctxb = (__bf16*)(ws + 41959424);    // [8192][1024] 16 MB
    __bf16* qkb  = (__bf16*)(ws + 58736640);    // [8192][2048] 32 MB
    __bf16* vTb  = (__bf16*)(ws + 92291072);    // [8*16*64][1024] 16 MB, end 109068288
    __bf16* ff1b = ctxb;                        // [8192][4096] 64 MB overlays ctx+qk+vT

    // weights -> bf16, transposed to [N][K]
    transpose_convert<<<dim3(32, 32),  256, 0, stream>>>(wq, wqkT,               1024, 1024);
    transpose_convert<<<dim3(32, 32),  256, 0, stream>>>(wk, wqkT + 1024 * 1024, 1024, 1024);
    transpose_convert<<<dim3(32, 32),  256, 0, stream>>>(wv, wvT,                1024, 1024);
    transpose_convert<<<dim3(32, 32),  256, 0, stream>>>(wo, woT,                1024, 1024);
    transpose_convert<<<dim3(128, 32), 256, 0, stream>>>(w1, w1T,                1024, 4096);
    transpose_convert<<<dim3(32, 128), 256, 0, stream>>>(w2, w2T,                4096, 1024);
    concat2<<<4, 256, 0, stream>>>(bq, bk, bqk, 1024);

    // LN1 -> hb
    ln_to_bf16<<<8192, 256, 0, stream>>>(x, ln1g, ln1b, hb);
    // QK GEMM: [8192,1024] x [1024,2048] -> qkb
    gemm_bt<0><<<dim3(16, 64), 256, 0, stream>>>(hb, wqkT, bqk, nullptr, qkb, 8192, 2048, 1024);
    // V GEMM with transposed epilogue -> vTb
    gemm_bt<3><<<dim3(8, 64), 256, 0, stream>>>(hb, wvT, bv, nullptr, vTb, 8192, 1024, 1024);
    // attention
    attn_kernel<<<dim3(16, 16, 8), 256, 0, stream>>>(qkb, vTb, mask, ctxb);
    // output proj + residual -> d_out (fp32)
    gemm_bt<2><<<dim3(8, 64), 256, 0, stream>>>(ctxb, woT, bo, x, out, 8192, 1024, 1024);
    // LN2 -> hb
    ln_to_bf16<<<8192, 256, 0, stream>>>(out, ln2g, ln2b, hb);
    // FFN
    gemm_bt<1><<<dim3(32, 64), 256, 0, stream>>>(hb, w1T, b1, nullptr, ff1b, 8192, 4096, 1024);
    gemm_bt<2><<<dim3(8, 64), 256, 0, stream>>>(ff1b, w2T, b2, out, out, 8192, 1024, 4096);
}

// Round 3
// 477.813 us; speedup vs baseline: 1.1034x; 1.0678x over previous
//
#include <hip/hip_runtime.h>
#include <hip/hip_bf16.h>

typedef __attribute__((ext_vector_type(8))) __bf16 bf16x8;
typedef __attribute__((ext_vector_type(4))) __bf16 bf16x4;
typedef __attribute__((ext_vector_type(4))) float  f32x4;

__device__ __forceinline__ void gload_lds16(const __bf16* g, __bf16* l) {
    __builtin_amdgcn_global_load_lds(
        (const __attribute__((address_space(1))) void*)g,
        (__attribute__((address_space(3))) void*)l, 16, 0, 0);
}

// ---------------------------------------------------------------------------
// Weight transpose + fp32->bf16 convert:  in [K][N] f32  ->  out [N][K] bf16
// ---------------------------------------------------------------------------
__global__ void transpose_convert(const float* __restrict__ in,
                                  __bf16* __restrict__ out, int K, int N) {
    __shared__ float t[32][33];
    const int nb = blockIdx.x * 32, kb = blockIdx.y * 32;
    const int tx = threadIdx.x & 31, ty = threadIdx.x >> 5;
#pragma unroll
    for (int i = 0; i < 32; i += 8)
        t[ty + i][tx] = in[(size_t)(kb + ty + i) * N + nb + tx];
    __syncthreads();
#pragma unroll
    for (int i = 0; i < 32; i += 8)
        out[(size_t)(nb + ty + i) * K + kb + tx] = (__bf16)t[tx][ty + i];
}

__global__ void concat3(const float* __restrict__ a, const float* __restrict__ b,
                        const float* __restrict__ c, float* __restrict__ o, int n) {
    int i = blockIdx.x * 256 + threadIdx.x;
    if (i < n) { o[i] = a[i]; o[n + i] = b[i]; o[2 * n + i] = c[i]; }
}

// ---------------------------------------------------------------------------
// LayerNorm over D=1024, one block per row, fp32 in -> bf16 out
// ---------------------------------------------------------------------------
__global__ __launch_bounds__(256) void ln_to_bf16(const float* __restrict__ x,
                                                  const float* __restrict__ g,
                                                  const float* __restrict__ bb,
                                                  __bf16* __restrict__ out) {
    const int row = blockIdx.x, t = threadIdx.x;
    const float4 v = ((const float4*)(x + (size_t)row * 1024))[t];
    float s  = v.x + v.y + v.z + v.w;
    float ss = v.x * v.x + v.y * v.y + v.z * v.z + v.w * v.w;
#pragma unroll
    for (int off = 32; off; off >>= 1) {
        s  += __shfl_down(s, off);
        ss += __shfl_down(ss, off);
    }
    __shared__ float ps[4], pss[4];
    if ((t & 63) == 0) { ps[t >> 6] = s; pss[t >> 6] = ss; }
    __syncthreads();
    s  = ps[0] + ps[1] + ps[2] + ps[3];
    ss = pss[0] + pss[1] + pss[2] + pss[3];
    const float mu   = s * (1.0f / 1024.0f);
    const float var  = ss * (1.0f / 1024.0f) - mu * mu;
    const float rinv = rsqrtf(var + 1e-5f);
    const float4 gv = ((const float4*)g)[t];
    const float4 bv = ((const float4*)bb)[t];
    bf16x4 o;
    o[0] = (__bf16)((v.x - mu) * rinv * gv.x + bv.x);
    o[1] = (__bf16)((v.y - mu) * rinv * gv.y + bv.y);
    o[2] = (__bf16)((v.z - mu) * rinv * gv.z + bv.z);
    o[3] = (__bf16)((v.w - mu) * rinv * gv.w + bv.w);
    *(bf16x4*)(out + (size_t)row * 1024 + 4 * t) = o;
}

// ---------------------------------------------------------------------------
// 256x256 8-phase GEMM (HK-style schedule, plain HIP). C = A * BT^T + bias.
// 8 waves (2M x 4N), per-wave 128x64. BK=64 as 2 sub-tiles of 32; 4 LDS
// sub-buffers x 32KB ring; counted vmcnt(8); raw s_barrier; setprio; swizzle.
// MODE 1: relu bf16 out (ldc=N) | MODE 4: qkv out (cols<2048 -> bf16 ldc=2048,
// cols>=2048 -> transposed V into vTout)
// ---------------------------------------------------------------------------
template <int MODE>
__global__ __launch_bounds__(512, 2) void gemm256(const __bf16* __restrict__ A,
                                                  const __bf16* __restrict__ BT,
                                                  const float* __restrict__ bias,
                                                  __bf16* __restrict__ outp,
                                                  __bf16* __restrict__ vTout,
                                                  int M, int N, int K, int NMB) {
    __shared__ __align__(16) __bf16 lds[65536];   // 4 sub-buffers x 16384 elems
    const int nwg = gridDim.x;
    const int bid = blockIdx.x;
    const int wgid = (bid & 7) * (nwg >> 3) + (bid >> 3);   // XCD-contiguous
    const int bm = (wgid % NMB) * 256, bn = (wgid / NMB) * 256;
    const int tid = threadIdx.x, l = tid & 63, w = tid >> 6;
    const int wm = (w >> 2) * 128, wn = (w & 3) * 64;
    const int lg = l >> 4, lm = l & 15;
    const int NT = K >> 6;

    // --- staging setup: linear LDS dest, pre-swizzled global source --------
    // swz(off) = off ^ ((off>>7)&7)<<4  (involution; bits4-6 ^= bits7-9)
    const __bf16* gsrc[4];
    int ldst[4];
#pragma unroll
    for (int j = 0; j < 4; ++j) {
        const unsigned X = (unsigned)(((j & 1) << 13) + (w << 10) + l * 16);
        const unsigned L = X ^ (((X >> 7) & 7u) << 4);
        const int row = L >> 6, col = (L & 63) >> 1;
        gsrc[j] = (j < 2 ? A + (size_t)(bm + row) * K : BT + (size_t)(bn + row) * K) + col;
        ldst[j] = ((j < 2 ? 0 : 16384) + ((j & 1) << 13) + (w << 10)) >> 1; // wave-uniform
    }
    // fragment read offsets (swizzled, element units)
    int aoff[2][4], boff[4];
#pragma unroll
    for (int mh = 0; mh < 2; ++mh)
#pragma unroll
        for (int fr = 0; fr < 4; ++fr) {
            const unsigned Lb = (unsigned)(wm + mh * 64 + fr * 16 + lm) * 64 + lg * 16;
            aoff[mh][fr] = (int)(Lb ^ (((Lb >> 7) & 7u) << 4)) >> 1;
        }
#pragma unroll
    for (int n = 0; n < 4; ++n) {
        const unsigned Lb = (unsigned)(wn + n * 16 + lm) * 64 + lg * 16;
        boff[n] = (int)(16384u + (Lb ^ (((Lb >> 7) & 7u) << 4))) >> 1;
    }

    f32x4 acc[8][4];
#pragma unroll
    for (int m = 0; m < 8; ++m)
#pragma unroll
        for (int n = 0; n < 4; ++n) acc[m][n] = f32x4{0.f, 0.f, 0.f, 0.f};

#define ISSUE_SUB(u)                                                          \
    do {                                                                      \
        __bf16* sbp = lds + (((u) & 3) << 14);                                \
        const int go = (u) << 5;                                              \
        _Pragma("unroll")                                                     \
        for (int j = 0; j < 4; ++j) gload_lds16(gsrc[j] + go, sbp + ldst[j]); \
    } while (0)

#define MFMA16(MH, BREG)                                                      \
    do {                                                                      \
        __builtin_amdgcn_s_setprio(1);                                        \
        _Pragma("unroll")                                                     \
        for (int i = 0; i < 4; ++i)                                           \
            _Pragma("unroll")                                                 \
            for (int n = 0; n < 4; ++n)                                       \
                acc[(MH)*4 + i][n] = __builtin_amdgcn_mfma_f32_16x16x32_bf16( \
                    af[i], BREG[n], acc[(MH)*4 + i][n], 0, 0, 0);             \
        __builtin_amdgcn_s_setprio(0);                                        \
    } while (0)

    // prologue: stage sub-tiles 0..3 (2 K-tiles), wait first 2
    ISSUE_SUB(0); ISSUE_SUB(1); ISSUE_SUB(2); ISSUE_SUB(3);
    asm volatile("s_waitcnt vmcnt(8)" ::: "memory");
    __builtin_amdgcn_s_barrier();

    for (int t = 0; t < NT; ++t) {
        const int sa = ((2 * t) & 3) << 14, sb = ((2 * t + 1) & 3) << 14;
        bf16x8 af[4], b0[4], b1[4];
        // P0: A(mh0) + B from sub-tile a (ks=0)
#pragma unroll
        for (int fr = 0; fr < 4; ++fr) af[fr] = *(const bf16x8*)(lds + sa + aoff[0][fr]);
#pragma unroll
        for (int n = 0; n < 4; ++n) b0[n] = *(const bf16x8*)(lds + sa + boff[n]);
        asm volatile("" ::: "memory");
        __builtin_amdgcn_s_barrier();
        __builtin_amdgcn_sched_barrier(0);
        MFMA16(0, b0);
        __builtin_amdgcn_sched_barrier(0);
        __builtin_amdgcn_s_barrier();
        // P1: A(mh1) from a
#pragma unroll
        for (int fr = 0; fr < 4; ++fr) af[fr] = *(const bf16x8*)(lds + sa + aoff[1][fr]);
        asm volatile("" ::: "memory");
        __builtin_amdgcn_s_barrier();
        __builtin_amdgcn_sched_barrier(0);
        MFMA16(1, b0);
        __builtin_amdgcn_sched_barrier(0);
        __builtin_amdgcn_s_barrier();
        // P2: stage u=2t+4 into (dead) buffer a; A(mh0)+B from b (ks=1)
        if (t < NT - 2) ISSUE_SUB(2 * t + 4);
#pragma unroll
        for (int fr = 0; fr < 4; ++fr) af[fr] = *(const bf16x8*)(lds + sb + aoff[0][fr]);
#pragma unroll
        for (int n = 0; n < 4; ++n) b1[n] = *(const bf16x8*)(lds + sb + boff[n]);
        asm volatile("" ::: "memory");
        __builtin_amdgcn_s_barrier();
        __builtin_amdgcn_sched_barrier(0);
        MFMA16(0, b1);
        __builtin_amdgcn_sched_barrier(0);
        __builtin_amdgcn_s_barrier();
        // P3: A(mh1) from b
#pragma unroll
        for (int fr = 0; fr < 4; ++fr) af[fr] = *(const bf16x8*)(lds + sb + aoff[1][fr]);
        asm volatile("" ::: "memory");
        __builtin_amdgcn_s_barrier();
        __builtin_amdgcn_sched_barrier(0);
        MFMA16(1, b1);
        __builtin_amdgcn_sched_barrier(0);
        __builtin_amdgcn_s_barrier();
        // tail: stage u=2t+5 into (dead) buffer b; counted wait
        if (t < NT - 2) {
            ISSUE_SUB(2 * t + 5);
            asm volatile("s_waitcnt vmcnt(8)" ::: "memory");
        } else if (t == NT - 2) {
            asm volatile("s_waitcnt vmcnt(0)" ::: "memory");
        }
        __builtin_amdgcn_s_barrier();
    }
#undef ISSUE_SUB
#undef MFMA16

    // epilogue: C/D layout col=lane&15, row=(lane>>4)*4+reg
    const int ldc = (MODE == 4) ? 2048 : N;
#pragma unroll
    for (int m = 0; m < 8; ++m) {
        const int row = bm + wm + (m >> 2) * 64 + (m & 3) * 16 + lg * 4;
#pragma unroll
        for (int n = 0; n < 4; ++n) {
            const int col = bn + wn + n * 16 + lm;
            const float bvv = bias[col];
            if (MODE == 4 && bn >= 2048) {
                bf16x4 o;
#pragma unroll
                for (int r = 0; r < 4; ++r) o[r] = (__bf16)(acc[m][n][r] + bvv);
                *(bf16x4*)(vTout + (size_t)((row >> 10) * 1024 + (col - 2048)) * 1024 +
                           (row & 1023)) = o;
            } else {
#pragma unroll
                for (int r = 0; r < 4; ++r) {
                    const float v = acc[m][n][r] + bvv;
                    outp[(size_t)(row + r) * ldc + col] =
                        (MODE == 1) ? (__bf16)fmaxf(v, 0.f) : (__bf16)v;
                }
            }
        }
    }
}

// ---------------------------------------------------------------------------
// m97-style 128x128 GEMM, MODE 2: f32 out + residual (for proj / FFN2, N=1024)
// ---------------------------------------------------------------------------
template <int MODE>
__global__ __launch_bounds__(256) void gemm_bt(const __bf16* __restrict__ A,
                                               const __bf16* __restrict__ BT,
                                               const float* __restrict__ bias,
                                               const float* __restrict__ resid,
                                               void* __restrict__ outp,
                                               int M, int N, int K) {
    __shared__ __align__(16) __bf16 As[128][32];
    __shared__ __align__(16) __bf16 Bs[128][32];
    const int bm = blockIdx.y * 128, bn = blockIdx.x * 128;
    const int tid = threadIdx.x, l = tid & 63, wid = tid >> 6;
    const int wr = (wid >> 1) * 64, wc = (wid & 1) * 64;
    const int lg = l >> 4, lm = l & 15;

    const int srow = wid * 32 + (l >> 2);
    const int scol = (l & 3) * 8;
    const __bf16* Ag = A  + (size_t)(bm + srow) * K + scol;
    const __bf16* Bg = BT + (size_t)(bn + srow) * K + scol;
    __bf16* AsD = &As[wid * 32][0];
    __bf16* BsD = &Bs[wid * 32][0];

    f32x4 acc[4][4];
#pragma unroll
    for (int m = 0; m < 4; ++m)
#pragma unroll
        for (int n = 0; n < 4; ++n) acc[m][n] = f32x4{0.f, 0.f, 0.f, 0.f};

    for (int k0 = 0; k0 < K; k0 += 32) {
        gload_lds16(Ag + k0,                   AsD);
        gload_lds16(Ag + (size_t)16 * K + k0,  AsD + 512);
        gload_lds16(Bg + k0,                   BsD);
        gload_lds16(Bg + (size_t)16 * K + k0,  BsD + 512);
        __syncthreads();
        bf16x8 af[4], bfr[4];
#pragma unroll
        for (int m = 0; m < 4; ++m) af[m]  = *(const bf16x8*)&As[wr + m * 16 + lm][lg * 8];
#pragma unroll
        for (int n = 0; n < 4; ++n) bfr[n] = *(const bf16x8*)&Bs[wc + n * 16 + lm][lg * 8];
#pragma unroll
        for (int m = 0; m < 4; ++m)
#pragma unroll
            for (int n = 0; n < 4; ++n)
                acc[m][n] = __builtin_amdgcn_mfma_f32_16x16x32_bf16(af[m], bfr[n], acc[m][n], 0, 0, 0);
        __syncthreads();
    }
#pragma unroll
    for (int m = 0; m < 4; ++m) {
        const int row = bm + wr + m * 16 + lg * 4;
#pragma unroll
        for (int n = 0; n < 4; ++n) {
            const int col = bn + wc + n * 16 + lm;
            const float bv = bias[col];
#pragma unroll
            for (int r = 0; r < 4; ++r) {
                const float v = acc[m][n][r] + bv;
                const size_t idx = (size_t)(row + r) * N + col;
                if (MODE == 0)      ((__bf16*)outp)[idx] = (__bf16)v;
                else if (MODE == 1) ((__bf16*)outp)[idx] = (__bf16)fmaxf(v, 0.f);
                else                ((float*)outp)[idx]  = resid[idx] + v;
            }
        }
    }
}

// ---------------------------------------------------------------------------
// Flash attention fwd. qk: [B*S][2048] bf16 (q|k per head). vT: [B*H*64][S].
// Grid (qt=16, h=16, b=8); 256 thr = 4 waves; wave w owns 16 q rows.
// ---------------------------------------------------------------------------
__global__ __launch_bounds__(256) void attn_kernel(const __bf16* __restrict__ qk,
                                                   const __bf16* __restrict__ vT,
                                                   const int* __restrict__ mask,
                                                   __bf16* __restrict__ ctx) {
    const int qt = blockIdx.x, h = blockIdx.y, b = blockIdx.z;
    const int tid = threadIdx.x, w = tid >> 6, l = tid & 63;
    const int lg = l >> 4, lm = l & 15;

    __shared__ __align__(16) __bf16 Ks[64][76];
    __shared__ __align__(16) __bf16 Vt[64][76];
    __shared__ __align__(16) __bf16 Ps[4][16][76];
    __shared__ int smask[64];

    const int qrow = qt * 64 + w * 16 + lm;
    const __bf16* qp = qk + (size_t)(b * 1024 + qrow) * 2048 + h * 64 + lg * 8;
    bf16x8 aq[2];
    aq[0] = *(const bf16x8*)qp;
    aq[1] = *(const bf16x8*)(qp + 32);

    float mrun[4] = {-1e30f, -1e30f, -1e30f, -1e30f};
    float lsum[4] = {0.f, 0.f, 0.f, 0.f};
    f32x4 oacc[4];
#pragma unroll
    for (int n = 0; n < 4; ++n) oacc[n] = f32x4{0.f, 0.f, 0.f, 0.f};

    for (int kt = 0; kt < 16; ++kt) {
#pragma unroll
        for (int it = 0; it < 2; ++it) {
            const int c = tid + it * 256;
            const int r = c >> 3, cc = (c & 7) * 8;
            *(uint4*)&Ks[r][cc] =
                *(const uint4*)&qk[(size_t)(b * 1024 + kt * 64 + r) * 2048 + 1024 + h * 64 + cc];
            *(uint4*)&Vt[r][cc] =
                *(const uint4*)&vT[(size_t)(b * 1024 + h * 64 + r) * 1024 + kt * 64 + cc];
        }
        if (tid < 64) smask[tid] = mask[b * 1024 + kt * 64 + tid];
        __syncthreads();

        f32x4 sacc[4];
#pragma unroll
        for (int n = 0; n < 4; ++n) {
            sacc[n] = f32x4{0.f, 0.f, 0.f, 0.f};
#pragma unroll
            for (int kk = 0; kk < 2; ++kk) {
                bf16x8 bk = *(const bf16x8*)&Ks[n * 16 + lm][lg * 8 + kk * 32];
                sacc[n] = __builtin_amdgcn_mfma_f32_16x16x32_bf16(aq[kk], bk, sacc[n], 0, 0, 0);
            }
        }
        float p[4][4], tmax[4] = {-1e30f, -1e30f, -1e30f, -1e30f};
#pragma unroll
        for (int n = 0; n < 4; ++n) {
            const int mk = smask[n * 16 + lm];
#pragma unroll
            for (int r = 0; r < 4; ++r) {
                float sv = sacc[n][r] * 0.125f;
                if (mk == 0) sv = -1e9f;
                p[n][r] = sv;
                tmax[r] = fmaxf(tmax[r], sv);
            }
        }
#pragma unroll
        for (int off = 1; off < 16; off <<= 1)
#pragma unroll
            for (int r = 0; r < 4; ++r) tmax[r] = fmaxf(tmax[r], __shfl_xor(tmax[r], off));
        float scale[4];
#pragma unroll
        for (int r = 0; r < 4; ++r) {
            const float mnew = fmaxf(mrun[r], tmax[r]);
            scale[r] = __expf(mrun[r] - mnew);
            mrun[r] = mnew;
        }
#pragma unroll
        for (int n = 0; n < 4; ++n)
#pragma unroll
            for (int r = 0; r < 4; ++r) p[n][r] = __expf(p[n][r] - mrun[r]);
        float rsum[4];
#pragma unroll
        for (int r = 0; r < 4; ++r) rsum[r] = p[0][r] + p[1][r] + p[2][r] + p[3][r];
#pragma unroll
        for (int off = 1; off < 16; off <<= 1)
#pragma unroll
            for (int r = 0; r < 4; ++r) rsum[r] += __shfl_xor(rsum[r], off);
#pragma unroll
        for (int r = 0; r < 4; ++r) lsum[r] = lsum[r] * scale[r] + rsum[r];
#pragma unroll
        for (int n = 0; n < 4; ++n)
#pragma unroll
            for (int r = 0; r < 4; ++r) oacc[n][r] *= scale[r];
#pragma unroll
        for (int n = 0; n < 4; ++n)
#pragma unroll
            for (int r = 0; r < 4; ++r) Ps[w][lg * 4 + r][n * 16 + lm] = (__bf16)p[n][r];
        bf16x8 ap[2];
        ap[0] = *(const bf16x8*)&Ps[w][lm][lg * 8];
        ap[1] = *(const bf16x8*)&Ps[w][lm][lg * 8 + 32];
#pragma unroll
        for (int n = 0; n < 4; ++n)
#pragma unroll
            for (int kk = 0; kk < 2; ++kk) {
                bf16x8 bv = *(const bf16x8*)&Vt[n * 16 + lm][lg * 8 + kk * 32];
                oacc[n] = __builtin_amdgcn_mfma_f32_16x16x32_bf16(ap[kk], bv, oacc[n], 0, 0, 0);
            }
        __syncthreads();
    }
#pragma unroll
    for (int n = 0; n < 4; ++n)
#pragma unroll
        for (int r = 0; r < 4; ++r) {
            const float val = oacc[n][r] / lsum[r];
            const int row = qt * 64 + w * 16 + lg * 4 + r;
            ctx[(size_t)(b * 1024 + row) * 1024 + h * 64 + n * 16 + lm] = (__bf16)val;
        }
}

// ---------------------------------------------------------------------------
extern "C" void kernel_launch(void* const* d_in, const int* in_sizes, int n_in,
                              void* d_out, int out_size, void* d_ws, size_t ws_size,
                              hipStream_t stream) {
    const float* x    = (const float*)d_in[0];
    const int*   mask = (const int*)d_in[1];
    const float* wq   = (const float*)d_in[2];
    const float* bq   = (const float*)d_in[3];
    const float* wk   = (const float*)d_in[4];
    const float* bk   = (const float*)d_in[5];
    const float* wv   = (const float*)d_in[6];
    const float* bv   = (const float*)d_in[7];
    const float* wo   = (const float*)d_in[8];
    const float* bo   = (const float*)d_in[9];
    const float* w1   = (const float*)d_in[10];
    const float* b1   = (const float*)d_in[11];
    const float* w2   = (const float*)d_in[12];
    const float* b2   = (const float*)d_in[13];
    const float* ln1g = (const float*)d_in[14];
    const float* ln1b = (const float*)d_in[15];
    const float* ln2g = (const float*)d_in[16];
    const float* ln2b = (const float*)d_in[17];
    float* out = (float*)d_out;
    char* ws = (char*)d_ws;

    // workspace layout (bytes)
    __bf16* wqkvT = (__bf16*)(ws + 0);          // [3072][1024]  6 MB
    __bf16* woT   = (__bf16*)(ws + 6291456);    // [1024][1024]  2 MB
    __bf16* w1T   = (__bf16*)(ws + 8388608);    // [4096][1024]  8 MB
    __bf16* w2T   = (__bf16*)(ws + 16777216);   // [1024][4096]  8 MB
    float*  bqkv  = (float*)(ws + 25165824);    // [3072]
    __bf16* hb    = (__bf16*)(ws + 25178112);   // [8192][1024] 16 MB (LN1/LN2 out)
    __bf16* qkb   = (__bf16*)(ws + 41955328);   // [8192][2048] 32 MB
    __bf16* vTb   = (__bf16*)(ws + 75509760);   // [8*16*64][1024] 16 MB
    __bf16* ctxb  = (__bf16*)(ws + 92286976);   // [8192][1024] 16 MB -> 109064192
    __bf16* ff1b  = qkb;                        // [8192][4096] 64 MB overlays qk+vT+ctx

    transpose_convert<<<dim3(32, 32),  256, 0, stream>>>(wq, wqkvT,               1024, 1024);
    transpose_convert<<<dim3(32, 32),  256, 0, stream>>>(wk, wqkvT + 1024 * 1024, 1024, 1024);
    transpose_convert<<<dim3(32, 32),  256, 0, stream>>>(wv, wqkvT + 2048 * 1024, 1024, 1024);
    transpose_convert<<<dim3(32, 32),  256, 0, stream>>>(wo, woT,                 1024, 1024);
    transpose_convert<<<dim3(128, 32), 256, 0, stream>>>(w1, w1T,                 1024, 4096);
    transpose_convert<<<dim3(32, 128), 256, 0, stream>>>(w2, w2T,                 4096, 1024);
    concat3<<<4, 256, 0, stream>>>(bq, bk, bv, bqkv, 1024);

    // LN1 -> hb
    ln_to_bf16<<<8192, 256, 0, stream>>>(x, ln1g, ln1b, hb);
    // fused QKV (8-phase 256^2): q|k -> qkb (ldc 2048), v -> vTb transposed
    gemm256<4><<<384, 512, 0, stream>>>(hb, wqkvT, bqkv, qkb, vTb, 8192, 3072, 1024, 32);
    // attention
    attn_kernel<<<dim3(16, 16, 8), 256, 0, stream>>>(qkb, vTb, mask, ctxb);
    // output proj + residual -> d_out (fp32)
    gemm_bt<2><<<dim3(8, 64), 256, 0, stream>>>(ctxb, woT, bo, x, out, 8192, 1024, 1024);
    // LN2 -> hb
    ln_to_bf16<<<8192, 256, 0, stream>>>(out, ln2g, ln2b, hb);
    // FFN1 (8-phase 256^2, relu)
    gemm256<1><<<512, 512, 0, stream>>>(hb, w1T, b1, ff1b, nullptr, 8192, 4096, 1024, 32);
    // FFN2 + residual
    gemm_bt<2><<<dim3(8, 64), 256, 0, stream>>>(ff1b, w2T, b2, out, out, 8192, 1024, 4096);
}

// Round 4
// 404.520 us; speedup vs baseline: 1.3033x; 1.1812x over previous
//
#include <hip/hip_runtime.h>
#include <hip/hip_bf16.h>

typedef __attribute__((ext_vector_type(8))) __bf16 bf16x8;
typedef __attribute__((ext_vector_type(4))) __bf16 bf16x4;
typedef __attribute__((ext_vector_type(4))) float  f32x4;

__device__ __forceinline__ void gload_lds16(const __bf16* g, __bf16* l) {
    __builtin_amdgcn_global_load_lds(
        (const __attribute__((address_space(1))) void*)g,
        (__attribute__((address_space(3))) void*)l, 16, 0, 0);
}

// ---------------------------------------------------------------------------
// Weight transpose + fp32->bf16 convert:  in [K][N] f32  ->  out [N][K] bf16
// ---------------------------------------------------------------------------
__global__ void transpose_convert(const float* __restrict__ in,
                                  __bf16* __restrict__ out, int K, int N) {
    __shared__ float t[32][33];
    const int nb = blockIdx.x * 32, kb = blockIdx.y * 32;
    const int tx = threadIdx.x & 31, ty = threadIdx.x >> 5;
#pragma unroll
    for (int i = 0; i < 32; i += 8)
        t[ty + i][tx] = in[(size_t)(kb + ty + i) * N + nb + tx];
    __syncthreads();
#pragma unroll
    for (int i = 0; i < 32; i += 8)
        out[(size_t)(nb + ty + i) * K + kb + tx] = (__bf16)t[tx][ty + i];
}

__global__ void concat3(const float* __restrict__ a, const float* __restrict__ b,
                        const float* __restrict__ c, float* __restrict__ o, int n) {
    int i = blockIdx.x * 256 + threadIdx.x;
    if (i < n) { o[i] = a[i]; o[n + i] = b[i]; o[2 * n + i] = c[i]; }
}

// ---------------------------------------------------------------------------
// LayerNorm over D=1024, one block per row, fp32 in -> bf16 out
// ---------------------------------------------------------------------------
__global__ __launch_bounds__(256) void ln_to_bf16(const float* __restrict__ x,
                                                  const float* __restrict__ g,
                                                  const float* __restrict__ bb,
                                                  __bf16* __restrict__ out) {
    const int row = blockIdx.x, t = threadIdx.x;
    const float4 v = ((const float4*)(x + (size_t)row * 1024))[t];
    float s  = v.x + v.y + v.z + v.w;
    float ss = v.x * v.x + v.y * v.y + v.z * v.z + v.w * v.w;
#pragma unroll
    for (int off = 32; off; off >>= 1) {
        s  += __shfl_down(s, off);
        ss += __shfl_down(ss, off);
    }
    __shared__ float ps[4], pss[4];
    if ((t & 63) == 0) { ps[t >> 6] = s; pss[t >> 6] = ss; }
    __syncthreads();
    s  = ps[0] + ps[1] + ps[2] + ps[3];
    ss = pss[0] + pss[1] + pss[2] + pss[3];
    const float mu   = s * (1.0f / 1024.0f);
    const float var  = ss * (1.0f / 1024.0f) - mu * mu;
    const float rinv = rsqrtf(var + 1e-5f);
    const float4 gv = ((const float4*)g)[t];
    const float4 bv = ((const float4*)bb)[t];
    bf16x4 o;
    o[0] = (__bf16)((v.x - mu) * rinv * gv.x + bv.x);
    o[1] = (__bf16)((v.y - mu) * rinv * gv.y + bv.y);
    o[2] = (__bf16)((v.z - mu) * rinv * gv.z + bv.z);
    o[3] = (__bf16)((v.w - mu) * rinv * gv.w + bv.w);
    *(bf16x4*)(out + (size_t)row * 1024 + 4 * t) = o;
}

// ---------------------------------------------------------------------------
// 256x256 8-phase GEMM. 8 waves (2M x 4N), per-wave 128x64. BK=64 as 2
// sub-tiles of 32; ring of 4 LDS sub-buffers; counted vmcnt(8); swizzle.
// MODE 1: relu bf16 | MODE 4: qkv out (Q cols pre-scaled 1/8; V transposed)
// ---------------------------------------------------------------------------
template <int MODE>
__global__ __launch_bounds__(512, 2) void gemm256(const __bf16* __restrict__ A,
                                                  const __bf16* __restrict__ BT,
                                                  const float* __restrict__ bias,
                                                  __bf16* __restrict__ outp,
                                                  __bf16* __restrict__ vTout,
                                                  int M, int N, int K, int NMB) {
    __shared__ __align__(16) __bf16 lds[65536];   // 4 sub-buffers x 16384 elems
    const int nwg = gridDim.x;
    const int bid = blockIdx.x;
    const int wgid = (bid & 7) * (nwg >> 3) + (bid >> 3);
    const int bm = (wgid % NMB) * 256, bn = (wgid / NMB) * 256;
    const int tid = threadIdx.x, l = tid & 63, w = tid >> 6;
    const int wm = (w >> 2) * 128, wn = (w & 3) * 64;
    const int lg = l >> 4, lm = l & 15;
    const int NT = K >> 6;

    const __bf16* gsrc[4];
    int ldst[4];
#pragma unroll
    for (int j = 0; j < 4; ++j) {
        const unsigned X = (unsigned)(((j & 1) << 13) + (w << 10) + l * 16);
        const unsigned L = X ^ (((X >> 7) & 7u) << 4);
        const int row = L >> 6, col = (L & 63) >> 1;
        gsrc[j] = (j < 2 ? A + (size_t)(bm + row) * K : BT + (size_t)(bn + row) * K) + col;
        ldst[j] = ((j < 2 ? 0 : 16384) + ((j & 1) << 13) + (w << 10)) >> 1;
    }
    int aoff[2][4], boff[4];
#pragma unroll
    for (int mh = 0; mh < 2; ++mh)
#pragma unroll
        for (int fr = 0; fr < 4; ++fr) {
            const unsigned Lb = (unsigned)(wm + mh * 64 + fr * 16 + lm) * 64 + lg * 16;
            aoff[mh][fr] = (int)(Lb ^ (((Lb >> 7) & 7u) << 4)) >> 1;
        }
#pragma unroll
    for (int n = 0; n < 4; ++n) {
        const unsigned Lb = (unsigned)(wn + n * 16 + lm) * 64 + lg * 16;
        boff[n] = (int)(16384u + (Lb ^ (((Lb >> 7) & 7u) << 4))) >> 1;
    }

    f32x4 acc[8][4];
#pragma unroll
    for (int m = 0; m < 8; ++m)
#pragma unroll
        for (int n = 0; n < 4; ++n) acc[m][n] = f32x4{0.f, 0.f, 0.f, 0.f};

#define ISSUE_SUB(u)                                                          \
    do {                                                                      \
        __bf16* sbp = lds + (((u) & 3) << 14);                                \
        const int go = (u) << 5;                                              \
        _Pragma("unroll")                                                     \
        for (int j = 0; j < 4; ++j) gload_lds16(gsrc[j] + go, sbp + ldst[j]); \
    } while (0)

#define MFMA16(MH, BREG)                                                      \
    do {                                                                      \
        __builtin_amdgcn_s_setprio(1);                                        \
        _Pragma("unroll")                                                     \
        for (int i = 0; i < 4; ++i)                                           \
            _Pragma("unroll")                                                 \
            for (int n = 0; n < 4; ++n)                                       \
                acc[(MH)*4 + i][n] = __builtin_amdgcn_mfma_f32_16x16x32_bf16( \
                    af[i], BREG[n], acc[(MH)*4 + i][n], 0, 0, 0);             \
        __builtin_amdgcn_s_setprio(0);                                        \
    } while (0)

    ISSUE_SUB(0); ISSUE_SUB(1); ISSUE_SUB(2); ISSUE_SUB(3);
    asm volatile("s_waitcnt vmcnt(8)" ::: "memory");
    __builtin_amdgcn_s_barrier();

    for (int t = 0; t < NT; ++t) {
        const int sa = ((2 * t) & 3) << 14, sb = ((2 * t + 1) & 3) << 14;
        bf16x8 af[4], b0[4], b1[4];
#pragma unroll
        for (int fr = 0; fr < 4; ++fr) af[fr] = *(const bf16x8*)(lds + sa + aoff[0][fr]);
#pragma unroll
        for (int n = 0; n < 4; ++n) b0[n] = *(const bf16x8*)(lds + sa + boff[n]);
        asm volatile("" ::: "memory");
        __builtin_amdgcn_s_barrier();
        __builtin_amdgcn_sched_barrier(0);
        MFMA16(0, b0);
        __builtin_amdgcn_sched_barrier(0);
        __builtin_amdgcn_s_barrier();
#pragma unroll
        for (int fr = 0; fr < 4; ++fr) af[fr] = *(const bf16x8*)(lds + sa + aoff[1][fr]);
        asm volatile("" ::: "memory");
        __builtin_amdgcn_s_barrier();
        __builtin_amdgcn_sched_barrier(0);
        MFMA16(1, b0);
        __builtin_amdgcn_sched_barrier(0);
        __builtin_amdgcn_s_barrier();
        if (t < NT - 2) ISSUE_SUB(2 * t + 4);
#pragma unroll
        for (int fr = 0; fr < 4; ++fr) af[fr] = *(const bf16x8*)(lds + sb + aoff[0][fr]);
#pragma unroll
        for (int n = 0; n < 4; ++n) b1[n] = *(const bf16x8*)(lds + sb + boff[n]);
        asm volatile("" ::: "memory");
        __builtin_amdgcn_s_barrier();
        __builtin_amdgcn_sched_barrier(0);
        MFMA16(0, b1);
        __builtin_amdgcn_sched_barrier(0);
        __builtin_amdgcn_s_barrier();
#pragma unroll
        for (int fr = 0; fr < 4; ++fr) af[fr] = *(const bf16x8*)(lds + sb + aoff[1][fr]);
        asm volatile("" ::: "memory");
        __builtin_amdgcn_s_barrier();
        __builtin_amdgcn_sched_barrier(0);
        MFMA16(1, b1);
        __builtin_amdgcn_sched_barrier(0);
        __builtin_amdgcn_s_barrier();
        if (t < NT - 2) {
            ISSUE_SUB(2 * t + 5);
            asm volatile("s_waitcnt vmcnt(8)" ::: "memory");
        } else if (t == NT - 2) {
            asm volatile("s_waitcnt vmcnt(0)" ::: "memory");
        }
        __builtin_amdgcn_s_barrier();
    }
#undef ISSUE_SUB
#undef MFMA16

    const int ldc = (MODE == 4) ? 2048 : N;
    const bool isQ = (MODE == 4) && (bn < 1024);
#pragma unroll
    for (int m = 0; m < 8; ++m) {
        const int row = bm + wm + (m >> 2) * 64 + (m & 3) * 16 + lg * 4;
#pragma unroll
        for (int n = 0; n < 4; ++n) {
            const int col = bn + wn + n * 16 + lm;
            const float bvv = bias[col];
            if (MODE == 4 && bn >= 2048) {
                bf16x4 o;
#pragma unroll
                for (int r = 0; r < 4; ++r) o[r] = (__bf16)(acc[m][n][r] + bvv);
                *(bf16x4*)(vTout + (size_t)((row >> 10) * 1024 + (col - 2048)) * 1024 +
                           (row & 1023)) = o;
            } else {
#pragma unroll
                for (int r = 0; r < 4; ++r) {
                    float v = acc[m][n][r] + bvv;
                    if (isQ) v *= 0.125f;   // fold 1/sqrt(dk) into Q
                    outp[(size_t)(row + r) * ldc + col] =
                        (MODE == 1) ? (__bf16)fmaxf(v, 0.f) : (__bf16)v;
                }
            }
        }
    }
}

// ---------------------------------------------------------------------------
// 256x128 8-phase GEMM, f32 out + residual (proj / FFN2, N=1024).
// 8 waves (4M x 2N), per-wave 64x64. Sub-buffer = A(8192)+B(4096) elems,
// ring of 4 (96 KiB). 3 gloads/thread/sub -> vmcnt(6). Grid 256 = 1 wg/CU.
// ---------------------------------------------------------------------------
__global__ __launch_bounds__(512, 2) void gemm256x128(const __bf16* __restrict__ A,
                                                      const __bf16* __restrict__ BT,
                                                      const float* __restrict__ bias,
                                                      const float* __restrict__ resid,
                                                      float* __restrict__ outp,
                                                      int M, int N, int K, int NMB) {
    __shared__ __align__(16) __bf16 lds[49152];   // 4 x 12288 elems
    const int nwg = gridDim.x;
    const int bid = blockIdx.x;
    const int wgid = (bid & 7) * (nwg >> 3) + (bid >> 3);
    const int bm = (wgid % NMB) * 256, bn = (wgid / NMB) * 128;
    const int tid = threadIdx.x, l = tid & 63, w = tid >> 6;
    const int wm = (w >> 1) * 64, wn = (w & 1) * 64;
    const int lg = l >> 4, lm = l & 15;
    const int NT = K >> 6;

    // staging: j=0,1 -> A rows [0,256) (16KB); j=2 -> B rows [0,128) (8KB)
    const __bf16* gsrc[3];
    int ldst[3];
#pragma unroll
    for (int j = 0; j < 3; ++j) {
        const unsigned X = (unsigned)((j == 1 ? 8192 : 0) + tid * 16);
        const unsigned L = X ^ (((X >> 7) & 7u) << 4);
        const int row = L >> 6, col = (L & 63) >> 1;
        gsrc[j] = (j < 2 ? A + (size_t)(bm + row) * K : BT + (size_t)(bn + row) * K) + col;
        ldst[j] = ((j < 2 ? (j << 13) : 16384) + (w << 10)) >> 1;
    }
    int aoff[2][2], boff[4];
#pragma unroll
    for (int mh = 0; mh < 2; ++mh)
#pragma unroll
        for (int fr = 0; fr < 2; ++fr) {
            const unsigned Lb = (unsigned)(wm + mh * 32 + fr * 16 + lm) * 64 + lg * 16;
            aoff[mh][fr] = (int)(Lb ^ (((Lb >> 7) & 7u) << 4)) >> 1;
        }
#pragma unroll
    for (int n = 0; n < 4; ++n) {
        const unsigned Lb = (unsigned)(wn + n * 16 + lm) * 64 + lg * 16;
        boff[n] = (int)(16384u + (Lb ^ (((Lb >> 7) & 7u) << 4))) >> 1;
    }

    f32x4 acc[4][4];
#pragma unroll
    for (int m = 0; m < 4; ++m)
#pragma unroll
        for (int n = 0; n < 4; ++n) acc[m][n] = f32x4{0.f, 0.f, 0.f, 0.f};

#define ISSUE_SUB(u)                                                          \
    do {                                                                      \
        __bf16* sbp = lds + ((u) & 3) * 12288;                                \
        const int go = (u) << 5;                                              \
        _Pragma("unroll")                                                     \
        for (int j = 0; j < 3; ++j) gload_lds16(gsrc[j] + go, sbp + ldst[j]); \
    } while (0)

#define MFMA8(MH, BREG)                                                       \
    do {                                                                      \
        __builtin_amdgcn_s_setprio(1);                                        \
        _Pragma("unroll")                                                     \
        for (int i = 0; i < 2; ++i)                                           \
            _Pragma("unroll")                                                 \
            for (int n = 0; n < 4; ++n)                                       \
                acc[(MH)*2 + i][n] = __builtin_amdgcn_mfma_f32_16x16x32_bf16( \
                    af[i], BREG[n], acc[(MH)*2 + i][n], 0, 0, 0);             \
        __builtin_amdgcn_s_setprio(0);                                        \
    } while (0)

    ISSUE_SUB(0); ISSUE_SUB(1); ISSUE_SUB(2); ISSUE_SUB(3);
    asm volatile("s_waitcnt vmcnt(6)" ::: "memory");
    __builtin_amdgcn_s_barrier();

    for (int t = 0; t < NT; ++t) {
        const int sa = ((2 * t) & 3) * 12288, sb = ((2 * t + 1) & 3) * 12288;
        bf16x8 af[2], b0[4], b1[4];
#pragma unroll
        for (int fr = 0; fr < 2; ++fr) af[fr] = *(const bf16x8*)(lds + sa + aoff[0][fr]);
#pragma unroll
        for (int n = 0; n < 4; ++n) b0[n] = *(const bf16x8*)(lds + sa + boff[n]);
        asm volatile("" ::: "memory");
        __builtin_amdgcn_s_barrier();
        __builtin_amdgcn_sched_barrier(0);
        MFMA8(0, b0);
        __builtin_amdgcn_sched_barrier(0);
        __builtin_amdgcn_s_barrier();
#pragma unroll
        for (int fr = 0; fr < 2; ++fr) af[fr] = *(const bf16x8*)(lds + sa + aoff[1][fr]);
        asm volatile("" ::: "memory");
        __builtin_amdgcn_s_barrier();
        __builtin_amdgcn_sched_barrier(0);
        MFMA8(1, b0);
        __builtin_amdgcn_sched_barrier(0);
        __builtin_amdgcn_s_barrier();
        if (t < NT - 2) ISSUE_SUB(2 * t + 4);
#pragma unroll
        for (int fr = 0; fr < 2; ++fr) af[fr] = *(const bf16x8*)(lds + sb + aoff[0][fr]);
#pragma unroll
        for (int n = 0; n < 4; ++n) b1[n] = *(const bf16x8*)(lds + sb + boff[n]);
        asm volatile("" ::: "memory");
        __builtin_amdgcn_s_barrier();
        __builtin_amdgcn_sched_barrier(0);
        MFMA8(0, b1);
        __builtin_amdgcn_sched_barrier(0);
        __builtin_amdgcn_s_barrier();
#pragma unroll
        for (int fr = 0; fr < 2; ++fr) af[fr] = *(const bf16x8*)(lds + sb + aoff[1][fr]);
        asm volatile("" ::: "memory");
        __builtin_amdgcn_s_barrier();
        __builtin_amdgcn_sched_barrier(0);
        MFMA8(1, b1);
        __builtin_amdgcn_sched_barrier(0);
        __builtin_amdgcn_s_barrier();
        if (t < NT - 2) {
            ISSUE_SUB(2 * t + 5);
            asm volatile("s_waitcnt vmcnt(6)" ::: "memory");
        } else if (t == NT - 2) {
            asm volatile("s_waitcnt vmcnt(0)" ::: "memory");
        }
        __builtin_amdgcn_s_barrier();
    }
#undef ISSUE_SUB
#undef MFMA8

#pragma unroll
    for (int m = 0; m < 4; ++m) {
        const int row = bm + wm + m * 16 + lg * 4;
#pragma unroll
        for (int n = 0; n < 4; ++n) {
            const int col = bn + wn + n * 16 + lm;
            const float bvv = bias[col];
#pragma unroll
            for (int r = 0; r < 4; ++r) {
                const size_t idx = (size_t)(row + r) * N + col;
                outp[idx] = resid[idx] + acc[m][n][r] + bvv;
            }
        }
    }
}

// ---------------------------------------------------------------------------
// Flash attention fwd, swapped-QK^T (S^T per lane -> lane-local softmax rows).
// qk: [B*S][2048] bf16 (Q pre-scaled by 1/8 | K). vT: [B*H*64][S] bf16.
// Grid (qt=16, h=16, b=8); 4 waves; wave w owns q rows [w*16, w*16+16).
// ---------------------------------------------------------------------------
__global__ __launch_bounds__(256) void attn_kernel(const __bf16* __restrict__ qk,
                                                   const __bf16* __restrict__ vT,
                                                   const int* __restrict__ mask,
                                                   __bf16* __restrict__ ctx) {
    const int qt = blockIdx.x, h = blockIdx.y, b = blockIdx.z;
    const int tid = threadIdx.x, w = tid >> 6, l = tid & 63;
    const int lg = l >> 4, lm = l & 15;

    __shared__ __align__(16) __bf16 Ks[64][76];
    __shared__ __align__(16) __bf16 Vt[64][76];
    __shared__ __align__(16) __bf16 Ps[4][16][76];
    __shared__ int smask[64];

    const int qrow = qt * 64 + w * 16 + lm;
    const __bf16* qp = qk + (size_t)(b * 1024 + qrow) * 2048 + h * 64 + lg * 8;
    bf16x8 aq[2];
    aq[0] = *(const bf16x8*)qp;
    aq[1] = *(const bf16x8*)(qp + 32);

    float mrun = -1e30f, lsum = 0.f;   // stats for query lm (lane-local)
    f32x4 oacc[4];
#pragma unroll
    for (int n = 0; n < 4; ++n) oacc[n] = f32x4{0.f, 0.f, 0.f, 0.f};

    for (int kt = 0; kt < 16; ++kt) {
#pragma unroll
        for (int it = 0; it < 2; ++it) {
            const int c = tid + it * 256;
            const int r = c >> 3, cc = (c & 7) * 8;
            *(uint4*)&Ks[r][cc] =
                *(const uint4*)&qk[(size_t)(b * 1024 + kt * 64 + r) * 2048 + 1024 + h * 64 + cc];
            *(uint4*)&Vt[r][cc] =
                *(const uint4*)&vT[(size_t)(b * 1024 + h * 64 + r) * 1024 + kt * 64 + cc];
        }
        if (tid < 64) smask[tid] = mask[b * 1024 + kt * 64 + tid];
        __syncthreads();

        // S^T = K Q^T : sacc[n][r] = S[key = n*16+lg*4+r][q = lm]
        f32x4 sacc[4];
#pragma unroll
        for (int n = 0; n < 4; ++n) {
            sacc[n] = f32x4{0.f, 0.f, 0.f, 0.f};
#pragma unroll
            for (int kk = 0; kk < 2; ++kk) {
                bf16x8 bk = *(const bf16x8*)&Ks[n * 16 + lm][lg * 8 + kk * 32];
                sacc[n] = __builtin_amdgcn_mfma_f32_16x16x32_bf16(bk, aq[kk], sacc[n], 0, 0, 0);
            }
        }
        // lane-local softmax row (16 scores of query lm)
        float p[4][4], mloc = -3e38f;
#pragma unroll
        for (int n = 0; n < 4; ++n) {
            const int4 mk = *(const int4*)&smask[n * 16 + lg * 4];
            const int mka[4] = {mk.x, mk.y, mk.z, mk.w};
#pragma unroll
            for (int r = 0; r < 4; ++r) {
                const float sv = (mka[r] == 0) ? -1e9f : sacc[n][r];
                p[n][r] = sv;
                mloc = fmaxf(mloc, sv);
            }
        }
        mloc = fmaxf(mloc, __shfl_xor(mloc, 16));
        mloc = fmaxf(mloc, __shfl_xor(mloc, 32));
        const float pm = fmaxf(mrun, mloc);
        if (!__all(pm - mrun <= 8.f)) {          // defer-max (T13)
            const float sc = __expf(mrun - pm);
            mrun = pm;
            lsum *= sc;
            float scr[4];
#pragma unroll
            for (int r = 0; r < 4; ++r) scr[r] = __shfl(sc, lg * 4 + r);
#pragma unroll
            for (int n = 0; n < 4; ++n)
#pragma unroll
                for (int r = 0; r < 4; ++r) oacc[n][r] *= scr[r];
        }
        float rs = 0.f;
#pragma unroll
        for (int n = 0; n < 4; ++n)
#pragma unroll
            for (int r = 0; r < 4; ++r) {
                p[n][r] = __expf(p[n][r] - mrun);
                rs += p[n][r];
            }
        rs += __shfl_xor(rs, 16);
        rs += __shfl_xor(rs, 32);
        lsum += rs;
        // P[q=lm][key] -> LDS, 4x b64 (consecutive keys per lane)
#pragma unroll
        for (int n = 0; n < 4; ++n) {
            bf16x4 pb;
#pragma unroll
            for (int r = 0; r < 4; ++r) pb[r] = (__bf16)p[n][r];
            *(bf16x4*)&Ps[w][lm][n * 16 + lg * 4] = pb;
        }
        bf16x8 ap[2];
        ap[0] = *(const bf16x8*)&Ps[w][lm][lg * 8];
        ap[1] = *(const bf16x8*)&Ps[w][lm][lg * 8 + 32];
#pragma unroll
        for (int n = 0; n < 4; ++n)
#pragma unroll
            for (int kk = 0; kk < 2; ++kk) {
                bf16x8 bv = *(const bf16x8*)&Vt[n * 16 + lm][lg * 8 + kk * 32];
                oacc[n] = __builtin_amdgcn_mfma_f32_16x16x32_bf16(ap[kk], bv, oacc[n], 0, 0, 0);
            }
        __syncthreads();
    }
    // epilogue: oacc lane holds O[q=lg*4+r][d=n*16+lm]; lsum lives at lane lm=q
    float lsr[4];
#pragma unroll
    for (int r = 0; r < 4; ++r) lsr[r] = __shfl(lsum, lg * 4 + r);
#pragma unroll
    for (int n = 0; n < 4; ++n)
#pragma unroll
        for (int r = 0; r < 4; ++r) {
            const float val = oacc[n][r] / lsr[r];
            const int row = qt * 64 + w * 16 + lg * 4 + r;
            ctx[(size_t)(b * 1024 + row) * 1024 + h * 64 + n * 16 + lm] = (__bf16)val;
        }
}

// ---------------------------------------------------------------------------
extern "C" void kernel_launch(void* const* d_in, const int* in_sizes, int n_in,
                              void* d_out, int out_size, void* d_ws, size_t ws_size,
                              hipStream_t stream) {
    const float* x    = (const float*)d_in[0];
    const int*   mask = (const int*)d_in[1];
    const float* wq   = (const float*)d_in[2];
    const float* bq   = (const float*)d_in[3];
    const float* wk   = (const float*)d_in[4];
    const float* bk   = (const float*)d_in[5];
    const float* wv   = (const float*)d_in[6];
    const float* bv   = (const float*)d_in[7];
    const float* wo   = (const float*)d_in[8];
    const float* bo   = (const float*)d_in[9];
    const float* w1   = (const float*)d_in[10];
    const float* b1   = (const float*)d_in[11];
    const float* w2   = (const float*)d_in[12];
    const float* b2   = (const float*)d_in[13];
    const float* ln1g = (const float*)d_in[14];
    const float* ln1b = (const float*)d_in[15];
    const float* ln2g = (const float*)d_in[16];
    const float* ln2b = (const float*)d_in[17];
    float* out = (float*)d_out;
    char* ws = (char*)d_ws;

    __bf16* wqkvT = (__bf16*)(ws + 0);          // [3072][1024]  6 MB
    __bf16* woT   = (__bf16*)(ws + 6291456);    // [1024][1024]  2 MB
    __bf16* w1T   = (__bf16*)(ws + 8388608);    // [4096][1024]  8 MB
    __bf16* w2T   = (__bf16*)(ws + 16777216);   // [1024][4096]  8 MB
    float*  bqkv  = (float*)(ws + 25165824);    // [3072]
    __bf16* hb    = (__bf16*)(ws + 25178112);   // [8192][1024] 16 MB
    __bf16* qkb   = (__bf16*)(ws + 41955328);   // [8192][2048] 32 MB
    __bf16* vTb   = (__bf16*)(ws + 75509760);   // [8*16*64][1024] 16 MB
    __bf16* ctxb  = (__bf16*)(ws + 92286976);   // [8192][1024] 16 MB
    __bf16* ff1b  = qkb;                        // [8192][4096] 64 MB overlays

    transpose_convert<<<dim3(32, 32),  256, 0, stream>>>(wq, wqkvT,               1024, 1024);
    transpose_convert<<<dim3(32, 32),  256, 0, stream>>>(wk, wqkvT + 1024 * 1024, 1024, 1024);
    transpose_convert<<<dim3(32, 32),  256, 0, stream>>>(wv, wqkvT + 2048 * 1024, 1024, 1024);
    transpose_convert<<<dim3(32, 32),  256, 0, stream>>>(wo, woT,                 1024, 1024);
    transpose_convert<<<dim3(128, 32), 256, 0, stream>>>(w1, w1T,                 1024, 4096);
    transpose_convert<<<dim3(32, 128), 256, 0, stream>>>(w2, w2T,                 4096, 1024);
    concat3<<<4, 256, 0, stream>>>(bq, bk, bv, bqkv, 1024);

    // LN1 -> hb
    ln_to_bf16<<<8192, 256, 0, stream>>>(x, ln1g, ln1b, hb);
    // fused QKV (256^2): Q(prescaled)|K -> qkb, V -> vTb transposed
    gemm256<4><<<384, 512, 0, stream>>>(hb, wqkvT, bqkv, qkb, vTb, 8192, 3072, 1024, 32);
    // attention
    attn_kernel<<<dim3(16, 16, 8), 256, 0, stream>>>(qkb, vTb, mask, ctxb);
    // output proj + residual -> d_out (fp32)
    gemm256x128<<<256, 512, 0, stream>>>(ctxb, woT, bo, x, out, 8192, 1024, 1024, 32);
    // LN2 -> hb
    ln_to_bf16<<<8192, 256, 0, stream>>>(out, ln2g, ln2b, hb);
    // FFN1 (256^2, relu)
    gemm256<1><<<512, 512, 0, stream>>>(hb, w1T, b1, ff1b, nullptr, 8192, 4096, 1024, 32);
    // FFN2 + residual
    gemm256x128<<<256, 512, 0, stream>>>(ff1b, w2T, b2, out, out, 8192, 1024, 4096, 32);
}

// Round 5
// 394.624 us; speedup vs baseline: 1.3360x; 1.0251x over previous
//
#include <hip/hip_runtime.h>
#include <hip/hip_bf16.h>

typedef __attribute__((ext_vector_type(8))) __bf16 bf16x8;
typedef __attribute__((ext_vector_type(4))) __bf16 bf16x4;
typedef __attribute__((ext_vector_type(4))) float  f32x4;

__device__ __forceinline__ void gload_lds16(const __bf16* g, __bf16* l) {
    __builtin_amdgcn_global_load_lds(
        (const __attribute__((address_space(1))) void*)g,
        (__attribute__((address_space(3))) void*)l, 16, 0, 0);
}

// ---------------------------------------------------------------------------
// All weight transposes (fp32 [K][N] -> bf16 [N][K]) in ONE launch.
// blocks 0..4095: wq,wk,wv,wo (1024x1024); 4096..8191: w1; 8192..12287: w2.
// ---------------------------------------------------------------------------
__global__ __launch_bounds__(256) void transpose_all(
    const float* __restrict__ wq, const float* __restrict__ wk,
    const float* __restrict__ wv, const float* __restrict__ wo,
    const float* __restrict__ w1, const float* __restrict__ w2,
    __bf16* __restrict__ wqkvT, __bf16* __restrict__ woT,
    __bf16* __restrict__ w1T, __bf16* __restrict__ w2T) {
    __shared__ float t[32][33];
    const int bid = blockIdx.x;
    const float* in; __bf16* out; int K, N, nb, kb;
    if (bid < 4096) {
        const int which = bid >> 10, tt = bid & 1023;
        K = 1024; N = 1024;
        in  = which == 0 ? wq : which == 1 ? wk : which == 2 ? wv : wo;
        out = which == 3 ? woT : wqkvT + (size_t)which * 1048576;
        nb = (tt & 31) * 32; kb = (tt >> 5) * 32;
    } else if (bid < 8192) {
        const int tt = bid - 4096;
        in = w1; out = w1T; K = 1024; N = 4096;
        nb = (tt & 127) * 32; kb = (tt >> 7) * 32;
    } else {
        const int tt = bid - 8192;
        in = w2; out = w2T; K = 4096; N = 1024;
        nb = (tt & 31) * 32; kb = (tt >> 5) * 32;
    }
    const int tx = threadIdx.x & 31, ty = threadIdx.x >> 5;
#pragma unroll
    for (int i = 0; i < 32; i += 8)
        t[ty + i][tx] = in[(size_t)(kb + ty + i) * N + nb + tx];
    __syncthreads();
#pragma unroll
    for (int i = 0; i < 32; i += 8)
        out[(size_t)(nb + ty + i) * K + kb + tx] = (__bf16)t[tx][ty + i];
}

__global__ void concat3(const float* __restrict__ a, const float* __restrict__ b,
                        const float* __restrict__ c, float* __restrict__ o, int n) {
    int i = blockIdx.x * 256 + threadIdx.x;
    if (i < n) { o[i] = a[i]; o[n + i] = b[i]; o[2 * n + i] = c[i]; }
}

// ---------------------------------------------------------------------------
// LayerNorm over D=1024, one block per row, fp32 in -> bf16 out
// ---------------------------------------------------------------------------
__global__ __launch_bounds__(256) void ln_to_bf16(const float* __restrict__ x,
                                                  const float* __restrict__ g,
                                                  const float* __restrict__ bb,
                                                  __bf16* __restrict__ out) {
    const int row = blockIdx.x, t = threadIdx.x;
    const float4 v = ((const float4*)(x + (size_t)row * 1024))[t];
    float s  = v.x + v.y + v.z + v.w;
    float ss = v.x * v.x + v.y * v.y + v.z * v.z + v.w * v.w;
#pragma unroll
    for (int off = 32; off; off >>= 1) {
        s  += __shfl_down(s, off);
        ss += __shfl_down(ss, off);
    }
    __shared__ float ps[4], pss[4];
    if ((t & 63) == 0) { ps[t >> 6] = s; pss[t >> 6] = ss; }
    __syncthreads();
    s  = ps[0] + ps[1] + ps[2] + ps[3];
    ss = pss[0] + pss[1] + pss[2] + pss[3];
    const float mu   = s * (1.0f / 1024.0f);
    const float var  = ss * (1.0f / 1024.0f) - mu * mu;
    const float rinv = rsqrtf(var + 1e-5f);
    const float4 gv = ((const float4*)g)[t];
    const float4 bv = ((const float4*)bb)[t];
    bf16x4 o;
    o[0] = (__bf16)((v.x - mu) * rinv * gv.x + bv.x);
    o[1] = (__bf16)((v.y - mu) * rinv * gv.y + bv.y);
    o[2] = (__bf16)((v.z - mu) * rinv * gv.z + bv.z);
    o[3] = (__bf16)((v.w - mu) * rinv * gv.w + bv.w);
    *(bf16x4*)(out + (size_t)row * 1024 + 4 * t) = o;
}

// ---------------------------------------------------------------------------
// 256x256 8-phase GEMM (FFN1). 8 waves (2M x 4N), per-wave 128x64. BK=64 as
// 2 sub-tiles of 32; ring of 4 LDS sub-buffers; counted vmcnt(8); swizzle.
// MODE 1: relu bf16 out.
// ---------------------------------------------------------------------------
template <int MODE>
__global__ __launch_bounds__(512, 2) void gemm256(const __bf16* __restrict__ A,
                                                  const __bf16* __restrict__ BT,
                                                  const float* __restrict__ bias,
                                                  __bf16* __restrict__ outp,
                                                  int M, int N, int K, int NMB) {
    __shared__ __align__(16) __bf16 lds[65536];
    const int nwg = gridDim.x;
    const int bid = blockIdx.x;
    const int wgid = (bid & 7) * (nwg >> 3) + (bid >> 3);
    const int bm = (wgid % NMB) * 256, bn = (wgid / NMB) * 256;
    const int tid = threadIdx.x, l = tid & 63, w = tid >> 6;
    const int wm = (w >> 2) * 128, wn = (w & 3) * 64;
    const int lg = l >> 4, lm = l & 15;
    const int NT = K >> 6;

    const __bf16* gsrc[4];
    int ldst[4];
#pragma unroll
    for (int j = 0; j < 4; ++j) {
        const unsigned X = (unsigned)(((j & 1) << 13) + (w << 10) + l * 16);
        const unsigned L = X ^ (((X >> 7) & 7u) << 4);
        const int row = L >> 6, col = (L & 63) >> 1;
        gsrc[j] = (j < 2 ? A + (size_t)(bm + row) * K : BT + (size_t)(bn + row) * K) + col;
        ldst[j] = ((j < 2 ? 0 : 16384) + ((j & 1) << 13) + (w << 10)) >> 1;
    }
    int aoff[2][4], boff[4];
#pragma unroll
    for (int mh = 0; mh < 2; ++mh)
#pragma unroll
        for (int fr = 0; fr < 4; ++fr) {
            const unsigned Lb = (unsigned)(wm + mh * 64 + fr * 16 + lm) * 64 + lg * 16;
            aoff[mh][fr] = (int)(Lb ^ (((Lb >> 7) & 7u) << 4)) >> 1;
        }
#pragma unroll
    for (int n = 0; n < 4; ++n) {
        const unsigned Lb = (unsigned)(wn + n * 16 + lm) * 64 + lg * 16;
        boff[n] = (int)(16384u + (Lb ^ (((Lb >> 7) & 7u) << 4))) >> 1;
    }

    f32x4 acc[8][4];
#pragma unroll
    for (int m = 0; m < 8; ++m)
#pragma unroll
        for (int n = 0; n < 4; ++n) acc[m][n] = f32x4{0.f, 0.f, 0.f, 0.f};

#define ISSUE_SUB(u)                                                          \
    do {                                                                      \
        __bf16* sbp = lds + (((u) & 3) << 14);                                \
        const int go = (u) << 5;                                              \
        _Pragma("unroll")                                                     \
        for (int j = 0; j < 4; ++j) gload_lds16(gsrc[j] + go, sbp + ldst[j]); \
    } while (0)

#define MFMA16(MH, BREG)                                                      \
    do {                                                                      \
        __builtin_amdgcn_s_setprio(1);                                        \
        _Pragma("unroll")                                                     \
        for (int i = 0; i < 4; ++i)                                           \
            _Pragma("unroll")                                                 \
            for (int n = 0; n < 4; ++n)                                       \
                acc[(MH)*4 + i][n] = __builtin_amdgcn_mfma_f32_16x16x32_bf16( \
                    af[i], BREG[n], acc[(MH)*4 + i][n], 0, 0, 0);             \
        __builtin_amdgcn_s_setprio(0);                                        \
    } while (0)

    ISSUE_SUB(0); ISSUE_SUB(1); ISSUE_SUB(2); ISSUE_SUB(3);
    asm volatile("s_waitcnt vmcnt(8)" ::: "memory");
    __builtin_amdgcn_s_barrier();

    for (int t = 0; t < NT; ++t) {
        const int sa = ((2 * t) & 3) << 14, sb = ((2 * t + 1) & 3) << 14;
        bf16x8 af[4], b0[4], b1[4];
#pragma unroll
        for (int fr = 0; fr < 4; ++fr) af[fr] = *(const bf16x8*)(lds + sa + aoff[0][fr]);
#pragma unroll
        for (int n = 0; n < 4; ++n) b0[n] = *(const bf16x8*)(lds + sa + boff[n]);
        asm volatile("" ::: "memory");
        __builtin_amdgcn_s_barrier();
        __builtin_amdgcn_sched_barrier(0);
        MFMA16(0, b0);
        __builtin_amdgcn_sched_barrier(0);
        __builtin_amdgcn_s_barrier();
#pragma unroll
        for (int fr = 0; fr < 4; ++fr) af[fr] = *(const bf16x8*)(lds + sa + aoff[1][fr]);
        asm volatile("" ::: "memory");
        __builtin_amdgcn_s_barrier();
        __builtin_amdgcn_sched_barrier(0);
        MFMA16(1, b0);
        __builtin_amdgcn_sched_barrier(0);
        __builtin_amdgcn_s_barrier();
        if (t < NT - 2) ISSUE_SUB(2 * t + 4);
#pragma unroll
        for (int fr = 0; fr < 4; ++fr) af[fr] = *(const bf16x8*)(lds + sb + aoff[0][fr]);
#pragma unroll
        for (int n = 0; n < 4; ++n) b1[n] = *(const bf16x8*)(lds + sb + boff[n]);
        asm volatile("" ::: "memory");
        __builtin_amdgcn_s_barrier();
        __builtin_amdgcn_sched_barrier(0);
        MFMA16(0, b1);
        __builtin_amdgcn_sched_barrier(0);
        __builtin_amdgcn_s_barrier();
#pragma unroll
        for (int fr = 0; fr < 4; ++fr) af[fr] = *(const bf16x8*)(lds + sb + aoff[1][fr]);
        asm volatile("" ::: "memory");
        __builtin_amdgcn_s_barrier();
        __builtin_amdgcn_sched_barrier(0);
        MFMA16(1, b1);
        __builtin_amdgcn_sched_barrier(0);
        __builtin_amdgcn_s_barrier();
        if (t < NT - 2) {
            ISSUE_SUB(2 * t + 5);
            asm volatile("s_waitcnt vmcnt(8)" ::: "memory");
        } else if (t == NT - 2) {
            asm volatile("s_waitcnt vmcnt(0)" ::: "memory");
        }
        __builtin_amdgcn_s_barrier();
    }
#undef ISSUE_SUB
#undef MFMA16

#pragma unroll
    for (int m = 0; m < 8; ++m) {
        const int row = bm + wm + (m >> 2) * 64 + (m & 3) * 16 + lg * 4;
#pragma unroll
        for (int n = 0; n < 4; ++n) {
            const int col = bn + wn + n * 16 + lm;
            const float bvv = bias[col];
#pragma unroll
            for (int r = 0; r < 4; ++r) {
                const float v = acc[m][n][r] + bvv;
                outp[(size_t)(row + r) * N + col] =
                    (MODE == 1) ? (__bf16)fmaxf(v, 0.f) : (__bf16)v;
            }
        }
    }
}

// ---------------------------------------------------------------------------
// 256x128 8-phase GEMM, f32 out + residual (proj / FFN2, N=1024).
// 8 waves (4M x 2N), per-wave 64x64. Ring of 4 x 12288-elem sub-buffers.
// ---------------------------------------------------------------------------
__global__ __launch_bounds__(512, 2) void gemm256x128(const __bf16* __restrict__ A,
                                                      const __bf16* __restrict__ BT,
                                                      const float* __restrict__ bias,
                                                      const float* __restrict__ resid,
                                                      float* __restrict__ outp,
                                                      int M, int N, int K, int NMB) {
    __shared__ __align__(16) __bf16 lds[49152];
    const int nwg = gridDim.x;
    const int bid = blockIdx.x;
    const int wgid = (bid & 7) * (nwg >> 3) + (bid >> 3);
    const int bm = (wgid % NMB) * 256, bn = (wgid / NMB) * 128;
    const int tid = threadIdx.x, l = tid & 63, w = tid >> 6;
    const int wm = (w >> 1) * 64, wn = (w & 1) * 64;
    const int lg = l >> 4, lm = l & 15;
    const int NT = K >> 6;

    const __bf16* gsrc[3];
    int ldst[3];
#pragma unroll
    for (int j = 0; j < 3; ++j) {
        const unsigned X = (unsigned)((j == 1 ? 8192 : 0) + tid * 16);
        const unsigned L = X ^ (((X >> 7) & 7u) << 4);
        const int row = L >> 6, col = (L & 63) >> 1;
        gsrc[j] = (j < 2 ? A + (size_t)(bm + row) * K : BT + (size_t)(bn + row) * K) + col;
        ldst[j] = ((j < 2 ? (j << 13) : 16384) + (w << 10)) >> 1;
    }
    int aoff[2][2], boff[4];
#pragma unroll
    for (int mh = 0; mh < 2; ++mh)
#pragma unroll
        for (int fr = 0; fr < 2; ++fr) {
            const unsigned Lb = (unsigned)(wm + mh * 32 + fr * 16 + lm) * 64 + lg * 16;
            aoff[mh][fr] = (int)(Lb ^ (((Lb >> 7) & 7u) << 4)) >> 1;
        }
#pragma unroll
    for (int n = 0; n < 4; ++n) {
        const unsigned Lb = (unsigned)(wn + n * 16 + lm) * 64 + lg * 16;
        boff[n] = (int)(16384u + (Lb ^ (((Lb >> 7) & 7u) << 4))) >> 1;
    }

    f32x4 acc[4][4];
#pragma unroll
    for (int m = 0; m < 4; ++m)
#pragma unroll
        for (int n = 0; n < 4; ++n) acc[m][n] = f32x4{0.f, 0.f, 0.f, 0.f};

#define ISSUE_SUB(u)                                                          \
    do {                                                                      \
        __bf16* sbp = lds + ((u) & 3) * 12288;                                \
        const int go = (u) << 5;                                              \
        _Pragma("unroll")                                                     \
        for (int j = 0; j < 3; ++j) gload_lds16(gsrc[j] + go, sbp + ldst[j]); \
    } while (0)

#define MFMA8(MH, BREG)                                                       \
    do {                                                                      \
        __builtin_amdgcn_s_setprio(1);                                        \
        _Pragma("unroll")                                                     \
        for (int i = 0; i < 2; ++i)                                           \
            _Pragma("unroll")                                                 \
            for (int n = 0; n < 4; ++n)                                       \
                acc[(MH)*2 + i][n] = __builtin_amdgcn_mfma_f32_16x16x32_bf16( \
                    af[i], BREG[n], acc[(MH)*2 + i][n], 0, 0, 0);             \
        __builtin_amdgcn_s_setprio(0);                                        \
    } while (0)

    ISSUE_SUB(0); ISSUE_SUB(1); ISSUE_SUB(2); ISSUE_SUB(3);
    asm volatile("s_waitcnt vmcnt(6)" ::: "memory");
    __builtin_amdgcn_s_barrier();

    for (int t = 0; t < NT; ++t) {
        const int sa = ((2 * t) & 3) * 12288, sb = ((2 * t + 1) & 3) * 12288;
        bf16x8 af[2], b0[4], b1[4];
#pragma unroll
        for (int fr = 0; fr < 2; ++fr) af[fr] = *(const bf16x8*)(lds + sa + aoff[0][fr]);
#pragma unroll
        for (int n = 0; n < 4; ++n) b0[n] = *(const bf16x8*)(lds + sa + boff[n]);
        asm volatile("" ::: "memory");
        __builtin_amdgcn_s_barrier();
        __builtin_amdgcn_sched_barrier(0);
        MFMA8(0, b0);
        __builtin_amdgcn_sched_barrier(0);
        __builtin_amdgcn_s_barrier();
#pragma unroll
        for (int fr = 0; fr < 2; ++fr) af[fr] = *(const bf16x8*)(lds + sa + aoff[1][fr]);
        asm volatile("" ::: "memory");
        __builtin_amdgcn_s_barrier();
        __builtin_amdgcn_sched_barrier(0);
        MFMA8(1, b0);
        __builtin_amdgcn_sched_barrier(0);
        __builtin_amdgcn_s_barrier();
        if (t < NT - 2) ISSUE_SUB(2 * t + 4);
#pragma unroll
        for (int fr = 0; fr < 2; ++fr) af[fr] = *(const bf16x8*)(lds + sb + aoff[0][fr]);
#pragma unroll
        for (int n = 0; n < 4; ++n) b1[n] = *(const bf16x8*)(lds + sb + boff[n]);
        asm volatile("" ::: "memory");
        __builtin_amdgcn_s_barrier();
        __builtin_amdgcn_sched_barrier(0);
        MFMA8(0, b1);
        __builtin_amdgcn_sched_barrier(0);
        __builtin_amdgcn_s_barrier();
#pragma unroll
        for (int fr = 0; fr < 2; ++fr) af[fr] = *(const bf16x8*)(lds + sb + aoff[1][fr]);
        asm volatile("" ::: "memory");
        __builtin_amdgcn_s_barrier();
        __builtin_amdgcn_sched_barrier(0);
        MFMA8(1, b1);
        __builtin_amdgcn_sched_barrier(0);
        __builtin_amdgcn_s_barrier();
        if (t < NT - 2) {
            ISSUE_SUB(2 * t + 5);
            asm volatile("s_waitcnt vmcnt(6)" ::: "memory");
        } else if (t == NT - 2) {
            asm volatile("s_waitcnt vmcnt(0)" ::: "memory");
        }
        __builtin_amdgcn_s_barrier();
    }
#undef ISSUE_SUB
#undef MFMA8

#pragma unroll
    for (int m = 0; m < 4; ++m) {
        const int row = bm + wm + m * 16 + lg * 4;
#pragma unroll
        for (int n = 0; n < 4; ++n) {
            const int col = bn + wn + n * 16 + lm;
            const float bvv = bias[col];
#pragma unroll
            for (int r = 0; r < 4; ++r) {
                const size_t idx = (size_t)(row + r) * N + col;
                outp[idx] = resid[idx] + acc[m][n][r] + bvv;
            }
        }
    }
}

// ---------------------------------------------------------------------------
// 128x256 8-phase GEMM for fused QKV (768 wgs = exactly 3/CU at M=8192,N=3072)
// 8 waves (2M x 4N), per-wave 64x64. A: 1 load/thr/sub, B: 2 -> vmcnt(6).
// Epilogue: Q cols scaled by 0.125*log2e; K bf16 (ldc 2048); V transposed.
// ---------------------------------------------------------------------------
__global__ __launch_bounds__(512, 2) void gemm_qkv(const __bf16* __restrict__ A,
                                                   const __bf16* __restrict__ BT,
                                                   const float* __restrict__ bias,
                                                   __bf16* __restrict__ outp,
                                                   __bf16* __restrict__ vTout,
                                                   int M, int N, int K, int NMB) {
    __shared__ __align__(16) __bf16 lds[49152];
    const int nwg = gridDim.x;
    const int bid = blockIdx.x;
    const int wgid = (bid & 7) * (nwg >> 3) + (bid >> 3);
    const int bm = (wgid % NMB) * 128, bn = (wgid / NMB) * 256;
    const int tid = threadIdx.x, l = tid & 63, w = tid >> 6;
    const int wm = (w >> 2) * 64, wn = (w & 3) * 64;
    const int lg = l >> 4, lm = l & 15;
    const int NT = K >> 6;

    // A region: 8192 B (128 rows x 64B); B region: 16384 B at byte base 8192
    const __bf16* gsrc[3];
    int ldst[3];
#pragma unroll
    for (int j = 0; j < 3; ++j) {
        const unsigned X = (unsigned)((j == 0 ? 0 : (j - 1) * 8192) + tid * 16);
        const unsigned L = X ^ (((X >> 7) & 7u) << 4);
        const int row = L >> 6, col = (L & 63) >> 1;
        gsrc[j] = (j == 0 ? A + (size_t)(bm + row) * K : BT + (size_t)(bn + row) * K) + col;
        ldst[j] = ((j == 0 ? 0 : 8192 + (j - 1) * 8192) + (w << 10)) >> 1;
    }
    int aoff[2][2], boff[4];
#pragma unroll
    for (int mh = 0; mh < 2; ++mh)
#pragma unroll
        for (int fr = 0; fr < 2; ++fr) {
            const unsigned Lb = (unsigned)(wm + mh * 32 + fr * 16 + lm) * 64 + lg * 16;
            aoff[mh][fr] = (int)(Lb ^ (((Lb >> 7) & 7u) << 4)) >> 1;
        }
#pragma unroll
    for (int n = 0; n < 4; ++n) {
        const unsigned Lb = (unsigned)(wn + n * 16 + lm) * 64 + lg * 16;
        boff[n] = (int)(8192u + (Lb ^ (((Lb >> 7) & 7u) << 4))) >> 1;
    }

    f32x4 acc[4][4];
#pragma unroll
    for (int m = 0; m < 4; ++m)
#pragma unroll
        for (int n = 0; n < 4; ++n) acc[m][n] = f32x4{0.f, 0.f, 0.f, 0.f};

#define ISSUE_SUB(u)                                                          \
    do {                                                                      \
        __bf16* sbp = lds + ((u) & 3) * 12288;                                \
        const int go = (u) << 5;                                              \
        _Pragma("unroll")                                                     \
        for (int j = 0; j < 3; ++j) gload_lds16(gsrc[j] + go, sbp + ldst[j]); \
    } while (0)

#define MFMA8(MH, BREG)                                                       \
    do {                                                                      \
        __builtin_amdgcn_s_setprio(1);                                        \
        _Pragma("unroll")                                                     \
        for (int i = 0; i < 2; ++i)                                           \
            _Pragma("unroll")                                                 \
            for (int n = 0; n < 4; ++n)                                       \
                acc[(MH)*2 + i][n] = __builtin_amdgcn_mfma_f32_16x16x32_bf16( \
                    af[i], BREG[n], acc[(MH)*2 + i][n], 0, 0, 0);             \
        __builtin_amdgcn_s_setprio(0);                                        \
    } while (0)

    ISSUE_SUB(0); ISSUE_SUB(1); ISSUE_SUB(2); ISSUE_SUB(3);
    asm volatile("s_waitcnt vmcnt(6)" ::: "memory");
    __builtin_amdgcn_s_barrier();

    for (int t = 0; t < NT; ++t) {
        const int sa = ((2 * t) & 3) * 12288, sb = ((2 * t + 1) & 3) * 12288;
        bf16x8 af[2], b0[4], b1[4];
#pragma unroll
        for (int fr = 0; fr < 2; ++fr) af[fr] = *(const bf16x8*)(lds + sa + aoff[0][fr]);
#pragma unroll
        for (int n = 0; n < 4; ++n) b0[n] = *(const bf16x8*)(lds + sa + boff[n]);
        asm volatile("" ::: "memory");
        __builtin_amdgcn_s_barrier();
        __builtin_amdgcn_sched_barrier(0);
        MFMA8(0, b0);
        __builtin_amdgcn_sched_barrier(0);
        __builtin_amdgcn_s_barrier();
#pragma unroll
        for (int fr = 0; fr < 2; ++fr) af[fr] = *(const bf16x8*)(lds + sa + aoff[1][fr]);
        asm volatile("" ::: "memory");
        __builtin_amdgcn_s_barrier();
        __builtin_amdgcn_sched_barrier(0);
        MFMA8(1, b0);
        __builtin_amdgcn_sched_barrier(0);
        __builtin_amdgcn_s_barrier();
        if (t < NT - 2) ISSUE_SUB(2 * t + 4);
#pragma unroll
        for (int fr = 0; fr < 2; ++fr) af[fr] = *(const bf16x8*)(lds + sb + aoff[0][fr]);
#pragma unroll
        for (int n = 0; n < 4; ++n) b1[n] = *(const bf16x8*)(lds + sb + boff[n]);
        asm volatile("" ::: "memory");
        __builtin_amdgcn_s_barrier();
        __builtin_amdgcn_sched_barrier(0);
        MFMA8(0, b1);
        __builtin_amdgcn_sched_barrier(0);
        __builtin_amdgcn_s_barrier();
#pragma unroll
        for (int fr = 0; fr < 2; ++fr) af[fr] = *(const bf16x8*)(lds + sb + aoff[1][fr]);
        asm volatile("" ::: "memory");
        __builtin_amdgcn_s_barrier();
        __builtin_amdgcn_sched_barrier(0);
        MFMA8(1, b1);
        __builtin_amdgcn_sched_barrier(0);
        __builtin_amdgcn_s_barrier();
        if (t < NT - 2) {
            ISSUE_SUB(2 * t + 5);
            asm volatile("s_waitcnt vmcnt(6)" ::: "memory");
        } else if (t == NT - 2) {
            asm volatile("s_waitcnt vmcnt(0)" ::: "memory");
        }
        __builtin_amdgcn_s_barrier();
    }
#undef ISSUE_SUB
#undef MFMA8

    const bool isQ = bn < 1024;
#pragma unroll
    for (int m = 0; m < 4; ++m) {
        const int row = bm + wm + m * 16 + lg * 4;
#pragma unroll
        for (int n = 0; n < 4; ++n) {
            const int col = bn + wn + n * 16 + lm;
            const float bvv = bias[col];
            if (bn >= 2048) {
                bf16x4 o;
#pragma unroll
                for (int r = 0; r < 4; ++r) o[r] = (__bf16)(acc[m][n][r] + bvv);
                *(bf16x4*)(vTout + (size_t)((row >> 10) * 1024 + (col - 2048)) * 1024 +
                           (row & 1023)) = o;
            } else {
#pragma unroll
                for (int r = 0; r < 4; ++r) {
                    float v = acc[m][n][r] + bvv;
                    if (isQ) v *= 0.18033688f;   // 1/8 * log2(e): exp2-domain softmax
                    outp[(size_t)(row + r) * 2048 + col] = (__bf16)v;
                }
            }
        }
    }
}

// ---------------------------------------------------------------------------
// Flash attention fwd, swapped-QK^T, exp2-domain softmax, async double-buffer.
// qk: [B*S][2048] bf16 (Q pre-scaled by 0.125*log2e | K). vT: [B*H*64][S].
// Grid (qt=8, h=16, b=8); 8 waves (512 thr); wave w owns q rows [w*16,w*16+16).
// ---------------------------------------------------------------------------
__global__ __launch_bounds__(512) void attn_kernel(const __bf16* __restrict__ qk,
                                                   const __bf16* __restrict__ vT,
                                                   const int* __restrict__ mask,
                                                   __bf16* __restrict__ ctx) {
    const int qt = blockIdx.x, h = blockIdx.y, b = blockIdx.z;
    const int tid = threadIdx.x, w = tid >> 6, l = tid & 63;
    const int lg = l >> 4, lm = l & 15;

    __shared__ __align__(16) __bf16 Ks[2][64][76];
    __shared__ __align__(16) __bf16 Vt[2][64][76];
    __shared__ __align__(16) __bf16 Ps[8][16][76];

    const int qrow = qt * 128 + w * 16 + lm;
    const __bf16* qp = qk + (size_t)(b * 1024 + qrow) * 2048 + h * 64 + lg * 8;
    bf16x8 aq[2];
    aq[0] = *(const bf16x8*)qp;
    aq[1] = *(const bf16x8*)(qp + 32);

    // staging: 512 threads cover one 64x64 tile with 1 uint4 each
    const int r0 = tid >> 3, cc0 = (tid & 7) * 8;
    const __bf16* kbase = qk + (size_t)(b * 1024 + r0) * 2048 + 1024 + h * 64 + cc0;
    const __bf16* vbase = vT + (size_t)(b * 1024 + h * 64 + r0) * 1024 + cc0;
    uint4 kreg, vreg;
#define ALOAD(kt)                                                      \
    do {                                                               \
        kreg = *(const uint4*)(kbase + (size_t)(kt) * 64 * 2048);      \
        vreg = *(const uint4*)(vbase + (kt) * 64);                     \
    } while (0)
#define AWRITE(bf)                                                     \
    do {                                                               \
        *(uint4*)&Ks[bf][r0][cc0] = kreg;                              \
        *(uint4*)&Vt[bf][r0][cc0] = vreg;                              \
    } while (0)

    ALOAD(0); AWRITE(0); ALOAD(1);
    __syncthreads();

    const int* mbase = mask + b * 1024;
    float mrun = -1e30f, lsum = 0.f;
    f32x4 oacc[4];
#pragma unroll
    for (int n = 0; n < 4; ++n) oacc[n] = f32x4{0.f, 0.f, 0.f, 0.f};

    for (int kt = 0; kt < 16; ++kt) {
        const int cur = kt & 1;
        // S^T = K Q^T : sacc[n][r] = S[key = n*16+lg*4+r][q = lm] * log2e
        f32x4 sacc[4];
        int4 mk4[4];
#pragma unroll
        for (int n = 0; n < 4; ++n) {
            mk4[n] = *(const int4*)(mbase + kt * 64 + n * 16 + lg * 4);
            sacc[n] = f32x4{0.f, 0.f, 0.f, 0.f};
#pragma unroll
            for (int kk = 0; kk < 2; ++kk) {
                bf16x8 bk = *(const bf16x8*)&Ks[cur][n * 16 + lm][lg * 8 + kk * 32];
                sacc[n] = __builtin_amdgcn_mfma_f32_16x16x32_bf16(bk, aq[kk], sacc[n], 0, 0, 0);
            }
        }
        float p[4][4], mn[4];
#pragma unroll
        for (int n = 0; n < 4; ++n) {
            p[n][0] = mk4[n].x ? sacc[n][0] : -1e9f;
            p[n][1] = mk4[n].y ? sacc[n][1] : -1e9f;
            p[n][2] = mk4[n].z ? sacc[n][2] : -1e9f;
            p[n][3] = mk4[n].w ? sacc[n][3] : -1e9f;
            mn[n] = fmaxf(fmaxf(p[n][0], p[n][1]), fmaxf(p[n][2], p[n][3]));
        }
        float mloc = fmaxf(fmaxf(mn[0], mn[1]), fmaxf(mn[2], mn[3]));
        mloc = fmaxf(mloc, __shfl_xor(mloc, 16));
        mloc = fmaxf(mloc, __shfl_xor(mloc, 32));
        const float pm = fmaxf(mrun, mloc);
        if (!__all(pm - mrun <= 11.5f)) {        // defer-max (T13), log2 domain
            const float sc = exp2f(mrun - pm);
            mrun = pm;
            lsum *= sc;
            float scr[4];
#pragma unroll
            for (int r = 0; r < 4; ++r) scr[r] = __shfl(sc, lg * 4 + r);
#pragma unroll
            for (int n = 0; n < 4; ++n)
#pragma unroll
                for (int r = 0; r < 4; ++r) oacc[n][r] *= scr[r];
        }
        float rsn[4];
#pragma unroll
        for (int n = 0; n < 4; ++n) {
#pragma unroll
            for (int r = 0; r < 4; ++r) p[n][r] = exp2f(p[n][r] - mrun);
            rsn[n] = (p[n][0] + p[n][1]) + (p[n][2] + p[n][3]);
        }
        float rs = (rsn[0] + rsn[1]) + (rsn[2] + rsn[3]);
        rs += __shfl_xor(rs, 16);
        rs += __shfl_xor(rs, 32);
        lsum += rs;
        // P[q=lm][key] -> per-wave LDS, b64 writes
#pragma unroll
        for (int n = 0; n < 4; ++n) {
            bf16x4 pb;
#pragma unroll
            for (int r = 0; r < 4; ++r) pb[r] = (__bf16)p[n][r];
            *(bf16x4*)&Ps[w][lm][n * 16 + lg * 4] = pb;
        }
        bf16x8 ap[2];
        ap[0] = *(const bf16x8*)&Ps[w][lm][lg * 8];
        ap[1] = *(const bf16x8*)&Ps[w][lm][lg * 8 + 32];
#pragma unroll
        for (int n = 0; n < 4; ++n)
#pragma unroll
            for (int kk = 0; kk < 2; ++kk) {
                bf16x8 bv = *(const bf16x8*)&Vt[cur][n * 16 + lm][lg * 8 + kk * 32];
                oacc[n] = __builtin_amdgcn_mfma_f32_16x16x32_bf16(ap[kk], bv, oacc[n], 0, 0, 0);
            }
        __syncthreads();                 // all waves done reading buf cur
        if (kt < 15) AWRITE(cur ^ 1);    // tile kt+1 (loaded last iter)
        if (kt < 14) ALOAD(kt + 2);      // prefetch tile kt+2
        __syncthreads();                 // writes visible for next iter
    }
#undef ALOAD
#undef AWRITE
    float lsr[4];
#pragma unroll
    for (int r = 0; r < 4; ++r) lsr[r] = __shfl(lsum, lg * 4 + r);
#pragma unroll
    for (int n = 0; n < 4; ++n)
#pragma unroll
        for (int r = 0; r < 4; ++r) {
            const float val = oacc[n][r] / lsr[r];
            const int row = qt * 128 + w * 16 + lg * 4 + r;
            ctx[(size_t)(b * 1024 + row) * 1024 + h * 64 + n * 16 + lm] = (__bf16)val;
        }
}

// ---------------------------------------------------------------------------
extern "C" void kernel_launch(void* const* d_in, const int* in_sizes, int n_in,
                              void* d_out, int out_size, void* d_ws, size_t ws_size,
                              hipStream_t stream) {
    const float* x    = (const float*)d_in[0];
    const int*   mask = (const int*)d_in[1];
    const float* wq   = (const float*)d_in[2];
    const float* bq   = (const float*)d_in[3];
    const float* wk   = (const float*)d_in[4];
    const float* bk   = (const float*)d_in[5];
    const float* wv   = (const float*)d_in[6];
    const float* bv   = (const float*)d_in[7];
    const float* wo   = (const float*)d_in[8];
    const float* bo   = (const float*)d_in[9];
    const float* w1   = (const float*)d_in[10];
    const float* b1   = (const float*)d_in[11];
    const float* w2   = (const float*)d_in[12];
    const float* b2   = (const float*)d_in[13];
    const float* ln1g = (const float*)d_in[14];
    const float* ln1b = (const float*)d_in[15];
    const float* ln2g = (const float*)d_in[16];
    const float* ln2b = (const float*)d_in[17];
    float* out = (float*)d_out;
    char* ws = (char*)d_ws;

    __bf16* wqkvT = (__bf16*)(ws + 0);          // [3072][1024]  6 MB
    __bf16* woT   = (__bf16*)(ws + 6291456);    // [1024][1024]  2 MB
    __bf16* w1T   = (__bf16*)(ws + 8388608);    // [4096][1024]  8 MB
    __bf16* w2T   = (__bf16*)(ws + 16777216);   // [1024][4096]  8 MB
    float*  bqkv  = (float*)(ws + 25165824);    // [3072]
    __bf16* hb    = (__bf16*)(ws + 25178112);   // [8192][1024] 16 MB
    __bf16* qkb   = (__bf16*)(ws + 41955328);   // [8192][2048] 32 MB
    __bf16* vTb   = (__bf16*)(ws + 75509760);   // [8*16*64][1024] 16 MB
    __bf16* ctxb  = (__bf16*)(ws + 92286976);   // [8192][1024] 16 MB -> 109064192
    __bf16* ff1b  = qkb;                        // [8192][4096] 64 MB overlays

    transpose_all<<<12288, 256, 0, stream>>>(wq, wk, wv, wo, w1, w2,
                                             wqkvT, woT, w1T, w2T);
    concat3<<<4, 256, 0, stream>>>(bq, bk, bv, bqkv, 1024);

    // LN1 -> hb
    ln_to_bf16<<<8192, 256, 0, stream>>>(x, ln1g, ln1b, hb);
    // fused QKV (128x256, 768 wgs = 3/CU): Q(prescaled)|K -> qkb, V -> vTb^T
    gemm_qkv<<<768, 512, 0, stream>>>(hb, wqkvT, bqkv, qkb, vTb, 8192, 3072, 1024, 64);
    // attention
    attn_kernel<<<dim3(8, 16, 8), 512, 0, stream>>>(qkb, vTb, mask, ctxb);
    // output proj + residual -> d_out (fp32)
    gemm256x128<<<256, 512, 0, stream>>>(ctxb, woT, bo, x, out, 8192, 1024, 1024, 32);
    // LN2 -> hb
    ln_to_bf16<<<8192, 256, 0, stream>>>(out, ln2g, ln2b, hb);
    // FFN1 (256^2, relu)
    gemm256<1><<<512, 512, 0, stream>>>(hb, w1T, b1, ff1b, 8192, 4096, 1024, 32);
    // FFN2 + residual
    gemm256x128<<<256, 512, 0, stream>>>(ff1b, w2T, b2, out, out, 8192, 1024, 4096, 32);
}

// Round 6
// 379.220 us; speedup vs baseline: 1.3902x; 1.0406x over previous
//
#include <hip/hip_runtime.h>
#include <hip/hip_bf16.h>

typedef __attribute__((ext_vector_type(8))) __bf16 bf16x8;
typedef __attribute__((ext_vector_type(4))) __bf16 bf16x4;
typedef __attribute__((ext_vector_type(4))) float  f32x4;

__device__ __forceinline__ void gload_lds16(const __bf16* g, __bf16* l) {
    __builtin_amdgcn_global_load_lds(
        (const __attribute__((address_space(1))) void*)g,
        (__attribute__((address_space(3))) void*)l, 16, 0, 0);
}

// ---------------------------------------------------------------------------
// All weight transposes (fp32 [K][N] -> bf16 [N][K]) in ONE launch.
// ---------------------------------------------------------------------------
__global__ __launch_bounds__(256) void transpose_all(
    const float* __restrict__ wq, const float* __restrict__ wk,
    const float* __restrict__ wv, const float* __restrict__ wo,
    const float* __restrict__ w1, const float* __restrict__ w2,
    __bf16* __restrict__ wqkvT, __bf16* __restrict__ woT,
    __bf16* __restrict__ w1T, __bf16* __restrict__ w2T) {
    __shared__ float t[32][33];
    const int bid = blockIdx.x;
    const float* in; __bf16* out; int K, N, nb, kb;
    if (bid < 4096) {
        const int which = bid >> 10, tt = bid & 1023;
        K = 1024; N = 1024;
        in  = which == 0 ? wq : which == 1 ? wk : which == 2 ? wv : wo;
        out = which == 3 ? woT : wqkvT + (size_t)which * 1048576;
        nb = (tt & 31) * 32; kb = (tt >> 5) * 32;
    } else if (bid < 8192) {
        const int tt = bid - 4096;
        in = w1; out = w1T; K = 1024; N = 4096;
        nb = (tt & 127) * 32; kb = (tt >> 7) * 32;
    } else {
        const int tt = bid - 8192;
        in = w2; out = w2T; K = 4096; N = 1024;
        nb = (tt & 31) * 32; kb = (tt >> 5) * 32;
    }
    const int tx = threadIdx.x & 31, ty = threadIdx.x >> 5;
#pragma unroll
    for (int i = 0; i < 32; i += 8)
        t[ty + i][tx] = in[(size_t)(kb + ty + i) * N + nb + tx];
    __syncthreads();
#pragma unroll
    for (int i = 0; i < 32; i += 8)
        out[(size_t)(nb + ty + i) * K + kb + tx] = (__bf16)t[tx][ty + i];
}

__global__ void concat3(const float* __restrict__ a, const float* __restrict__ b,
                        const float* __restrict__ c, float* __restrict__ o, int n) {
    int i = blockIdx.x * 256 + threadIdx.x;
    if (i < n) { o[i] = a[i]; o[n + i] = b[i]; o[2 * n + i] = c[i]; }
}

// ---------------------------------------------------------------------------
// LayerNorm over D=1024, one block per row, fp32 in -> bf16 out
// ---------------------------------------------------------------------------
__global__ __launch_bounds__(256) void ln_to_bf16(const float* __restrict__ x,
                                                  const float* __restrict__ g,
                                                  const float* __restrict__ bb,
                                                  __bf16* __restrict__ out) {
    const int row = blockIdx.x, t = threadIdx.x;
    const float4 v = ((const float4*)(x + (size_t)row * 1024))[t];
    float s  = v.x + v.y + v.z + v.w;
    float ss = v.x * v.x + v.y * v.y + v.z * v.z + v.w * v.w;
#pragma unroll
    for (int off = 32; off; off >>= 1) {
        s  += __shfl_down(s, off);
        ss += __shfl_down(ss, off);
    }
    __shared__ float ps[4], pss[4];
    if ((t & 63) == 0) { ps[t >> 6] = s; pss[t >> 6] = ss; }
    __syncthreads();
    s  = ps[0] + ps[1] + ps[2] + ps[3];
    ss = pss[0] + pss[1] + pss[2] + pss[3];
    const float mu   = s * (1.0f / 1024.0f);
    const float var  = ss * (1.0f / 1024.0f) - mu * mu;
    const float rinv = rsqrtf(var + 1e-5f);
    const float4 gv = ((const float4*)g)[t];
    const float4 bv = ((const float4*)bb)[t];
    bf16x4 o;
    o[0] = (__bf16)((v.x - mu) * rinv * gv.x + bv.x);
    o[1] = (__bf16)((v.y - mu) * rinv * gv.y + bv.y);
    o[2] = (__bf16)((v.z - mu) * rinv * gv.z + bv.z);
    o[3] = (__bf16)((v.w - mu) * rinv * gv.w + bv.w);
    *(bf16x4*)(out + (size_t)row * 1024 + 4 * t) = o;
}

// ---------------------------------------------------------------------------
// 256x256 8-phase GEMM (FFN1). 2D per-XCD chunk: chunk covers MH bm x all bn.
// MODE 1: relu bf16 out.
// ---------------------------------------------------------------------------
template <int MODE>
__global__ __launch_bounds__(512, 2) void gemm256(const __bf16* __restrict__ A,
                                                  const __bf16* __restrict__ BT,
                                                  const float* __restrict__ bias,
                                                  __bf16* __restrict__ outp,
                                                  int M, int N, int K, int NMB) {
    __shared__ __align__(16) __bf16 lds[65536];
    const int bid = blockIdx.x;
    const int c8 = bid & 7, loc = bid >> 3;       // XCD id, chunk-local index
    const int MH = NMB >> 3;                      // bm rows per XCD chunk
    const int bm = (c8 * MH + loc % MH) * 256;
    const int bn = (loc / MH) * 256;
    const int tid = threadIdx.x, l = tid & 63, w = tid >> 6;
    const int wm = (w >> 2) * 128, wn = (w & 3) * 64;
    const int lg = l >> 4, lm = l & 15;
    const int NT = K >> 6;

    const __bf16* gsrc[4];
    int ldst[4];
#pragma unroll
    for (int j = 0; j < 4; ++j) {
        const unsigned X = (unsigned)(((j & 1) << 13) + (w << 10) + l * 16);
        const unsigned L = X ^ (((X >> 7) & 7u) << 4);
        const int row = L >> 6, col = (L & 63) >> 1;
        gsrc[j] = (j < 2 ? A + (size_t)(bm + row) * K : BT + (size_t)(bn + row) * K) + col;
        ldst[j] = ((j < 2 ? 0 : 16384) + ((j & 1) << 13) + (w << 10)) >> 1;
    }
    int aoff[2][4], boff[4];
#pragma unroll
    for (int mh = 0; mh < 2; ++mh)
#pragma unroll
        for (int fr = 0; fr < 4; ++fr) {
            const unsigned Lb = (unsigned)(wm + mh * 64 + fr * 16 + lm) * 64 + lg * 16;
            aoff[mh][fr] = (int)(Lb ^ (((Lb >> 7) & 7u) << 4)) >> 1;
        }
#pragma unroll
    for (int n = 0; n < 4; ++n) {
        const unsigned Lb = (unsigned)(wn + n * 16 + lm) * 64 + lg * 16;
        boff[n] = (int)(16384u + (Lb ^ (((Lb >> 7) & 7u) << 4))) >> 1;
    }

    f32x4 acc[8][4];
#pragma unroll
    for (int m = 0; m < 8; ++m)
#pragma unroll
        for (int n = 0; n < 4; ++n) acc[m][n] = f32x4{0.f, 0.f, 0.f, 0.f};

#define ISSUE_SUB(u)                                                          \
    do {                                                                      \
        __bf16* sbp = lds + (((u) & 3) << 14);                                \
        const int go = (u) << 5;                                              \
        _Pragma("unroll")                                                     \
        for (int j = 0; j < 4; ++j) gload_lds16(gsrc[j] + go, sbp + ldst[j]); \
    } while (0)

#define MFMA16(MH_, BREG)                                                     \
    do {                                                                      \
        __builtin_amdgcn_s_setprio(1);                                        \
        _Pragma("unroll")                                                     \
        for (int i = 0; i < 4; ++i)                                           \
            _Pragma("unroll")                                                 \
            for (int n = 0; n < 4; ++n)                                       \
                acc[(MH_)*4 + i][n] = __builtin_amdgcn_mfma_f32_16x16x32_bf16(\
                    af[i], BREG[n], acc[(MH_)*4 + i][n], 0, 0, 0);            \
        __builtin_amdgcn_s_setprio(0);                                        \
    } while (0)

    ISSUE_SUB(0); ISSUE_SUB(1); ISSUE_SUB(2); ISSUE_SUB(3);
    asm volatile("s_waitcnt vmcnt(8)" ::: "memory");
    __builtin_amdgcn_s_barrier();

    for (int t = 0; t < NT; ++t) {
        const int sa = ((2 * t) & 3) << 14, sb = ((2 * t + 1) & 3) << 14;
        bf16x8 af[4], b0[4], b1[4];
#pragma unroll
        for (int fr = 0; fr < 4; ++fr) af[fr] = *(const bf16x8*)(lds + sa + aoff[0][fr]);
#pragma unroll
        for (int n = 0; n < 4; ++n) b0[n] = *(const bf16x8*)(lds + sa + boff[n]);
        asm volatile("" ::: "memory");
        __builtin_amdgcn_s_barrier();
        __builtin_amdgcn_sched_barrier(0);
        MFMA16(0, b0);
        __builtin_amdgcn_sched_barrier(0);
        __builtin_amdgcn_s_barrier();
#pragma unroll
        for (int fr = 0; fr < 4; ++fr) af[fr] = *(const bf16x8*)(lds + sa + aoff[1][fr]);
        asm volatile("" ::: "memory");
        __builtin_amdgcn_s_barrier();
        __builtin_amdgcn_sched_barrier(0);
        MFMA16(1, b0);
        __builtin_amdgcn_sched_barrier(0);
        __builtin_amdgcn_s_barrier();
        if (t < NT - 2) ISSUE_SUB(2 * t + 4);
#pragma unroll
        for (int fr = 0; fr < 4; ++fr) af[fr] = *(const bf16x8*)(lds + sb + aoff[0][fr]);
#pragma unroll
        for (int n = 0; n < 4; ++n) b1[n] = *(const bf16x8*)(lds + sb + boff[n]);
        asm volatile("" ::: "memory");
        __builtin_amdgcn_s_barrier();
        __builtin_amdgcn_sched_barrier(0);
        MFMA16(0, b1);
        __builtin_amdgcn_sched_barrier(0);
        __builtin_amdgcn_s_barrier();
#pragma unroll
        for (int fr = 0; fr < 4; ++fr) af[fr] = *(const bf16x8*)(lds + sb + aoff[1][fr]);
        asm volatile("" ::: "memory");
        __builtin_amdgcn_s_barrier();
        __builtin_amdgcn_sched_barrier(0);
        MFMA16(1, b1);
        __builtin_amdgcn_sched_barrier(0);
        __builtin_amdgcn_s_barrier();
        if (t < NT - 2) {
            ISSUE_SUB(2 * t + 5);
            asm volatile("s_waitcnt vmcnt(8)" ::: "memory");
        } else if (t == NT - 2) {
            asm volatile("s_waitcnt vmcnt(0)" ::: "memory");
        }
        __builtin_amdgcn_s_barrier();
    }
#undef ISSUE_SUB
#undef MFMA16

#pragma unroll
    for (int m = 0; m < 8; ++m) {
        const int row = bm + wm + (m >> 2) * 64 + (m & 3) * 16 + lg * 4;
#pragma unroll
        for (int n = 0; n < 4; ++n) {
            const int col = bn + wn + n * 16 + lm;
            const float bvv = bias[col];
#pragma unroll
            for (int r = 0; r < 4; ++r) {
                const float v = acc[m][n][r] + bvv;
                outp[(size_t)(row + r) * N + col] =
                    (MODE == 1) ? (__bf16)fmaxf(v, 0.f) : (__bf16)v;
            }
        }
    }
}

// ---------------------------------------------------------------------------
// 256x128 8-phase GEMM, f32 out + residual (proj / FFN2, N=1024).
// ---------------------------------------------------------------------------
__global__ __launch_bounds__(512, 2) void gemm256x128(const __bf16* __restrict__ A,
                                                      const __bf16* __restrict__ BT,
                                                      const float* __restrict__ bias,
                                                      const float* __restrict__ resid,
                                                      float* __restrict__ outp,
                                                      int M, int N, int K, int NMB) {
    __shared__ __align__(16) __bf16 lds[49152];
    const int bid = blockIdx.x;
    const int c8 = bid & 7, loc = bid >> 3;
    const int MH = NMB >> 3;
    const int bm = (c8 * MH + loc % MH) * 256;
    const int bn = (loc / MH) * 128;
    const int tid = threadIdx.x, l = tid & 63, w = tid >> 6;
    const int wm = (w >> 1) * 64, wn = (w & 1) * 64;
    const int lg = l >> 4, lm = l & 15;
    const int NT = K >> 6;

    const __bf16* gsrc[3];
    int ldst[3];
#pragma unroll
    for (int j = 0; j < 3; ++j) {
        const unsigned X = (unsigned)((j == 1 ? 8192 : 0) + tid * 16);
        const unsigned L = X ^ (((X >> 7) & 7u) << 4);
        const int row = L >> 6, col = (L & 63) >> 1;
        gsrc[j] = (j < 2 ? A + (size_t)(bm + row) * K : BT + (size_t)(bn + row) * K) + col;
        ldst[j] = ((j < 2 ? (j << 13) : 16384) + (w << 10)) >> 1;
    }
    int aoff[2][2], boff[4];
#pragma unroll
    for (int mh = 0; mh < 2; ++mh)
#pragma unroll
        for (int fr = 0; fr < 2; ++fr) {
            const unsigned Lb = (unsigned)(wm + mh * 32 + fr * 16 + lm) * 64 + lg * 16;
            aoff[mh][fr] = (int)(Lb ^ (((Lb >> 7) & 7u) << 4)) >> 1;
        }
#pragma unroll
    for (int n = 0; n < 4; ++n) {
        const unsigned Lb = (unsigned)(wn + n * 16 + lm) * 64 + lg * 16;
        boff[n] = (int)(16384u + (Lb ^ (((Lb >> 7) & 7u) << 4))) >> 1;
    }

    f32x4 acc[4][4];
#pragma unroll
    for (int m = 0; m < 4; ++m)
#pragma unroll
        for (int n = 0; n < 4; ++n) acc[m][n] = f32x4{0.f, 0.f, 0.f, 0.f};

#define ISSUE_SUB(u)                                                          \
    do {                                                                      \
        __bf16* sbp = lds + ((u) & 3) * 12288;                                \
        const int go = (u) << 5;                                              \
        _Pragma("unroll")                                                     \
        for (int j = 0; j < 3; ++j) gload_lds16(gsrc[j] + go, sbp + ldst[j]); \
    } while (0)

#define MFMA8(MH_, BREG)                                                      \
    do {                                                                      \
        __builtin_amdgcn_s_setprio(1);                                        \
        _Pragma("unroll")                                                     \
        for (int i = 0; i < 2; ++i)                                           \
            _Pragma("unroll")                                                 \
            for (int n = 0; n < 4; ++n)                                       \
                acc[(MH_)*2 + i][n] = __builtin_amdgcn_mfma_f32_16x16x32_bf16(\
                    af[i], BREG[n], acc[(MH_)*2 + i][n], 0, 0, 0);            \
        __builtin_amdgcn_s_setprio(0);                                        \
    } while (0)

    ISSUE_SUB(0); ISSUE_SUB(1); ISSUE_SUB(2); ISSUE_SUB(3);
    asm volatile("s_waitcnt vmcnt(6)" ::: "memory");
    __builtin_amdgcn_s_barrier();

    for (int t = 0; t < NT; ++t) {
        const int sa = ((2 * t) & 3) * 12288, sb = ((2 * t + 1) & 3) * 12288;
        bf16x8 af[2], b0[4], b1[4];
#pragma unroll
        for (int fr = 0; fr < 2; ++fr) af[fr] = *(const bf16x8*)(lds + sa + aoff[0][fr]);
#pragma unroll
        for (int n = 0; n < 4; ++n) b0[n] = *(const bf16x8*)(lds + sa + boff[n]);
        asm volatile("" ::: "memory");
        __builtin_amdgcn_s_barrier();
        __builtin_amdgcn_sched_barrier(0);
        MFMA8(0, b0);
        __builtin_amdgcn_sched_barrier(0);
        __builtin_amdgcn_s_barrier();
#pragma unroll
        for (int fr = 0; fr < 2; ++fr) af[fr] = *(const bf16x8*)(lds + sa + aoff[1][fr]);
        asm volatile("" ::: "memory");
        __builtin_amdgcn_s_barrier();
        __builtin_amdgcn_sched_barrier(0);
        MFMA8(1, b0);
        __builtin_amdgcn_sched_barrier(0);
        __builtin_amdgcn_s_barrier();
        if (t < NT - 2) ISSUE_SUB(2 * t + 4);
#pragma unroll
        for (int fr = 0; fr < 2; ++fr) af[fr] = *(const bf16x8*)(lds + sb + aoff[0][fr]);
#pragma unroll
        for (int n = 0; n < 4; ++n) b1[n] = *(const bf16x8*)(lds + sb + boff[n]);
        asm volatile("" ::: "memory");
        __builtin_amdgcn_s_barrier();
        __builtin_amdgcn_sched_barrier(0);
        MFMA8(0, b1);
        __builtin_amdgcn_sched_barrier(0);
        __builtin_amdgcn_s_barrier();
#pragma unroll
        for (int fr = 0; fr < 2; ++fr) af[fr] = *(const bf16x8*)(lds + sb + aoff[1][fr]);
        asm volatile("" ::: "memory");
        __builtin_amdgcn_s_barrier();
        __builtin_amdgcn_sched_barrier(0);
        MFMA8(1, b1);
        __builtin_amdgcn_sched_barrier(0);
        __builtin_amdgcn_s_barrier();
        if (t < NT - 2) {
            ISSUE_SUB(2 * t + 5);
            asm volatile("s_waitcnt vmcnt(6)" ::: "memory");
        } else if (t == NT - 2) {
            asm volatile("s_waitcnt vmcnt(0)" ::: "memory");
        }
        __builtin_amdgcn_s_barrier();
    }
#undef ISSUE_SUB
#undef MFMA8

#pragma unroll
    for (int m = 0; m < 4; ++m) {
        const int row = bm + wm + m * 16 + lg * 4;
#pragma unroll
        for (int n = 0; n < 4; ++n) {
            const int col = bn + wn + n * 16 + lm;
            const float bvv = bias[col];
#pragma unroll
            for (int r = 0; r < 4; ++r) {
                const size_t idx = (size_t)(row + r) * N + col;
                outp[idx] = resid[idx] + acc[m][n][r] + bvv;
            }
        }
    }
}

// ---------------------------------------------------------------------------
// 128x256 8-phase GEMM for fused QKV (768 wgs = 3/CU).
// Epilogue: Q scaled by 0.125*log2e; K bf16 (ldc 2048); V transposed.
// ---------------------------------------------------------------------------
__global__ __launch_bounds__(512, 2) void gemm_qkv(const __bf16* __restrict__ A,
                                                   const __bf16* __restrict__ BT,
                                                   const float* __restrict__ bias,
                                                   __bf16* __restrict__ outp,
                                                   __bf16* __restrict__ vTout,
                                                   int M, int N, int K, int NMB) {
    __shared__ __align__(16) __bf16 lds[49152];
    const int bid = blockIdx.x;
    const int c8 = bid & 7, loc = bid >> 3;
    const int MH = NMB >> 3;
    const int bm = (c8 * MH + loc % MH) * 128;
    const int bn = (loc / MH) * 256;
    const int tid = threadIdx.x, l = tid & 63, w = tid >> 6;
    const int wm = (w >> 2) * 64, wn = (w & 3) * 64;
    const int lg = l >> 4, lm = l & 15;
    const int NT = K >> 6;

    const __bf16* gsrc[3];
    int ldst[3];
#pragma unroll
    for (int j = 0; j < 3; ++j) {
        const unsigned X = (unsigned)((j == 0 ? 0 : (j - 1) * 8192) + tid * 16);
        const unsigned L = X ^ (((X >> 7) & 7u) << 4);
        const int row = L >> 6, col = (L & 63) >> 1;
        gsrc[j] = (j == 0 ? A + (size_t)(bm + row) * K : BT + (size_t)(bn + row) * K) + col;
        ldst[j] = ((j == 0 ? 0 : 8192 + (j - 1) * 8192) + (w << 10)) >> 1;
    }
    int aoff[2][2], boff[4];
#pragma unroll
    for (int mh = 0; mh < 2; ++mh)
#pragma unroll
        for (int fr = 0; fr < 2; ++fr) {
            const unsigned Lb = (unsigned)(wm + mh * 32 + fr * 16 + lm) * 64 + lg * 16;
            aoff[mh][fr] = (int)(Lb ^ (((Lb >> 7) & 7u) << 4)) >> 1;
        }
#pragma unroll
    for (int n = 0; n < 4; ++n) {
        const unsigned Lb = (unsigned)(wn + n * 16 + lm) * 64 + lg * 16;
        boff[n] = (int)(8192u + (Lb ^ (((Lb >> 7) & 7u) << 4))) >> 1;
    }

    f32x4 acc[4][4];
#pragma unroll
    for (int m = 0; m < 4; ++m)
#pragma unroll
        for (int n = 0; n < 4; ++n) acc[m][n] = f32x4{0.f, 0.f, 0.f, 0.f};

#define ISSUE_SUB(u)                                                          \
    do {                                                                      \
        __bf16* sbp = lds + ((u) & 3) * 12288;                                \
        const int go = (u) << 5;                                              \
        _Pragma("unroll")                                                     \
        for (int j = 0; j < 3; ++j) gload_lds16(gsrc[j] + go, sbp + ldst[j]); \
    } while (0)

#define MFMA8(MH_, BREG)                                                      \
    do {                                                                      \
        __builtin_amdgcn_s_setprio(1);                                        \
        _Pragma("unroll")                                                     \
        for (int i = 0; i < 2; ++i)                                           \
            _Pragma("unroll")                                                 \
            for (int n = 0; n < 4; ++n)                                       \
                acc[(MH_)*2 + i][n] = __builtin_amdgcn_mfma_f32_16x16x32_bf16(\
                    af[i], BREG[n], acc[(MH_)*2 + i][n], 0, 0, 0);            \
        __builtin_amdgcn_s_setprio(0);                                        \
    } while (0)

    ISSUE_SUB(0); ISSUE_SUB(1); ISSUE_SUB(2); ISSUE_SUB(3);
    asm volatile("s_waitcnt vmcnt(6)" ::: "memory");
    __builtin_amdgcn_s_barrier();

    for (int t = 0; t < NT; ++t) {
        const int sa = ((2 * t) & 3) * 12288, sb = ((2 * t + 1) & 3) * 12288;
        bf16x8 af[2], b0[4], b1[4];
#pragma unroll
        for (int fr = 0; fr < 2; ++fr) af[fr] = *(const bf16x8*)(lds + sa + aoff[0][fr]);
#pragma unroll
        for (int n = 0; n < 4; ++n) b0[n] = *(const bf16x8*)(lds + sa + boff[n]);
        asm volatile("" ::: "memory");
        __builtin_amdgcn_s_barrier();
        __builtin_amdgcn_sched_barrier(0);
        MFMA8(0, b0);
        __builtin_amdgcn_sched_barrier(0);
        __builtin_amdgcn_s_barrier();
#pragma unroll
        for (int fr = 0; fr < 2; ++fr) af[fr] = *(const bf16x8*)(lds + sa + aoff[1][fr]);
        asm volatile("" ::: "memory");
        __builtin_amdgcn_s_barrier();
        __builtin_amdgcn_sched_barrier(0);
        MFMA8(1, b0);
        __builtin_amdgcn_sched_barrier(0);
        __builtin_amdgcn_s_barrier();
        if (t < NT - 2) ISSUE_SUB(2 * t + 4);
#pragma unroll
        for (int fr = 0; fr < 2; ++fr) af[fr] = *(const bf16x8*)(lds + sb + aoff[0][fr]);
#pragma unroll
        for (int n = 0; n < 4; ++n) b1[n] = *(const bf16x8*)(lds + sb + boff[n]);
        asm volatile("" ::: "memory");
        __builtin_amdgcn_s_barrier();
        __builtin_amdgcn_sched_barrier(0);
        MFMA8(0, b1);
        __builtin_amdgcn_sched_barrier(0);
        __builtin_amdgcn_s_barrier();
#pragma unroll
        for (int fr = 0; fr < 2; ++fr) af[fr] = *(const bf16x8*)(lds + sb + aoff[1][fr]);
        asm volatile("" ::: "memory");
        __builtin_amdgcn_s_barrier();
        __builtin_amdgcn_sched_barrier(0);
        MFMA8(1, b1);
        __builtin_amdgcn_sched_barrier(0);
        __builtin_amdgcn_s_barrier();
        if (t < NT - 2) {
            ISSUE_SUB(2 * t + 5);
            asm volatile("s_waitcnt vmcnt(6)" ::: "memory");
        } else if (t == NT - 2) {
            asm volatile("s_waitcnt vmcnt(0)" ::: "memory");
        }
        __builtin_amdgcn_s_barrier();
    }
#undef ISSUE_SUB
#undef MFMA8

    const bool isQ = bn < 1024;
#pragma unroll
    for (int m = 0; m < 4; ++m) {
        const int row = bm + wm + m * 16 + lg * 4;
#pragma unroll
        for (int n = 0; n < 4; ++n) {
            const int col = bn + wn + n * 16 + lm;
            const float bvv = bias[col];
            if (bn >= 2048) {
                bf16x4 o;
#pragma unroll
                for (int r = 0; r < 4; ++r) o[r] = (__bf16)(acc[m][n][r] + bvv);
                *(bf16x4*)(vTout + (size_t)((row >> 10) * 1024 + (col - 2048)) * 1024 +
                           (row & 1023)) = o;
            } else {
#pragma unroll
                for (int r = 0; r < 4; ++r) {
                    float v = acc[m][n][r] + bvv;
                    if (isQ) v *= 0.18033688f;   // 1/8 * log2(e): exp2-domain softmax
                    outp[(size_t)(row + r) * 2048 + col] = (__bf16)v;
                }
            }
        }
    }
}

// ---------------------------------------------------------------------------
// Flash attention fwd, swapped-QK^T, IN-REGISTER P (no Ps LDS), single barrier
// per tile, lane-local online-softmax stats, O[q][d] direct output.
// qk: [B*S][2048] bf16 (Q pre-scaled by 0.125*log2e | K). vT: [B*H*64][S].
// Grid (h=16, qt=8, b=8) -> bid%8 = head%8 (XCD-aligned KV reuse).
// ---------------------------------------------------------------------------
__global__ __launch_bounds__(512, 6) void attn_kernel(const __bf16* __restrict__ qk,
                                                      const __bf16* __restrict__ vT,
                                                      const int* __restrict__ mask,
                                                      __bf16* __restrict__ ctx) {
    const int h = blockIdx.x, qt = blockIdx.y, b = blockIdx.z;
    const int tid = threadIdx.x, w = tid >> 6, l = tid & 63;
    const int lg = l >> 4, lm = l & 15;

    __shared__ __align__(16) __bf16 Ks[2][64][76];
    __shared__ __align__(16) __bf16 Vt[2][64][76];

    const int qrow = qt * 128 + w * 16 + lm;
    const __bf16* qp = qk + (size_t)(b * 1024 + qrow) * 2048 + h * 64 + lg * 8;
    bf16x8 aq[2];
    aq[0] = *(const bf16x8*)qp;
    aq[1] = *(const bf16x8*)(qp + 32);

    // staging: 512 threads cover one 64x64 tile with 1 uint4 each
    const int r0 = tid >> 3, cc0 = (tid & 7) * 8;
    const __bf16* kbase = qk + (size_t)(b * 1024 + r0) * 2048 + 1024 + h * 64 + cc0;
    const __bf16* vbase = vT + (size_t)(b * 1024 + h * 64 + r0) * 1024 + cc0;
    uint4 kreg, vreg;
#define ALOAD(kt)                                                      \
    do {                                                               \
        kreg = *(const uint4*)(kbase + (size_t)(kt) * 64 * 2048);      \
        vreg = *(const uint4*)(vbase + (kt) * 64);                     \
    } while (0)
#define AWRITE(bf)                                                     \
    do {                                                               \
        *(uint4*)&Ks[bf][r0][cc0] = kreg;                              \
        *(uint4*)&Vt[bf][r0][cc0] = vreg;                              \
    } while (0)

    ALOAD(0); AWRITE(0); ALOAD(1);
    __syncthreads();

    const int* mbase = mask + b * 1024;
    const int srcA = ((lg & 1) << 5) + lm, srcB = srcA + 16;  // P-exchange lanes
    float mrun = -1e30f, lsum = 0.f;   // stats for query lm (lane-local)
    f32x4 oacc[4];                      // O[q=lm][d = nd*16 + lg*4 + r]
#pragma unroll
    for (int n = 0; n < 4; ++n) oacc[n] = f32x4{0.f, 0.f, 0.f, 0.f};

    for (int kt = 0; kt < 16; ++kt) {
        const int cur = kt & 1;
        if (kt < 15) AWRITE(cur ^ 1);    // tile kt+1 (regs from last iter)
        if (kt < 14) ALOAD(kt + 2);      // prefetch tile kt+2
        // S^T = K Q^T : sacc[n][r] = S[key = n*16+lg*4+r][q = lm] (log2 units)
        f32x4 sacc[4];
        int4 mk4[4];
#pragma unroll
        for (int n = 0; n < 4; ++n) {
            mk4[n] = *(const int4*)(mbase + kt * 64 + n * 16 + lg * 4);
            sacc[n] = f32x4{0.f, 0.f, 0.f, 0.f};
#pragma unroll
            for (int kk = 0; kk < 2; ++kk) {
                bf16x8 bk = *(const bf16x8*)&Ks[cur][n * 16 + lm][lg * 8 + kk * 32];
                sacc[n] = __builtin_amdgcn_mfma_f32_16x16x32_bf16(bk, aq[kk], sacc[n], 0, 0, 0);
            }
        }
        float p[4][4], mn[4];
#pragma unroll
        for (int n = 0; n < 4; ++n) {
            p[n][0] = mk4[n].x ? sacc[n][0] : -1e9f;
            p[n][1] = mk4[n].y ? sacc[n][1] : -1e9f;
            p[n][2] = mk4[n].z ? sacc[n][2] : -1e9f;
            p[n][3] = mk4[n].w ? sacc[n][3] : -1e9f;
            mn[n] = fmaxf(fmaxf(p[n][0], p[n][1]), fmaxf(p[n][2], p[n][3]));
        }
        float mloc = fmaxf(fmaxf(mn[0], mn[1]), fmaxf(mn[2], mn[3]));
        mloc = fmaxf(mloc, __shfl_xor(mloc, 16));
        mloc = fmaxf(mloc, __shfl_xor(mloc, 32));
        const float pm = fmaxf(mrun, mloc);
        if (!__all(pm - mrun <= 11.5f)) {        // defer-max (T13), log2 domain
            const float sc = exp2f(mrun - pm);
            mrun = pm;
            lsum *= sc;
#pragma unroll
            for (int n = 0; n < 4; ++n)
#pragma unroll
                for (int r = 0; r < 4; ++r) oacc[n][r] *= sc;   // lane-local!
        }
        float rsn[4];
#pragma unroll
        for (int n = 0; n < 4; ++n) {
#pragma unroll
            for (int r = 0; r < 4; ++r) p[n][r] = exp2f(p[n][r] - mrun);
            rsn[n] = (p[n][0] + p[n][1]) + (p[n][2] + p[n][3]);
        }
        float rs = (rsn[0] + rsn[1]) + (rsn[2] + rsn[3]);
        rs += __shfl_xor(rs, 16);
        rs += __shfl_xor(rs, 32);
        lsum += rs;
        // PV: O += V^T_frag(A) x P_frag(B); P B-frag built via cross-lane shfl
#pragma unroll
        for (int kk = 0; kk < 2; ++kk) {
            bf16x4 pb0, pb1;
#pragma unroll
            for (int r = 0; r < 4; ++r) {
                pb0[r] = (__bf16)p[2 * kk][r];
                pb1[r] = (__bf16)p[2 * kk + 1][r];
            }
            const uint2 u0 = *(const uint2*)&pb0;
            const uint2 u1 = *(const uint2*)&pb1;
            const int a0 = __shfl((int)u0.x, srcA), a1 = __shfl((int)u0.y, srcA);
            const int a2 = __shfl((int)u0.x, srcB), a3 = __shfl((int)u0.y, srcB);
            const int c0 = __shfl((int)u1.x, srcA), c1 = __shfl((int)u1.y, srcA);
            const int c2 = __shfl((int)u1.x, srcB), c3 = __shfl((int)u1.y, srcB);
            uint4 pf;
            const bool hi = (lg & 2) != 0;       // n' = kk*2 + (lg>>1)
            pf.x = hi ? c0 : a0;
            pf.y = hi ? c1 : a1;
            pf.z = hi ? c2 : a2;
            pf.w = hi ? c3 : a3;
            const bf16x8 pfrag = *(const bf16x8*)&pf;
#pragma unroll
            for (int nd = 0; nd < 4; ++nd) {
                bf16x8 vf = *(const bf16x8*)&Vt[cur][nd * 16 + lm][lg * 8 + kk * 32];
                oacc[nd] = __builtin_amdgcn_mfma_f32_16x16x32_bf16(vf, pfrag, oacc[nd], 0, 0, 0);
            }
        }
        __syncthreads();   // single barrier: read(cur) done, write(cur^1) visible
    }
#undef ALOAD
#undef AWRITE
    const float rinv = 1.0f / lsum;
#pragma unroll
    for (int nd = 0; nd < 4; ++nd) {
        bf16x4 o;
#pragma unroll
        for (int r = 0; r < 4; ++r) o[r] = (__bf16)(oacc[nd][r] * rinv);
        *(bf16x4*)(ctx + (size_t)(b * 1024 + qrow) * 1024 + h * 64 + nd * 16 + lg * 4) = o;
    }
}

// ---------------------------------------------------------------------------
extern "C" void kernel_launch(void* const* d_in, const int* in_sizes, int n_in,
                              void* d_out, int out_size, void* d_ws, size_t ws_size,
                              hipStream_t stream) {
    const float* x    = (const float*)d_in[0];
    const int*   mask = (const int*)d_in[1];
    const float* wq   = (const float*)d_in[2];
    const float* bq   = (const float*)d_in[3];
    const float* wk   = (const float*)d_in[4];
    const float* bk   = (const float*)d_in[5];
    const float* wv   = (const float*)d_in[6];
    const float* bv   = (const float*)d_in[7];
    const float* wo   = (const float*)d_in[8];
    const float* bo   = (const float*)d_in[9];
    const float* w1   = (const float*)d_in[10];
    const float* b1   = (const float*)d_in[11];
    const float* w2   = (const float*)d_in[12];
    const float* b2   = (const float*)d_in[13];
    const float* ln1g = (const float*)d_in[14];
    const float* ln1b = (const float*)d_in[15];
    const float* ln2g = (const float*)d_in[16];
    const float* ln2b = (const float*)d_in[17];
    float* out = (float*)d_out;
    char* ws = (char*)d_ws;

    __bf16* wqkvT = (__bf16*)(ws + 0);          // [3072][1024]  6 MB
    __bf16* woT   = (__bf16*)(ws + 6291456);    // [1024][1024]  2 MB
    __bf16* w1T   = (__bf16*)(ws + 8388608);    // [4096][1024]  8 MB
    __bf16* w2T   = (__bf16*)(ws + 16777216);   // [1024][4096]  8 MB
    float*  bqkv  = (float*)(ws + 25165824);    // [3072]
    __bf16* hb    = (__bf16*)(ws + 25178112);   // [8192][1024] 16 MB
    __bf16* qkb   = (__bf16*)(ws + 41955328);   // [8192][2048] 32 MB
    __bf16* vTb   = (__bf16*)(ws + 75509760);   // [8*16*64][1024] 16 MB
    __bf16* ctxb  = (__bf16*)(ws + 92286976);   // [8192][1024] 16 MB -> 109064192
    __bf16* ff1b  = qkb;                        // [8192][4096] 64 MB overlays

    transpose_all<<<12288, 256, 0, stream>>>(wq, wk, wv, wo, w1, w2,
                                             wqkvT, woT, w1T, w2T);
    concat3<<<4, 256, 0, stream>>>(bq, bk, bv, bqkv, 1024);

    // LN1 -> hb
    ln_to_bf16<<<8192, 256, 0, stream>>>(x, ln1g, ln1b, hb);
    // fused QKV (128x256): Q(prescaled)|K -> qkb, V -> vTb^T
    gemm_qkv<<<768, 512, 0, stream>>>(hb, wqkvT, bqkv, qkb, vTb, 8192, 3072, 1024, 64);
    // attention (head-major grid for XCD-aligned KV reuse)
    attn_kernel<<<dim3(16, 8, 8), 512, 0, stream>>>(qkb, vTb, mask, ctxb);
    // output proj + residual -> d_out (fp32)
    gemm256x128<<<256, 512, 0, stream>>>(ctxb, woT, bo, x, out, 8192, 1024, 1024, 32);
    // LN2 -> hb
    ln_to_bf16<<<8192, 256, 0, stream>>>(out, ln2g, ln2b, hb);
    // FFN1 (256^2, relu)
    gemm256<1><<<512, 512, 0, stream>>>(hb, w1T, b1, ff1b, 8192, 4096, 1024, 32);
    // FFN2 + residual
    gemm256x128<<<256, 512, 0, stream>>>(ff1b, w2T, b2, out, out, 8192, 1024, 4096, 32);
}

// Round 7
// 368.632 us; speedup vs baseline: 1.4302x; 1.0287x over previous
//
#include <hip/hip_runtime.h>
#include <hip/hip_bf16.h>

typedef __attribute__((ext_vector_type(8))) __bf16 bf16x8;
typedef __attribute__((ext_vector_type(4))) __bf16 bf16x4;
typedef __attribute__((ext_vector_type(4))) float  f32x4;

__device__ __forceinline__ void gload_lds16(const __bf16* g, __bf16* l) {
    __builtin_amdgcn_global_load_lds(
        (const __attribute__((address_space(1))) void*)g,
        (__attribute__((address_space(3))) void*)l, 16, 0, 0);
}

// ---------------------------------------------------------------------------
// All weight transposes (fp32 [K][N] -> bf16 [N][K]) in ONE launch.
// ---------------------------------------------------------------------------
__global__ __launch_bounds__(256) void transpose_all(
    const float* __restrict__ wq, const float* __restrict__ wk,
    const float* __restrict__ wv, const float* __restrict__ wo,
    const float* __restrict__ w1, const float* __restrict__ w2,
    __bf16* __restrict__ wqkvT, __bf16* __restrict__ woT,
    __bf16* __restrict__ w1T, __bf16* __restrict__ w2T) {
    __shared__ float t[32][33];
    const int bid = blockIdx.x;
    const float* in; __bf16* out; int K, N, nb, kb;
    if (bid < 4096) {
        const int which = bid >> 10, tt = bid & 1023;
        K = 1024; N = 1024;
        in  = which == 0 ? wq : which == 1 ? wk : which == 2 ? wv : wo;
        out = which == 3 ? woT : wqkvT + (size_t)which * 1048576;
        nb = (tt & 31) * 32; kb = (tt >> 5) * 32;
    } else if (bid < 8192) {
        const int tt = bid - 4096;
        in = w1; out = w1T; K = 1024; N = 4096;
        nb = (tt & 127) * 32; kb = (tt >> 7) * 32;
    } else {
        const int tt = bid - 8192;
        in = w2; out = w2T; K = 4096; N = 1024;
        nb = (tt & 31) * 32; kb = (tt >> 5) * 32;
    }
    const int tx = threadIdx.x & 31, ty = threadIdx.x >> 5;
#pragma unroll
    for (int i = 0; i < 32; i += 8)
        t[ty + i][tx] = in[(size_t)(kb + ty + i) * N + nb + tx];
    __syncthreads();
#pragma unroll
    for (int i = 0; i < 32; i += 8)
        out[(size_t)(nb + ty + i) * K + kb + tx] = (__bf16)t[tx][ty + i];
}

__global__ void concat3(const float* __restrict__ a, const float* __restrict__ b,
                        const float* __restrict__ c, float* __restrict__ o, int n) {
    int i = blockIdx.x * 256 + threadIdx.x;
    if (i < n) { o[i] = a[i]; o[n + i] = b[i]; o[2 * n + i] = c[i]; }
}

// ---------------------------------------------------------------------------
// LayerNorm over D=1024, one block per row, fp32 in -> bf16 out
// ---------------------------------------------------------------------------
__global__ __launch_bounds__(256) void ln_to_bf16(const float* __restrict__ x,
                                                  const float* __restrict__ g,
                                                  const float* __restrict__ bb,
                                                  __bf16* __restrict__ out) {
    const int row = blockIdx.x, t = threadIdx.x;
    const float4 v = ((const float4*)(x + (size_t)row * 1024))[t];
    float s  = v.x + v.y + v.z + v.w;
    float ss = v.x * v.x + v.y * v.y + v.z * v.z + v.w * v.w;
#pragma unroll
    for (int off = 32; off; off >>= 1) {
        s  += __shfl_down(s, off);
        ss += __shfl_down(ss, off);
    }
    __shared__ float ps[4], pss[4];
    if ((t & 63) == 0) { ps[t >> 6] = s; pss[t >> 6] = ss; }
    __syncthreads();
    s  = ps[0] + ps[1] + ps[2] + ps[3];
    ss = pss[0] + pss[1] + pss[2] + pss[3];
    const float mu   = s * (1.0f / 1024.0f);
    const float var  = ss * (1.0f / 1024.0f) - mu * mu;
    const float rinv = rsqrtf(var + 1e-5f);
    const float4 gv = ((const float4*)g)[t];
    const float4 bv = ((const float4*)bb)[t];
    bf16x4 o;
    o[0] = (__bf16)((v.x - mu) * rinv * gv.x + bv.x);
    o[1] = (__bf16)((v.y - mu) * rinv * gv.y + bv.y);
    o[2] = (__bf16)((v.z - mu) * rinv * gv.z + bv.z);
    o[3] = (__bf16)((v.w - mu) * rinv * gv.w + bv.w);
    *(bf16x4*)(out + (size_t)row * 1024 + 4 * t) = o;
}

// ---------------------------------------------------------------------------
// 256x256 8-phase GEMM (FFN1). 2D per-XCD chunk. MODE 1: relu bf16 out.
// ---------------------------------------------------------------------------
template <int MODE>
__global__ __launch_bounds__(512, 2) void gemm256(const __bf16* __restrict__ A,
                                                  const __bf16* __restrict__ BT,
                                                  const float* __restrict__ bias,
                                                  __bf16* __restrict__ outp,
                                                  int M, int N, int K, int NMB) {
    __shared__ __align__(16) __bf16 lds[65536];
    const int bid = blockIdx.x;
    const int c8 = bid & 7, loc = bid >> 3;       // XCD id, chunk-local index
    const int MH = NMB >> 3;                      // bm rows per XCD chunk
    const int bm = (c8 * MH + loc % MH) * 256;
    const int bn = (loc / MH) * 256;
    const int tid = threadIdx.x, l = tid & 63, w = tid >> 6;
    const int wm = (w >> 2) * 128, wn = (w & 3) * 64;
    const int lg = l >> 4, lm = l & 15;
    const int NT = K >> 6;

    const __bf16* gsrc[4];
    int ldst[4];
#pragma unroll
    for (int j = 0; j < 4; ++j) {
        const unsigned X = (unsigned)(((j & 1) << 13) + (w << 10) + l * 16);
        const unsigned L = X ^ (((X >> 7) & 7u) << 4);
        const int row = L >> 6, col = (L & 63) >> 1;
        gsrc[j] = (j < 2 ? A + (size_t)(bm + row) * K : BT + (size_t)(bn + row) * K) + col;
        ldst[j] = ((j < 2 ? 0 : 16384) + ((j & 1) << 13) + (w << 10)) >> 1;
    }
    int aoff[2][4], boff[4];
#pragma unroll
    for (int mh = 0; mh < 2; ++mh)
#pragma unroll
        for (int fr = 0; fr < 4; ++fr) {
            const unsigned Lb = (unsigned)(wm + mh * 64 + fr * 16 + lm) * 64 + lg * 16;
            aoff[mh][fr] = (int)(Lb ^ (((Lb >> 7) & 7u) << 4)) >> 1;
        }
#pragma unroll
    for (int n = 0; n < 4; ++n) {
        const unsigned Lb = (unsigned)(wn + n * 16 + lm) * 64 + lg * 16;
        boff[n] = (int)(16384u + (Lb ^ (((Lb >> 7) & 7u) << 4))) >> 1;
    }

    f32x4 acc[8][4];
#pragma unroll
    for (int m = 0; m < 8; ++m)
#pragma unroll
        for (int n = 0; n < 4; ++n) acc[m][n] = f32x4{0.f, 0.f, 0.f, 0.f};

#define ISSUE_SUB(u)                                                          \
    do {                                                                      \
        __bf16* sbp = lds + (((u) & 3) << 14);                                \
        const int go = (u) << 5;                                              \
        _Pragma("unroll")                                                     \
        for (int j = 0; j < 4; ++j) gload_lds16(gsrc[j] + go, sbp + ldst[j]); \
    } while (0)

#define MFMA16(MH_, BREG)                                                     \
    do {                                                                      \
        __builtin_amdgcn_s_setprio(1);                                        \
        _Pragma("unroll")                                                     \
        for (int i = 0; i < 4; ++i)                                           \
            _Pragma("unroll")                                                 \
            for (int n = 0; n < 4; ++n)                                       \
                acc[(MH_)*4 + i][n] = __builtin_amdgcn_mfma_f32_16x16x32_bf16(\
                    af[i], BREG[n], acc[(MH_)*4 + i][n], 0, 0, 0);            \
        __builtin_amdgcn_s_setprio(0);                                        \
    } while (0)

    ISSUE_SUB(0); ISSUE_SUB(1); ISSUE_SUB(2); ISSUE_SUB(3);
    asm volatile("s_waitcnt vmcnt(8)" ::: "memory");
    __builtin_amdgcn_s_barrier();

    for (int t = 0; t < NT; ++t) {
        const int sa = ((2 * t) & 3) << 14, sb = ((2 * t + 1) & 3) << 14;
        bf16x8 af[4], b0[4], b1[4];
#pragma unroll
        for (int fr = 0; fr < 4; ++fr) af[fr] = *(const bf16x8*)(lds + sa + aoff[0][fr]);
#pragma unroll
        for (int n = 0; n < 4; ++n) b0[n] = *(const bf16x8*)(lds + sa + boff[n]);
        asm volatile("" ::: "memory");
        __builtin_amdgcn_s_barrier();
        __builtin_amdgcn_sched_barrier(0);
        MFMA16(0, b0);
        __builtin_amdgcn_sched_barrier(0);
        __builtin_amdgcn_s_barrier();
#pragma unroll
        for (int fr = 0; fr < 4; ++fr) af[fr] = *(const bf16x8*)(lds + sa + aoff[1][fr]);
        asm volatile("" ::: "memory");
        __builtin_amdgcn_s_barrier();
        __builtin_amdgcn_sched_barrier(0);
        MFMA16(1, b0);
        __builtin_amdgcn_sched_barrier(0);
        __builtin_amdgcn_s_barrier();
        if (t < NT - 2) ISSUE_SUB(2 * t + 4);
#pragma unroll
        for (int fr = 0; fr < 4; ++fr) af[fr] = *(const bf16x8*)(lds + sb + aoff[0][fr]);
#pragma unroll
        for (int n = 0; n < 4; ++n) b1[n] = *(const bf16x8*)(lds + sb + boff[n]);
        asm volatile("" ::: "memory");
        __builtin_amdgcn_s_barrier();
        __builtin_amdgcn_sched_barrier(0);
        MFMA16(0, b1);
        __builtin_amdgcn_sched_barrier(0);
        __builtin_amdgcn_s_barrier();
#pragma unroll
        for (int fr = 0; fr < 4; ++fr) af[fr] = *(const bf16x8*)(lds + sb + aoff[1][fr]);
        asm volatile("" ::: "memory");
        __builtin_amdgcn_s_barrier();
        __builtin_amdgcn_sched_barrier(0);
        MFMA16(1, b1);
        __builtin_amdgcn_sched_barrier(0);
        __builtin_amdgcn_s_barrier();
        if (t < NT - 2) {
            ISSUE_SUB(2 * t + 5);
            asm volatile("s_waitcnt vmcnt(8)" ::: "memory");
        } else if (t == NT - 2) {
            asm volatile("s_waitcnt vmcnt(0)" ::: "memory");
        }
        __builtin_amdgcn_s_barrier();
    }
#undef ISSUE_SUB
#undef MFMA16

#pragma unroll
    for (int m = 0; m < 8; ++m) {
        const int row = bm + wm + (m >> 2) * 64 + (m & 3) * 16 + lg * 4;
#pragma unroll
        for (int n = 0; n < 4; ++n) {
            const int col = bn + wn + n * 16 + lm;
            const float bvv = bias[col];
#pragma unroll
            for (int r = 0; r < 4; ++r) {
                const float v = acc[m][n][r] + bvv;
                outp[(size_t)(row + r) * N + col] =
                    (MODE == 1) ? (__bf16)fmaxf(v, 0.f) : (__bf16)v;
            }
        }
    }
}

// ---------------------------------------------------------------------------
// 256x128 8-phase GEMM, f32 out + residual (proj / FFN2, N=1024).
// ---------------------------------------------------------------------------
__global__ __launch_bounds__(512, 2) void gemm256x128(const __bf16* __restrict__ A,
                                                      const __bf16* __restrict__ BT,
                                                      const float* __restrict__ bias,
                                                      const float* __restrict__ resid,
                                                      float* __restrict__ outp,
                                                      int M, int N, int K, int NMB) {
    __shared__ __align__(16) __bf16 lds[49152];
    const int bid = blockIdx.x;
    const int c8 = bid & 7, loc = bid >> 3;
    const int MH = NMB >> 3;
    const int bm = (c8 * MH + loc % MH) * 256;
    const int bn = (loc / MH) * 128;
    const int tid = threadIdx.x, l = tid & 63, w = tid >> 6;
    const int wm = (w >> 1) * 64, wn = (w & 1) * 64;
    const int lg = l >> 4, lm = l & 15;
    const int NT = K >> 6;

    const __bf16* gsrc[3];
    int ldst[3];
#pragma unroll
    for (int j = 0; j < 3; ++j) {
        const unsigned X = (unsigned)((j == 1 ? 8192 : 0) + tid * 16);
        const unsigned L = X ^ (((X >> 7) & 7u) << 4);
        const int row = L >> 6, col = (L & 63) >> 1;
        gsrc[j] = (j < 2 ? A + (size_t)(bm + row) * K : BT + (size_t)(bn + row) * K) + col;
        ldst[j] = ((j < 2 ? (j << 13) : 16384) + (w << 10)) >> 1;
    }
    int aoff[2][2], boff[4];
#pragma unroll
    for (int mh = 0; mh < 2; ++mh)
#pragma unroll
        for (int fr = 0; fr < 2; ++fr) {
            const unsigned Lb = (unsigned)(wm + mh * 32 + fr * 16 + lm) * 64 + lg * 16;
            aoff[mh][fr] = (int)(Lb ^ (((Lb >> 7) & 7u) << 4)) >> 1;
        }
#pragma unroll
    for (int n = 0; n < 4; ++n) {
        const unsigned Lb = (unsigned)(wn + n * 16 + lm) * 64 + lg * 16;
        boff[n] = (int)(16384u + (Lb ^ (((Lb >> 7) & 7u) << 4))) >> 1;
    }

    f32x4 acc[4][4];
#pragma unroll
    for (int m = 0; m < 4; ++m)
#pragma unroll
        for (int n = 0; n < 4; ++n) acc[m][n] = f32x4{0.f, 0.f, 0.f, 0.f};

#define ISSUE_SUB(u)                                                          \
    do {                                                                      \
        __bf16* sbp = lds + ((u) & 3) * 12288;                                \
        const int go = (u) << 5;                                              \
        _Pragma("unroll")                                                     \
        for (int j = 0; j < 3; ++j) gload_lds16(gsrc[j] + go, sbp + ldst[j]); \
    } while (0)

#define MFMA8(MH_, BREG)                                                      \
    do {                                                                      \
        __builtin_amdgcn_s_setprio(1);                                        \
        _Pragma("unroll")                                                     \
        for (int i = 0; i < 2; ++i)                                           \
            _Pragma("unroll")                                                 \
            for (int n = 0; n < 4; ++n)                                       \
                acc[(MH_)*2 + i][n] = __builtin_amdgcn_mfma_f32_16x16x32_bf16(\
                    af[i], BREG[n], acc[(MH_)*2 + i][n], 0, 0, 0);            \
        __builtin_amdgcn_s_setprio(0);                                        \
    } while (0)

    ISSUE_SUB(0); ISSUE_SUB(1); ISSUE_SUB(2); ISSUE_SUB(3);
    asm volatile("s_waitcnt vmcnt(6)" ::: "memory");
    __builtin_amdgcn_s_barrier();

    for (int t = 0; t < NT; ++t) {
        const int sa = ((2 * t) & 3) * 12288, sb = ((2 * t + 1) & 3) * 12288;
        bf16x8 af[2], b0[4], b1[4];
#pragma unroll
        for (int fr = 0; fr < 2; ++fr) af[fr] = *(const bf16x8*)(lds + sa + aoff[0][fr]);
#pragma unroll
        for (int n = 0; n < 4; ++n) b0[n] = *(const bf16x8*)(lds + sa + boff[n]);
        asm volatile("" ::: "memory");
        __builtin_amdgcn_s_barrier();
        __builtin_amdgcn_sched_barrier(0);
        MFMA8(0, b0);
        __builtin_amdgcn_sched_barrier(0);
        __builtin_amdgcn_s_barrier();
#pragma unroll
        for (int fr = 0; fr < 2; ++fr) af[fr] = *(const bf16x8*)(lds + sa + aoff[1][fr]);
        asm volatile("" ::: "memory");
        __builtin_amdgcn_s_barrier();
        __builtin_amdgcn_sched_barrier(0);
        MFMA8(1, b0);
        __builtin_amdgcn_sched_barrier(0);
        __builtin_amdgcn_s_barrier();
        if (t < NT - 2) ISSUE_SUB(2 * t + 4);
#pragma unroll
        for (int fr = 0; fr < 2; ++fr) af[fr] = *(const bf16x8*)(lds + sb + aoff[0][fr]);
#pragma unroll
        for (int n = 0; n < 4; ++n) b1[n] = *(const bf16x8*)(lds + sb + boff[n]);
        asm volatile("" ::: "memory");
        __builtin_amdgcn_s_barrier();
        __builtin_amdgcn_sched_barrier(0);
        MFMA8(0, b1);
        __builtin_amdgcn_sched_barrier(0);
        __builtin_amdgcn_s_barrier();
#pragma unroll
        for (int fr = 0; fr < 2; ++fr) af[fr] = *(const bf16x8*)(lds + sb + aoff[1][fr]);
        asm volatile("" ::: "memory");
        __builtin_amdgcn_s_barrier();
        __builtin_amdgcn_sched_barrier(0);
        MFMA8(1, b1);
        __builtin_amdgcn_sched_barrier(0);
        __builtin_amdgcn_s_barrier();
        if (t < NT - 2) {
            ISSUE_SUB(2 * t + 5);
            asm volatile("s_waitcnt vmcnt(6)" ::: "memory");
        } else if (t == NT - 2) {
            asm volatile("s_waitcnt vmcnt(0)" ::: "memory");
        }
        __builtin_amdgcn_s_barrier();
    }
#undef ISSUE_SUB
#undef MFMA8

#pragma unroll
    for (int m = 0; m < 4; ++m) {
        const int row = bm + wm + m * 16 + lg * 4;
#pragma unroll
        for (int n = 0; n < 4; ++n) {
            const int col = bn + wn + n * 16 + lm;
            const float bvv = bias[col];
#pragma unroll
            for (int r = 0; r < 4; ++r) {
                const size_t idx = (size_t)(row + r) * N + col;
                outp[idx] = resid[idx] + acc[m][n][r] + bvv;
            }
        }
    }
}

// ---------------------------------------------------------------------------
// 128x256 8-phase GEMM for fused QKV (768 wgs = 3/CU).
// Epilogue: Q scaled by 0.125*log2e; K bf16 (ldc 2048); V transposed AND
// key-axis permuted within 32-token blocks so attention's contiguous
// ds_read_b128 of V^T matches the natural P-fragment k-order (zero-shuffle PV).
// perm(s) = (s&~31) | ((s>>2)&3)<<3 | ((s>>4)&1)<<2 | (s&3)
// ---------------------------------------------------------------------------
__global__ __launch_bounds__(512, 2) void gemm_qkv(const __bf16* __restrict__ A,
                                                   const __bf16* __restrict__ BT,
                                                   const float* __restrict__ bias,
                                                   __bf16* __restrict__ outp,
                                                   __bf16* __restrict__ vTout,
                                                   int M, int N, int K, int NMB) {
    __shared__ __align__(16) __bf16 lds[49152];
    const int bid = blockIdx.x;
    const int c8 = bid & 7, loc = bid >> 3;
    const int MH = NMB >> 3;
    const int bm = (c8 * MH + loc % MH) * 128;
    const int bn = (loc / MH) * 256;
    const int tid = threadIdx.x, l = tid & 63, w = tid >> 6;
    const int wm = (w >> 2) * 64, wn = (w & 3) * 64;
    const int lg = l >> 4, lm = l & 15;
    const int NT = K >> 6;

    const __bf16* gsrc[3];
    int ldst[3];
#pragma unroll
    for (int j = 0; j < 3; ++j) {
        const unsigned X = (unsigned)((j == 0 ? 0 : (j - 1) * 8192) + tid * 16);
        const unsigned L = X ^ (((X >> 7) & 7u) << 4);
        const int row = L >> 6, col = (L & 63) >> 1;
        gsrc[j] = (j == 0 ? A + (size_t)(bm + row) * K : BT + (size_t)(bn + row) * K) + col;
        ldst[j] = ((j == 0 ? 0 : 8192 + (j - 1) * 8192) + (w << 10)) >> 1;
    }
    int aoff[2][2], boff[4];
#pragma unroll
    for (int mh = 0; mh < 2; ++mh)
#pragma unroll
        for (int fr = 0; fr < 2; ++fr) {
            const unsigned Lb = (unsigned)(wm + mh * 32 + fr * 16 + lm) * 64 + lg * 16;
            aoff[mh][fr] = (int)(Lb ^ (((Lb >> 7) & 7u) << 4)) >> 1;
        }
#pragma unroll
    for (int n = 0; n < 4; ++n) {
        const unsigned Lb = (unsigned)(wn + n * 16 + lm) * 64 + lg * 16;
        boff[n] = (int)(8192u + (Lb ^ (((Lb >> 7) & 7u) << 4))) >> 1;
    }

    f32x4 acc[4][4];
#pragma unroll
    for (int m = 0; m < 4; ++m)
#pragma unroll
        for (int n = 0; n < 4; ++n) acc[m][n] = f32x4{0.f, 0.f, 0.f, 0.f};

#define ISSUE_SUB(u)                                                          \
    do {                                                                      \
        __bf16* sbp = lds + ((u) & 3) * 12288;                                \
        const int go = (u) << 5;                                              \
        _Pragma("unroll")                                                     \
        for (int j = 0; j < 3; ++j) gload_lds16(gsrc[j] + go, sbp + ldst[j]); \
    } while (0)

#define MFMA8(MH_, BREG)                                                      \
    do {                                                                      \
        __builtin_amdgcn_s_setprio(1);                                        \
        _Pragma("unroll")                                                     \
        for (int i = 0; i < 2; ++i)                                           \
            _Pragma("unroll")                                                 \
            for (int n = 0; n < 4; ++n)                                       \
                acc[(MH_)*2 + i][n] = __builtin_amdgcn_mfma_f32_16x16x32_bf16(\
                    af[i], BREG[n], acc[(MH_)*2 + i][n], 0, 0, 0);            \
        __builtin_amdgcn_s_setprio(0);                                        \
    } while (0)

    ISSUE_SUB(0); ISSUE_SUB(1); ISSUE_SUB(2); ISSUE_SUB(3);
    asm volatile("s_waitcnt vmcnt(6)" ::: "memory");
    __builtin_amdgcn_s_barrier();

    for (int t = 0; t < NT; ++t) {
        const int sa = ((2 * t) & 3) * 12288, sb = ((2 * t + 1) & 3) * 12288;
        bf16x8 af[2], b0[4], b1[4];
#pragma unroll
        for (int fr = 0; fr < 2; ++fr) af[fr] = *(const bf16x8*)(lds + sa + aoff[0][fr]);
#pragma unroll
        for (int n = 0; n < 4; ++n) b0[n] = *(const bf16x8*)(lds + sa + boff[n]);
        asm volatile("" ::: "memory");
        __builtin_amdgcn_s_barrier();
        __builtin_amdgcn_sched_barrier(0);
        MFMA8(0, b0);
        __builtin_amdgcn_sched_barrier(0);
        __builtin_amdgcn_s_barrier();
#pragma unroll
        for (int fr = 0; fr < 2; ++fr) af[fr] = *(const bf16x8*)(lds + sa + aoff[1][fr]);
        asm volatile("" ::: "memory");
        __builtin_amdgcn_s_barrier();
        __builtin_amdgcn_sched_barrier(0);
        MFMA8(1, b0);
        __builtin_amdgcn_sched_barrier(0);
        __builtin_amdgcn_s_barrier();
        if (t < NT - 2) ISSUE_SUB(2 * t + 4);
#pragma unroll
        for (int fr = 0; fr < 2; ++fr) af[fr] = *(const bf16x8*)(lds + sb + aoff[0][fr]);
#pragma unroll
        for (int n = 0; n < 4; ++n) b1[n] = *(const bf16x8*)(lds + sb + boff[n]);
        asm volatile("" ::: "memory");
        __builtin_amdgcn_s_barrier();
        __builtin_amdgcn_sched_barrier(0);
        MFMA8(0, b1);
        __builtin_amdgcn_sched_barrier(0);
        __builtin_amdgcn_s_barrier();
#pragma unroll
        for (int fr = 0; fr < 2; ++fr) af[fr] = *(const bf16x8*)(lds + sb + aoff[1][fr]);
        asm volatile("" ::: "memory");
        __builtin_amdgcn_s_barrier();
        __builtin_amdgcn_sched_barrier(0);
        MFMA8(1, b1);
        __builtin_amdgcn_sched_barrier(0);
        __builtin_amdgcn_s_barrier();
        if (t < NT - 2) {
            ISSUE_SUB(2 * t + 5);
            asm volatile("s_waitcnt vmcnt(6)" ::: "memory");
        } else if (t == NT - 2) {
            asm volatile("s_waitcnt vmcnt(0)" ::: "memory");
        }
        __builtin_amdgcn_s_barrier();
    }
#undef ISSUE_SUB
#undef MFMA8

    const bool isQ = bn < 1024;
#pragma unroll
    for (int m = 0; m < 4; ++m) {
        const int row = bm + wm + m * 16 + lg * 4;
#pragma unroll
        for (int n = 0; n < 4; ++n) {
            const int col = bn + wn + n * 16 + lm;
            const float bvv = bias[col];
            if (bn >= 2048) {
                bf16x4 o;
#pragma unroll
                for (int r = 0; r < 4; ++r) o[r] = (__bf16)(acc[m][n][r] + bvv);
                const int s = row & 1023;   // token within sequence; s%4 == 0
                const int sp = (s & ~31) | (((s >> 2) & 3) << 3) | (((s >> 4) & 1) << 2);
                *(bf16x4*)(vTout + (size_t)((row >> 10) * 1024 + (col - 2048)) * 1024 +
                           sp) = o;
            } else {
#pragma unroll
                for (int r = 0; r < 4; ++r) {
                    float v = acc[m][n][r] + bvv;
                    if (isQ) v *= 0.18033688f;   // 1/8 * log2(e): exp2-domain softmax
                    outp[(size_t)(row + r) * 2048 + col] = (__bf16)v;
                }
            }
        }
    }
}

// ---------------------------------------------------------------------------
// Flash attention fwd, swapped-QK^T, ZERO-SHUFFLE PV (V key-permuted upstream),
// in-register P, single barrier per tile, lane-local online-softmax stats.
// qk: [B*S][2048] bf16 (Q pre-scaled by 0.125*log2e | K). vT: [B*H*64][S perm].
// Grid (h=16, qt=8, b=8) -> bid%8 = head%8 (XCD-aligned KV reuse).
// ---------------------------------------------------------------------------
__global__ __launch_bounds__(512, 4) void attn_kernel(const __bf16* __restrict__ qk,
                                                      const __bf16* __restrict__ vT,
                                                      const int* __restrict__ mask,
                                                      __bf16* __restrict__ ctx) {
    const int h = blockIdx.x, qt = blockIdx.y, b = blockIdx.z;
    const int tid = threadIdx.x, w = tid >> 6, l = tid & 63;
    const int lg = l >> 4, lm = l & 15;

    __shared__ __align__(16) __bf16 Ks[2][64][76];
    __shared__ __align__(16) __bf16 Vt[2][64][76];

    const int qrow = qt * 128 + w * 16 + lm;
    const __bf16* qp = qk + (size_t)(b * 1024 + qrow) * 2048 + h * 64 + lg * 8;
    bf16x8 aq[2];
    aq[0] = *(const bf16x8*)qp;
    aq[1] = *(const bf16x8*)(qp + 32);

    // staging: 512 threads cover one 64x64 tile with 1 uint4 each
    const int r0 = tid >> 3, cc0 = (tid & 7) * 8;
    const __bf16* kbase = qk + (size_t)(b * 1024 + r0) * 2048 + 1024 + h * 64 + cc0;
    const __bf16* vbase = vT + (size_t)(b * 1024 + h * 64 + r0) * 1024 + cc0;
    uint4 kreg, vreg;
#define ALOAD(kt)                                                      \
    do {                                                               \
        kreg = *(const uint4*)(kbase + (size_t)(kt) * 64 * 2048);      \
        vreg = *(const uint4*)(vbase + (kt) * 64);                     \
    } while (0)
#define AWRITE(bf)                                                     \
    do {                                                               \
        *(uint4*)&Ks[bf][r0][cc0] = kreg;                              \
        *(uint4*)&Vt[bf][r0][cc0] = vreg;                              \
    } while (0)

    ALOAD(0); AWRITE(0); ALOAD(1);
    __syncthreads();

    const int* mbase = mask + b * 1024;
    float mrun = -1e30f, lsum = 0.f;   // stats for query lm (lane-local)
    f32x4 oacc[4];                      // O[q=lm][d = nd*16 + lg*4 + r]
#pragma unroll
    for (int n = 0; n < 4; ++n) oacc[n] = f32x4{0.f, 0.f, 0.f, 0.f};

    for (int kt = 0; kt < 16; ++kt) {
        const int cur = kt & 1;
        if (kt < 15) AWRITE(cur ^ 1);    // tile kt+1 (regs from last iter)
        if (kt < 14) ALOAD(kt + 2);      // prefetch tile kt+2
        // S^T = K Q^T : sacc[n][r] = S[key = n*16+lg*4+r][q = lm] (log2 units)
        f32x4 sacc[4];
        int4 mk4[4];
#pragma unroll
        for (int n = 0; n < 4; ++n) {
            mk4[n] = *(const int4*)(mbase + kt * 64 + n * 16 + lg * 4);
            sacc[n] = f32x4{0.f, 0.f, 0.f, 0.f};
#pragma unroll
            for (int kk = 0; kk < 2; ++kk) {
                bf16x8 bk = *(const bf16x8*)&Ks[cur][n * 16 + lm][lg * 8 + kk * 32];
                sacc[n] = __builtin_amdgcn_mfma_f32_16x16x32_bf16(bk, aq[kk], sacc[n], 0, 0, 0);
            }
        }
        float p[4][4], mn[4];
#pragma unroll
        for (int n = 0; n < 4; ++n) {
            p[n][0] = mk4[n].x ? sacc[n][0] : -1e9f;
            p[n][1] = mk4[n].y ? sacc[n][1] : -1e9f;
            p[n][2] = mk4[n].z ? sacc[n][2] : -1e9f;
            p[n][3] = mk4[n].w ? sacc[n][3] : -1e9f;
            mn[n] = fmaxf(fmaxf(p[n][0], p[n][1]), fmaxf(p[n][2], p[n][3]));
        }
        float mloc = fmaxf(fmaxf(mn[0], mn[1]), fmaxf(mn[2], mn[3]));
        mloc = fmaxf(mloc, __shfl_xor(mloc, 16));
        mloc = fmaxf(mloc, __shfl_xor(mloc, 32));
        const float pm = fmaxf(mrun, mloc);
        if (!__all(pm - mrun <= 11.5f)) {        // defer-max (T13), log2 domain
            const float sc = exp2f(mrun - pm);
            mrun = pm;
            lsum *= sc;
#pragma unroll
            for (int n = 0; n < 4; ++n)
#pragma unroll
                for (int r = 0; r < 4; ++r) oacc[n][r] *= sc;   // lane-local
        }
        float rsn[4];
#pragma unroll
        for (int n = 0; n < 4; ++n) {
#pragma unroll
            for (int r = 0; r < 4; ++r) p[n][r] = exp2f(p[n][r] - mrun);
            rsn[n] = (p[n][0] + p[n][1]) + (p[n][2] + p[n][3]);
        }
        float rs = (rsn[0] + rsn[1]) + (rsn[2] + rsn[3]);
        rs += __shfl_xor(rs, 16);
        rs += __shfl_xor(rs, 32);
        lsum += rs;
        // PV: O += V^T_frag(A) x P_frag(B). V key-axis pre-permuted so the
        // natural in-lane pack of p[][] IS the B-fragment. No cross-lane ops.
#pragma unroll
        for (int kk = 0; kk < 2; ++kk) {
            bf16x8 pfrag;
#pragma unroll
            for (int r = 0; r < 4; ++r) {
                pfrag[r]     = (__bf16)p[2 * kk][r];
                pfrag[4 + r] = (__bf16)p[2 * kk + 1][r];
            }
#pragma unroll
            for (int nd = 0; nd < 4; ++nd) {
                bf16x8 vf = *(const bf16x8*)&Vt[cur][nd * 16 + lm][lg * 8 + kk * 32];
                oacc[nd] = __builtin_amdgcn_mfma_f32_16x16x32_bf16(vf, pfrag, oacc[nd], 0, 0, 0);
            }
        }
        __syncthreads();   // single barrier: read(cur) done, write(cur^1) visible
    }
#undef ALOAD
#undef AWRITE
    const float rinv = 1.0f / lsum;
#pragma unroll
    for (int nd = 0; nd < 4; ++nd) {
        bf16x4 o;
#pragma unroll
        for (int r = 0; r < 4; ++r) o[r] = (__bf16)(oacc[nd][r] * rinv);
        *(bf16x4*)(ctx + (size_t)(b * 1024 + qrow) * 1024 + h * 64 + nd * 16 + lg * 4) = o;
    }
}

// ---------------------------------------------------------------------------
extern "C" void kernel_launch(void* const* d_in, const int* in_sizes, int n_in,
                              void* d_out, int out_size, void* d_ws, size_t ws_size,
                              hipStream_t stream) {
    const float* x    = (const float*)d_in[0];
    const int*   mask = (const int*)d_in[1];
    const float* wq   = (const float*)d_in[2];
    const float* bq   = (const float*)d_in[3];
    const float* wk   = (const float*)d_in[4];
    const float* bk   = (const float*)d_in[5];
    const float* wv   = (const float*)d_in[6];
    const float* bv   = (const float*)d_in[7];
    const float* wo   = (const float*)d_in[8];
    const float* bo   = (const float*)d_in[9];
    const float* w1   = (const float*)d_in[10];
    const float* b1   = (const float*)d_in[11];
    const float* w2   = (const float*)d_in[12];
    const float* b2   = (const float*)d_in[13];
    const float* ln1g = (const float*)d_in[14];
    const float* ln1b = (const float*)d_in[15];
    const float* ln2g = (const float*)d_in[16];
    const float* ln2b = (const float*)d_in[17];
    float* out = (float*)d_out;
    char* ws = (char*)d_ws;

    __bf16* wqkvT = (__bf16*)(ws + 0);          // [3072][1024]  6 MB
    __bf16* woT   = (__bf16*)(ws + 6291456);    // [1024][1024]  2 MB
    __bf16* w1T   = (__bf16*)(ws + 8388608);    // [4096][1024]  8 MB
    __bf16* w2T   = (__bf16*)(ws + 16777216);   // [1024][4096]  8 MB
    float*  bqkv  = (float*)(ws + 25165824);    // [3072]
    __bf16* hb    = (__bf16*)(ws + 25178112);   // [8192][1024] 16 MB
    __bf16* qkb   = (__bf16*)(ws + 41955328);   // [8192][2048] 32 MB
    __bf16* vTb   = (__bf16*)(ws + 75509760);   // [8*16*64][1024] 16 MB
    __bf16* ctxb  = (__bf16*)(ws + 92286976);   // [8192][1024] 16 MB -> 109064192
    __bf16* ff1b  = qkb;                        // [8192][4096] 64 MB overlays

    transpose_all<<<12288, 256, 0, stream>>>(wq, wk, wv, wo, w1, w2,
                                             wqkvT, woT, w1T, w2T);
    concat3<<<4, 256, 0, stream>>>(bq, bk, bv, bqkv, 1024);

    // LN1 -> hb
    ln_to_bf16<<<8192, 256, 0, stream>>>(x, ln1g, ln1b, hb);
    // fused QKV (128x256): Q(prescaled)|K -> qkb, V -> vTb^T (key-permuted)
    gemm_qkv<<<768, 512, 0, stream>>>(hb, wqkvT, bqkv, qkb, vTb, 8192, 3072, 1024, 64);
    // attention (head-major grid for XCD-aligned KV reuse)
    attn_kernel<<<dim3(16, 8, 8), 512, 0, stream>>>(qkb, vTb, mask, ctxb);
    // output proj + residual -> d_out (fp32)
    gemm256x128<<<256, 512, 0, stream>>>(ctxb, woT, bo, x, out, 8192, 1024, 1024, 32);
    // LN2 -> hb
    ln_to_bf16<<<8192, 256, 0, stream>>>(out, ln2g, ln2b, hb);
    // FFN1 (256^2, relu)
    gemm256<1><<<512, 512, 0, stream>>>(hb, w1T, b1, ff1b, 8192, 4096, 1024, 32);
    // FFN2 + residual
    gemm256x128<<<256, 512, 0, stream>>>(ff1b, w2T, b2, out, out, 8192, 1024, 4096, 32);
}

// Round 9
// 363.582 us; speedup vs baseline: 1.4500x; 1.0139x over previous
//
#include <hip/hip_runtime.h>
#include <hip/hip_bf16.h>

typedef __attribute__((ext_vector_type(8))) __bf16 bf16x8;
typedef __attribute__((ext_vector_type(4))) __bf16 bf16x4;
typedef __attribute__((ext_vector_type(4))) float  f32x4;

__device__ __forceinline__ void gload_lds16(const __bf16* g, __bf16* l) {
    __builtin_amdgcn_global_load_lds(
        (const __attribute__((address_space(1))) void*)g,
        (__attribute__((address_space(3))) void*)l, 16, 0, 0);
}

// Soft barrier: ds-write visibility (lgkmcnt(0)) + rendezvous, but does NOT
// drain vmcnt -> register prefetch loads stay in flight across the barrier.
// asm fences stop the compiler moving LDS ops across it (rule #18 analog).
#define SOFT_BARRIER()                                            \
    do {                                                          \
        asm volatile("s_waitcnt lgkmcnt(0)" ::: "memory");        \
        __builtin_amdgcn_s_barrier();                             \
        asm volatile("" ::: "memory");                            \
    } while (0)

// ---------------------------------------------------------------------------
// All weight transposes (fp32 [K][N] -> bf16 [N][K]) + bias concat, ONE launch.
// blocks 0..4095: wq,wk,wv,wo; 4096..8191: w1; 8192..12287: w2; 12288..12291:
// concat bq|bk|bv -> bqkv.
// ---------------------------------------------------------------------------
__global__ __launch_bounds__(256) void transpose_all(
    const float* __restrict__ wq, const float* __restrict__ wk,
    const float* __restrict__ wv, const float* __restrict__ wo,
    const float* __restrict__ w1, const float* __restrict__ w2,
    __bf16* __restrict__ wqkvT, __bf16* __restrict__ woT,
    __bf16* __restrict__ w1T, __bf16* __restrict__ w2T,
    const float* __restrict__ bq, const float* __restrict__ bk,
    const float* __restrict__ bv, float* __restrict__ bqkv) {
    __shared__ float t[32][33];
    const int bid = blockIdx.x;
    if (bid >= 12288) {   // bias concat tail: 4 blocks x 256 thr = 1024 lanes
        const int i = (bid - 12288) * 256 + threadIdx.x;
        bqkv[i] = bq[i]; bqkv[1024 + i] = bk[i]; bqkv[2048 + i] = bv[i];
        return;
    }
    const float* in; __bf16* out; int K, N, nb, kb;
    if (bid < 4096) {
        const int which = bid >> 10, tt = bid & 1023;
        K = 1024; N = 1024;
        in  = which == 0 ? wq : which == 1 ? wk : which == 2 ? wv : wo;
        out = which == 3 ? woT : wqkvT + (size_t)which * 1048576;
        nb = (tt & 31) * 32; kb = (tt >> 5) * 32;
    } else if (bid < 8192) {
        const int tt = bid - 4096;
        in = w1; out = w1T; K = 1024; N = 4096;
        nb = (tt & 127) * 32; kb = (tt >> 7) * 32;
    } else {
        const int tt = bid - 8192;
        in = w2; out = w2T; K = 4096; N = 1024;
        nb = (tt & 31) * 32; kb = (tt >> 5) * 32;
    }
    const int tx = threadIdx.x & 31, ty = threadIdx.x >> 5;
#pragma unroll
    for (int i = 0; i < 32; i += 8)
        t[ty + i][tx] = in[(size_t)(kb + ty + i) * N + nb + tx];
    __syncthreads();
#pragma unroll
    for (int i = 0; i < 32; i += 8)
        out[(size_t)(nb + ty + i) * K + kb + tx] = (__bf16)t[tx][ty + i];
}

// ---------------------------------------------------------------------------
// LayerNorm over D=1024, one block per row, fp32 in -> bf16 out
// ---------------------------------------------------------------------------
__global__ __launch_bounds__(256) void ln_to_bf16(const float* __restrict__ x,
                                                  const float* __restrict__ g,
                                                  const float* __restrict__ bb,
                                                  __bf16* __restrict__ out) {
    const int row = blockIdx.x, t = threadIdx.x;
    const float4 v = ((const float4*)(x + (size_t)row * 1024))[t];
    float s  = v.x + v.y + v.z + v.w;
    float ss = v.x * v.x + v.y * v.y + v.z * v.z + v.w * v.w;
#pragma unroll
    for (int off = 32; off; off >>= 1) {
        s  += __shfl_down(s, off);
        ss += __shfl_down(ss, off);
    }
    __shared__ float ps[4], pss[4];
    if ((t & 63) == 0) { ps[t >> 6] = s; pss[t >> 6] = ss; }
    __syncthreads();
    s  = ps[0] + ps[1] + ps[2] + ps[3];
    ss = pss[0] + pss[1] + pss[2] + pss[3];
    const float mu   = s * (1.0f / 1024.0f);
    const float var  = ss * (1.0f / 1024.0f) - mu * mu;
    const float rinv = rsqrtf(var + 1e-5f);
    const float4 gv = ((const float4*)g)[t];
    const float4 bv = ((const float4*)bb)[t];
    bf16x4 o;
    o[0] = (__bf16)((v.x - mu) * rinv * gv.x + bv.x);
    o[1] = (__bf16)((v.y - mu) * rinv * gv.y + bv.y);
    o[2] = (__bf16)((v.z - mu) * rinv * gv.z + bv.z);
    o[3] = (__bf16)((v.w - mu) * rinv * gv.w + bv.w);
    *(bf16x4*)(out + (size_t)row * 1024 + 4 * t) = o;
}

// ---------------------------------------------------------------------------
// 256x256 8-phase GEMM (FFN1). 2D per-XCD chunk. MODE 1: relu bf16 out.
// ---------------------------------------------------------------------------
template <int MODE>
__global__ __launch_bounds__(512, 2) void gemm256(const __bf16* __restrict__ A,
                                                  const __bf16* __restrict__ BT,
                                                  const float* __restrict__ bias,
                                                  __bf16* __restrict__ outp,
                                                  int M, int N, int K, int NMB) {
    __shared__ __align__(16) __bf16 lds[65536];
    const int bid = blockIdx.x;
    const int c8 = bid & 7, loc = bid >> 3;       // XCD id, chunk-local index
    const int MH = NMB >> 3;                      // bm rows per XCD chunk
    const int bm = (c8 * MH + loc % MH) * 256;
    const int bn = (loc / MH) * 256;
    const int tid = threadIdx.x, l = tid & 63, w = tid >> 6;
    const int wm = (w >> 2) * 128, wn = (w & 3) * 64;
    const int lg = l >> 4, lm = l & 15;
    const int NT = K >> 6;

    const __bf16* gsrc[4];
    int ldst[4];
#pragma unroll
    for (int j = 0; j < 4; ++j) {
        const unsigned X = (unsigned)(((j & 1) << 13) + (w << 10) + l * 16);
        const unsigned L = X ^ (((X >> 7) & 7u) << 4);
        const int row = L >> 6, col = (L & 63) >> 1;
        gsrc[j] = (j < 2 ? A + (size_t)(bm + row) * K : BT + (size_t)(bn + row) * K) + col;
        ldst[j] = ((j < 2 ? 0 : 16384) + ((j & 1) << 13) + (w << 10)) >> 1;
    }
    int aoff[2][4], boff[4];
#pragma unroll
    for (int mh = 0; mh < 2; ++mh)
#pragma unroll
        for (int fr = 0; fr < 4; ++fr) {
            const unsigned Lb = (unsigned)(wm + mh * 64 + fr * 16 + lm) * 64 + lg * 16;
            aoff[mh][fr] = (int)(Lb ^ (((Lb >> 7) & 7u) << 4)) >> 1;
        }
#pragma unroll
    for (int n = 0; n < 4; ++n) {
        const unsigned Lb = (unsigned)(wn + n * 16 + lm) * 64 + lg * 16;
        boff[n] = (int)(16384u + (Lb ^ (((Lb >> 7) & 7u) << 4))) >> 1;
    }

    f32x4 acc[8][4];
#pragma unroll
    for (int m = 0; m < 8; ++m)
#pragma unroll
        for (int n = 0; n < 4; ++n) acc[m][n] = f32x4{0.f, 0.f, 0.f, 0.f};

#define ISSUE_SUB(u)                                                          \
    do {                                                                      \
        __bf16* sbp = lds + (((u) & 3) << 14);                                \
        const int go = (u) << 5;                                              \
        _Pragma("unroll")                                                     \
        for (int j = 0; j < 4; ++j) gload_lds16(gsrc[j] + go, sbp + ldst[j]); \
    } while (0)

#define MFMA16(MH_, BREG)                                                     \
    do {                                                                      \
        __builtin_amdgcn_s_setprio(1);                                        \
        _Pragma("unroll")                                                     \
        for (int i = 0; i < 4; ++i)                                           \
            _Pragma("unroll")                                                 \
            for (int n = 0; n < 4; ++n)                                       \
                acc[(MH_)*4 + i][n] = __builtin_amdgcn_mfma_f32_16x16x32_bf16(\
                    af[i], BREG[n], acc[(MH_)*4 + i][n], 0, 0, 0);            \
        __builtin_amdgcn_s_setprio(0);                                        \
    } while (0)

    ISSUE_SUB(0); ISSUE_SUB(1); ISSUE_SUB(2); ISSUE_SUB(3);
    asm volatile("s_waitcnt vmcnt(8)" ::: "memory");
    __builtin_amdgcn_s_barrier();

    for (int t = 0; t < NT; ++t) {
        const int sa = ((2 * t) & 3) << 14, sb = ((2 * t + 1) & 3) << 14;
        bf16x8 af[4], b0[4], b1[4];
#pragma unroll
        for (int fr = 0; fr < 4; ++fr) af[fr] = *(const bf16x8*)(lds + sa + aoff[0][fr]);
#pragma unroll
        for (int n = 0; n < 4; ++n) b0[n] = *(const bf16x8*)(lds + sa + boff[n]);
        asm volatile("" ::: "memory");
        __builtin_amdgcn_s_barrier();
        __builtin_amdgcn_sched_barrier(0);
        MFMA16(0, b0);
        __builtin_amdgcn_sched_barrier(0);
        __builtin_amdgcn_s_barrier();
#pragma unroll
        for (int fr = 0; fr < 4; ++fr) af[fr] = *(const bf16x8*)(lds + sa + aoff[1][fr]);
        asm volatile("" ::: "memory");
        __builtin_amdgcn_s_barrier();
        __builtin_amdgcn_sched_barrier(0);
        MFMA16(1, b0);
        __builtin_amdgcn_sched_barrier(0);
        __builtin_amdgcn_s_barrier();
        if (t < NT - 2) ISSUE_SUB(2 * t + 4);
#pragma unroll
        for (int fr = 0; fr < 4; ++fr) af[fr] = *(const bf16x8*)(lds + sb + aoff[0][fr]);
#pragma unroll
        for (int n = 0; n < 4; ++n) b1[n] = *(const bf16x8*)(lds + sb + boff[n]);
        asm volatile("" ::: "memory");
        __builtin_amdgcn_s_barrier();
        __builtin_amdgcn_sched_barrier(0);
        MFMA16(0, b1);
        __builtin_amdgcn_sched_barrier(0);
        __builtin_amdgcn_s_barrier();
#pragma unroll
        for (int fr = 0; fr < 4; ++fr) af[fr] = *(const bf16x8*)(lds + sb + aoff[1][fr]);
        asm volatile("" ::: "memory");
        __builtin_amdgcn_s_barrier();
        __builtin_amdgcn_sched_barrier(0);
        MFMA16(1, b1);
        __builtin_amdgcn_sched_barrier(0);
        __builtin_amdgcn_s_barrier();
        if (t < NT - 2) {
            ISSUE_SUB(2 * t + 5);
            asm volatile("s_waitcnt vmcnt(8)" ::: "memory");
        } else if (t == NT - 2) {
            asm volatile("s_waitcnt vmcnt(0)" ::: "memory");
        }
        __builtin_amdgcn_s_barrier();
    }
#undef ISSUE_SUB
#undef MFMA16

#pragma unroll
    for (int m = 0; m < 8; ++m) {
        const int row = bm + wm + (m >> 2) * 64 + (m & 3) * 16 + lg * 4;
#pragma unroll
        for (int n = 0; n < 4; ++n) {
            const int col = bn + wn + n * 16 + lm;
            const float bvv = bias[col];
#pragma unroll
            for (int r = 0; r < 4; ++r) {
                const float v = acc[m][n][r] + bvv;
                outp[(size_t)(row + r) * N + col] =
                    (MODE == 1) ? (__bf16)fmaxf(v, 0.f) : (__bf16)v;
            }
        }
    }
}

// ---------------------------------------------------------------------------
// 256x128 8-phase GEMM, f32 out + residual (proj / FFN2, N=1024). PROVEN.
// ---------------------------------------------------------------------------
__global__ __launch_bounds__(512, 2) void gemm256x128(const __bf16* __restrict__ A,
                                                      const __bf16* __restrict__ BT,
                                                      const float* __restrict__ bias,
                                                      const float* __restrict__ resid,
                                                      float* __restrict__ outp,
                                                      int M, int N, int K, int NMB) {
    __shared__ __align__(16) __bf16 lds[49152];
    const int bid = blockIdx.x;
    const int c8 = bid & 7, loc = bid >> 3;
    const int MH = NMB >> 3;
    const int bm = (c8 * MH + loc % MH) * 256;
    const int bn = (loc / MH) * 128;
    const int tid = threadIdx.x, l = tid & 63, w = tid >> 6;
    const int wm = (w >> 1) * 64, wn = (w & 1) * 64;
    const int lg = l >> 4, lm = l & 15;
    const int NT = K >> 6;

    const __bf16* gsrc[3];
    int ldst[3];
#pragma unroll
    for (int j = 0; j < 3; ++j) {
        const unsigned X = (unsigned)((j == 1 ? 8192 : 0) + tid * 16);
        const unsigned L = X ^ (((X >> 7) & 7u) << 4);
        const int row = L >> 6, col = (L & 63) >> 1;
        gsrc[j] = (j < 2 ? A + (size_t)(bm + row) * K : BT + (size_t)(bn + row) * K) + col;
        ldst[j] = ((j < 2 ? (j << 13) : 16384) + (w << 10)) >> 1;
    }
    int aoff[2][2], boff[4];
#pragma unroll
    for (int mh = 0; mh < 2; ++mh)
#pragma unroll
        for (int fr = 0; fr < 2; ++fr) {
            const unsigned Lb = (unsigned)(wm + mh * 32 + fr * 16 + lm) * 64 + lg * 16;
            aoff[mh][fr] = (int)(Lb ^ (((Lb >> 7) & 7u) << 4)) >> 1;
        }
#pragma unroll
    for (int n = 0; n < 4; ++n) {
        const unsigned Lb = (unsigned)(wn + n * 16 + lm) * 64 + lg * 16;
        boff[n] = (int)(16384u + (Lb ^ (((Lb >> 7) & 7u) << 4))) >> 1;
    }

    f32x4 acc[4][4];
#pragma unroll
    for (int m = 0; m < 4; ++m)
#pragma unroll
        for (int n = 0; n < 4; ++n) acc[m][n] = f32x4{0.f, 0.f, 0.f, 0.f};

#define ISSUE_SUB(u)                                                          \
    do {                                                                      \
        __bf16* sbp = lds + ((u) & 3) * 12288;                                \
        const int go = (u) << 5;                                              \
        _Pragma("unroll")                                                     \
        for (int j = 0; j < 3; ++j) gload_lds16(gsrc[j] + go, sbp + ldst[j]); \
    } while (0)

#define MFMA8(MH_, BREG)                                                      \
    do {                                                                      \
        __builtin_amdgcn_s_setprio(1);                                        \
        _Pragma("unroll")                                                     \
        for (int i = 0; i < 2; ++i)                                           \
            _Pragma("unroll")                                                 \
            for (int n = 0; n < 4; ++n)                                       \
                acc[(MH_)*2 + i][n] = __builtin_amdgcn_mfma_f32_16x16x32_bf16(\
                    af[i], BREG[n], acc[(MH_)*2 + i][n], 0, 0, 0);            \
        __builtin_amdgcn_s_setprio(0);                                        \
    } while (0)

    ISSUE_SUB(0); ISSUE_SUB(1); ISSUE_SUB(2); ISSUE_SUB(3);
    asm volatile("s_waitcnt vmcnt(6)" ::: "memory");
    __builtin_amdgcn_s_barrier();

    for (int t = 0; t < NT; ++t) {
        const int sa = ((2 * t) & 3) * 12288, sb = ((2 * t + 1) & 3) * 12288;
        bf16x8 af[2], b0[4], b1[4];
#pragma unroll
        for (int fr = 0; fr < 2; ++fr) af[fr] = *(const bf16x8*)(lds + sa + aoff[0][fr]);
#pragma unroll
        for (int n = 0; n < 4; ++n) b0[n] = *(const bf16x8*)(lds + sa + boff[n]);
        asm volatile("" ::: "memory");
        __builtin_amdgcn_s_barrier();
        __builtin_amdgcn_sched_barrier(0);
        MFMA8(0, b0);
        __builtin_amdgcn_sched_barrier(0);
        __builtin_amdgcn_s_barrier();
#pragma unroll
        for (int fr = 0; fr < 2; ++fr) af[fr] = *(const bf16x8*)(lds + sa + aoff[1][fr]);
        asm volatile("" ::: "memory");
        __builtin_amdgcn_s_barrier();
        __builtin_amdgcn_sched_barrier(0);
        MFMA8(1, b0);
        __builtin_amdgcn_sched_barrier(0);
        __builtin_amdgcn_s_barrier();
        if (t < NT - 2) ISSUE_SUB(2 * t + 4);
#pragma unroll
        for (int fr = 0; fr < 2; ++fr) af[fr] = *(const bf16x8*)(lds + sb + aoff[0][fr]);
#pragma unroll
        for (int n = 0; n < 4; ++n) b1[n] = *(const bf16x8*)(lds + sb + boff[n]);
        asm volatile("" ::: "memory");
        __builtin_amdgcn_s_barrier();
        __builtin_amdgcn_sched_barrier(0);
        MFMA8(0, b1);
        __builtin_amdgcn_sched_barrier(0);
        __builtin_amdgcn_s_barrier();
#pragma unroll
        for (int fr = 0; fr < 2; ++fr) af[fr] = *(const bf16x8*)(lds + sb + aoff[1][fr]);
        asm volatile("" ::: "memory");
        __builtin_amdgcn_s_barrier();
        __builtin_amdgcn_sched_barrier(0);
        MFMA8(1, b1);
        __builtin_amdgcn_sched_barrier(0);
        __builtin_amdgcn_s_barrier();
        if (t < NT - 2) {
            ISSUE_SUB(2 * t + 5);
            asm volatile("s_waitcnt vmcnt(6)" ::: "memory");
        } else if (t == NT - 2) {
            asm volatile("s_waitcnt vmcnt(0)" ::: "memory");
        }
        __builtin_amdgcn_s_barrier();
    }
#undef ISSUE_SUB
#undef MFMA8

#pragma unroll
    for (int m = 0; m < 4; ++m) {
        const int row = bm + wm + m * 16 + lg * 4;
#pragma unroll
        for (int n = 0; n < 4; ++n) {
            const int col = bn + wn + n * 16 + lm;
            const float bvv = bias[col];
#pragma unroll
            for (int r = 0; r < 4; ++r) {
                const size_t idx = (size_t)(row + r) * N + col;
                outp[idx] = resid[idx] + acc[m][n][r] + bvv;
            }
        }
    }
}

// ---------------------------------------------------------------------------
// 128x256 8-phase GEMM for fused QKV (768 wgs).
// Epilogue: Q scaled by 0.125*log2e; K bf16 (ldc 2048); V transposed AND
// key-axis permuted within 32-token blocks (zero-shuffle PV downstream).
// perm(s) = (s&~31) | ((s>>2)&3)<<3 | ((s>>4)&1)<<2 | (s&3)
// ---------------------------------------------------------------------------
__global__ __launch_bounds__(512, 2) void gemm_qkv(const __bf16* __restrict__ A,
                                                   const __bf16* __restrict__ BT,
                                                   const float* __restrict__ bias,
                                                   __bf16* __restrict__ outp,
                                                   __bf16* __restrict__ vTout,
                                                   int M, int N, int K, int NMB) {
    __shared__ __align__(16) __bf16 lds[49152];
    const int bid = blockIdx.x;
    const int c8 = bid & 7, loc = bid >> 3;
    const int MH = NMB >> 3;
    const int bm = (c8 * MH + loc % MH) * 128;
    const int bn = (loc / MH) * 256;
    const int tid = threadIdx.x, l = tid & 63, w = tid >> 6;
    const int wm = (w >> 2) * 64, wn = (w & 3) * 64;
    const int lg = l >> 4, lm = l & 15;
    const int NT = K >> 6;

    const __bf16* gsrc[3];
    int ldst[3];
#pragma unroll
    for (int j = 0; j < 3; ++j) {
        const unsigned X = (unsigned)((j == 0 ? 0 : (j - 1) * 8192) + tid * 16);
        const unsigned L = X ^ (((X >> 7) & 7u) << 4);
        const int row = L >> 6, col = (L & 63) >> 1;
        gsrc[j] = (j == 0 ? A + (size_t)(bm + row) * K : BT + (size_t)(bn + row) * K) + col;
        ldst[j] = ((j == 0 ? 0 : 8192 + (j - 1) * 8192) + (w << 10)) >> 1;
    }
    int aoff[2][2], boff[4];
#pragma unroll
    for (int mh = 0; mh < 2; ++mh)
#pragma unroll
        for (int fr = 0; fr < 2; ++fr) {
            const unsigned Lb = (unsigned)(wm + mh * 32 + fr * 16 + lm) * 64 + lg * 16;
            aoff[mh][fr] = (int)(Lb ^ (((Lb >> 7) & 7u) << 4)) >> 1;
        }
#pragma unroll
    for (int n = 0; n < 4; ++n) {
        const unsigned Lb = (unsigned)(wn + n * 16 + lm) * 64 + lg * 16;
        boff[n] = (int)(8192u + (Lb ^ (((Lb >> 7) & 7u) << 4))) >> 1;
    }

    f32x4 acc[4][4];
#pragma unroll
    for (int m = 0; m < 4; ++m)
#pragma unroll
        for (int n = 0; n < 4; ++n) acc[m][n] = f32x4{0.f, 0.f, 0.f, 0.f};

#define ISSUE_SUB(u)                                                          \
    do {                                                                      \
        __bf16* sbp = lds + ((u) & 3) * 12288;                                \
        const int go = (u) << 5;                                              \
        _Pragma("unroll")                                                     \
        for (int j = 0; j < 3; ++j) gload_lds16(gsrc[j] + go, sbp + ldst[j]); \
    } while (0)

#define MFMA8(MH_, BREG)                                                      \
    do {                                                                      \
        __builtin_amdgcn_s_setprio(1);                                        \
        _Pragma("unroll")                                                     \
        for (int i = 0; i < 2; ++i)                                           \
            _Pragma("unroll")                                                 \
            for (int n = 0; n < 4; ++n)                                       \
                acc[(MH_)*2 + i][n] = __builtin_amdgcn_mfma_f32_16x16x32_bf16(\
                    af[i], BREG[n], acc[(MH_)*2 + i][n], 0, 0, 0);            \
        __builtin_amdgcn_s_setprio(0);                                        \
    } while (0)

    ISSUE_SUB(0); ISSUE_SUB(1); ISSUE_SUB(2); ISSUE_SUB(3);
    asm volatile("s_waitcnt vmcnt(6)" ::: "memory");
    __builtin_amdgcn_s_barrier();

    for (int t = 0; t < NT; ++t) {
        const int sa = ((2 * t) & 3) * 12288, sb = ((2 * t + 1) & 3) * 12288;
        bf16x8 af[2], b0[4], b1[4];
#pragma unroll
        for (int fr = 0; fr < 2; ++fr) af[fr] = *(const bf16x8*)(lds + sa + aoff[0][fr]);
#pragma unroll
        for (int n = 0; n < 4; ++n) b0[n] = *(const bf16x8*)(lds + sa + boff[n]);
        asm volatile("" ::: "memory");
        __builtin_amdgcn_s_barrier();
        __builtin_amdgcn_sched_barrier(0);
        MFMA8(0, b0);
        __builtin_amdgcn_sched_barrier(0);
        __builtin_amdgcn_s_barrier();
#pragma unroll
        for (int fr = 0; fr < 2; ++fr) af[fr] = *(const bf16x8*)(lds + sa + aoff[1][fr]);
        asm volatile("" ::: "memory");
        __builtin_amdgcn_s_barrier();
        __builtin_amdgcn_sched_barrier(0);
        MFMA8(1, b0);
        __builtin_amdgcn_sched_barrier(0);
        __builtin_amdgcn_s_barrier();
        if (t < NT - 2) ISSUE_SUB(2 * t + 4);
#pragma unroll
        for (int fr = 0; fr < 2; ++fr) af[fr] = *(const bf16x8*)(lds + sb + aoff[0][fr]);
#pragma unroll
        for (int n = 0; n < 4; ++n) b1[n] = *(const bf16x8*)(lds + sb + boff[n]);
        asm volatile("" ::: "memory");
        __builtin_amdgcn_s_barrier();
        __builtin_amdgcn_sched_barrier(0);
        MFMA8(0, b1);
        __builtin_amdgcn_sched_barrier(0);
        __builtin_amdgcn_s_barrier();
#pragma unroll
        for (int fr = 0; fr < 2; ++fr) af[fr] = *(const bf16x8*)(lds + sb + aoff[1][fr]);
        asm volatile("" ::: "memory");
        __builtin_amdgcn_s_barrier();
        __builtin_amdgcn_sched_barrier(0);
        MFMA8(1, b1);
        __builtin_amdgcn_sched_barrier(0);
        __builtin_amdgcn_s_barrier();
        if (t < NT - 2) {
            ISSUE_SUB(2 * t + 5);
            asm volatile("s_waitcnt vmcnt(6)" ::: "memory");
        } else if (t == NT - 2) {
            asm volatile("s_waitcnt vmcnt(0)" ::: "memory");
        }
        __builtin_amdgcn_s_barrier();
    }
#undef ISSUE_SUB
#undef MFMA8

    const bool isQ = bn < 1024;
#pragma unroll
    for (int m = 0; m < 4; ++m) {
        const int row = bm + wm + m * 16 + lg * 4;
#pragma unroll
        for (int n = 0; n < 4; ++n) {
            const int col = bn + wn + n * 16 + lm;
            const float bvv = bias[col];
            if (bn >= 2048) {
                bf16x4 o;
#pragma unroll
                for (int r = 0; r < 4; ++r) o[r] = (__bf16)(acc[m][n][r] + bvv);
                const int s = row & 1023;   // token within sequence; s%4 == 0
                const int sp = (s & ~31) | (((s >> 2) & 3) << 3) | (((s >> 4) & 1) << 2);
                *(bf16x4*)(vTout + (size_t)((row >> 10) * 1024 + (col - 2048)) * 1024 +
                           sp) = o;
            } else {
#pragma unroll
                for (int r = 0; r < 4; ++r) {
                    float v = acc[m][n][r] + bvv;
                    if (isQ) v *= 0.18033688f;   // 1/8 * log2(e): exp2-domain softmax
                    outp[(size_t)(row + r) * 2048 + col] = (__bf16)v;
                }
            }
        }
    }
}

// ---------------------------------------------------------------------------
// Flash attention fwd, swapped-QK^T, ZERO-SHUFFLE PV (V key-permuted upstream),
// in-register P, lane-local online-softmax stats. Soft barriers: lgkmcnt(0)+
// s_barrier only -> register prefetch (ALOAD) stays in flight across tiles.
// ---------------------------------------------------------------------------
__global__ __launch_bounds__(512, 4) void attn_kernel(const __bf16* __restrict__ qk,
                                                      const __bf16* __restrict__ vT,
                                                      const int* __restrict__ mask,
                                                      __bf16* __restrict__ ctx) {
    const int h = blockIdx.x, qt = blockIdx.y, b = blockIdx.z;
    const int tid = threadIdx.x, w = tid >> 6, l = tid & 63;
    const int lg = l >> 4, lm = l & 15;

    __shared__ __align__(16) __bf16 Ks[2][64][76];
    __shared__ __align__(16) __bf16 Vt[2][64][76];

    const int qrow = qt * 128 + w * 16 + lm;
    const __bf16* qp = qk + (size_t)(b * 1024 + qrow) * 2048 + h * 64 + lg * 8;
    bf16x8 aq[2];
    aq[0] = *(const bf16x8*)qp;
    aq[1] = *(const bf16x8*)(qp + 32);

    const int r0 = tid >> 3, cc0 = (tid & 7) * 8;
    const __bf16* kbase = qk + (size_t)(b * 1024 + r0) * 2048 + 1024 + h * 64 + cc0;
    const __bf16* vbase = vT + (size_t)(b * 1024 + h * 64 + r0) * 1024 + cc0;
    uint4 kreg, vreg;
#define ALOAD(kt)                                                      \
    do {                                                               \
        kreg = *(const uint4*)(kbase + (size_t)(kt) * 64 * 2048);      \
        vreg = *(const uint4*)(vbase + (kt) * 64);                     \
    } while (0)
#define AWRITE(bf)                                                     \
    do {                                                               \
        *(uint4*)&Ks[bf][r0][cc0] = kreg;                              \
        *(uint4*)&Vt[bf][r0][cc0] = vreg;                              \
    } while (0)

    ALOAD(0); AWRITE(0); ALOAD(1);
    SOFT_BARRIER();

    const int* mbase = mask + b * 1024;
    float mrun = -1e30f, lsum = 0.f;
    f32x4 oacc[4];
#pragma unroll
    for (int n = 0; n < 4; ++n) oacc[n] = f32x4{0.f, 0.f, 0.f, 0.f};

    for (int kt = 0; kt < 16; ++kt) {
        const int cur = kt & 1;
        if (kt < 15) AWRITE(cur ^ 1);
        if (kt < 14) ALOAD(kt + 2);
        f32x4 sacc[4];
        int4 mk4[4];
#pragma unroll
        for (int n = 0; n < 4; ++n) {
            mk4[n] = *(const int4*)(mbase + kt * 64 + n * 16 + lg * 4);
            sacc[n] = f32x4{0.f, 0.f, 0.f, 0.f};
#pragma unroll
            for (int kk = 0; kk < 2; ++kk) {
                bf16x8 bk = *(const bf16x8*)&Ks[cur][n * 16 + lm][lg * 8 + kk * 32];
                sacc[n] = __builtin_amdgcn_mfma_f32_16x16x32_bf16(bk, aq[kk], sacc[n], 0, 0, 0);
            }
        }
        float p[4][4], mn[4];
#pragma unroll
        for (int n = 0; n < 4; ++n) {
            p[n][0] = mk4[n].x ? sacc[n][0] : -1e9f;
            p[n][1] = mk4[n].y ? sacc[n][1] : -1e9f;
            p[n][2] = mk4[n].z ? sacc[n][2] : -1e9f;
            p[n][3] = mk4[n].w ? sacc[n][3] : -1e9f;
            mn[n] = fmaxf(fmaxf(p[n][0], p[n][1]), fmaxf(p[n][2], p[n][3]));
        }
        float mloc = fmaxf(fmaxf(mn[0], mn[1]), fmaxf(mn[2], mn[3]));
        mloc = fmaxf(mloc, __shfl_xor(mloc, 16));
        mloc = fmaxf(mloc, __shfl_xor(mloc, 32));
        const float pm = fmaxf(mrun, mloc);
        if (!__all(pm - mrun <= 11.5f)) {        // defer-max (T13), log2 domain
            const float sc = exp2f(mrun - pm);
            mrun = pm;
            lsum *= sc;
#pragma unroll
            for (int n = 0; n < 4; ++n)
#pragma unroll
                for (int r = 0; r < 4; ++r) oacc[n][r] *= sc;
        }
        float rsn[4];
#pragma unroll
        for (int n = 0; n < 4; ++n) {
#pragma unroll
            for (int r = 0; r < 4; ++r) p[n][r] = exp2f(p[n][r] - mrun);
            rsn[n] = (p[n][0] + p[n][1]) + (p[n][2] + p[n][3]);
        }
        float rs = (rsn[0] + rsn[1]) + (rsn[2] + rsn[3]);
        rs += __shfl_xor(rs, 16);
        rs += __shfl_xor(rs, 32);
        lsum += rs;
        // PV: O += V^T_frag(A) x P_frag(B). V key-axis pre-permuted so the
        // natural in-lane pack of p[][] IS the B-fragment. No cross-lane ops.
#pragma unroll
        for (int kk = 0; kk < 2; ++kk) {
            bf16x8 pfrag;
#pragma unroll
            for (int r = 0; r < 4; ++r) {
                pfrag[r]     = (__bf16)p[2 * kk][r];
                pfrag[4 + r] = (__bf16)p[2 * kk + 1][r];
            }
#pragma unroll
            for (int nd = 0; nd < 4; ++nd) {
                bf16x8 vf = *(const bf16x8*)&Vt[cur][nd * 16 + lm][lg * 8 + kk * 32];
                oacc[nd] = __builtin_amdgcn_mfma_f32_16x16x32_bf16(vf, pfrag, oacc[nd], 0, 0, 0);
            }
        }
        SOFT_BARRIER();   // read(cur) done wave-wide; write(cur^1) visible
    }
#undef ALOAD
#undef AWRITE
    const float rinv = 1.0f / lsum;
#pragma unroll
    for (int nd = 0; nd < 4; ++nd) {
        bf16x4 o;
#pragma unroll
        for (int r = 0; r < 4; ++r) o[r] = (__bf16)(oacc[nd][r] * rinv);
        *(bf16x4*)(ctx + (size_t)(b * 1024 + qrow) * 1024 + h * 64 + nd * 16 + lg * 4) = o;
    }
}

// ---------------------------------------------------------------------------
extern "C" void kernel_launch(void* const* d_in, const int* in_sizes, int n_in,
                              void* d_out, int out_size, void* d_ws, size_t ws_size,
                              hipStream_t stream) {
    const float* x    = (const float*)d_in[0];
    const int*   mask = (const int*)d_in[1];
    const float* wq   = (const float*)d_in[2];
    const float* bq   = (const float*)d_in[3];
    const float* wk   = (const float*)d_in[4];
    const float* bk   = (const float*)d_in[5];
    const float* wv   = (const float*)d_in[6];
    const float* bv   = (const float*)d_in[7];
    const float* wo   = (const float*)d_in[8];
    const float* bo   = (const float*)d_in[9];
    const float* w1   = (const float*)d_in[10];
    const float* b1   = (const float*)d_in[11];
    const float* w2   = (const float*)d_in[12];
    const float* b2   = (const float*)d_in[13];
    const float* ln1g = (const float*)d_in[14];
    const float* ln1b = (const float*)d_in[15];
    const float* ln2g = (const float*)d_in[16];
    const float* ln2b = (const float*)d_in[17];
    float* out = (float*)d_out;
    char* ws = (char*)d_ws;

    __bf16* wqkvT = (__bf16*)(ws + 0);          // [3072][1024]  6 MB
    __bf16* woT   = (__bf16*)(ws + 6291456);    // [1024][1024]  2 MB
    __bf16* w1T   = (__bf16*)(ws + 8388608);    // [4096][1024]  8 MB
    __bf16* w2T   = (__bf16*)(ws + 16777216);   // [1024][4096]  8 MB
    float*  bqkv  = (float*)(ws + 25165824);    // [3072]
    __bf16* hb    = (__bf16*)(ws + 25178112);   // [8192][1024] 16 MB
    __bf16* qkb   = (__bf16*)(ws + 41955328);   // [8192][2048] 32 MB
    __bf16* vTb   = (__bf16*)(ws + 75509760);   // [8*16*64][1024] 16 MB
    __bf16* ctxb  = (__bf16*)(ws + 92286976);   // [8192][1024] 16 MB -> 109064192
    __bf16* ff1b  = qkb;                        // [8192][4096] 64 MB overlays

    // weights transpose + bias concat (single launch)
    transpose_all<<<12292, 256, 0, stream>>>(wq, wk, wv, wo, w1, w2,
                                             wqkvT, woT, w1T, w2T,
                                             bq, bk, bv, bqkv);

    // LN1 -> hb
    ln_to_bf16<<<8192, 256, 0, stream>>>(x, ln1g, ln1b, hb);
    // fused QKV (128x256): Q(prescaled)|K -> qkb, V -> vTb^T (key-permuted)
    gemm_qkv<<<768, 512, 0, stream>>>(hb, wqkvT, bqkv, qkb, vTb, 8192, 3072, 1024, 64);
    // attention (head-major grid for XCD-aligned KV reuse)
    attn_kernel<<<dim3(16, 8, 8), 512, 0, stream>>>(qkb, vTb, mask, ctxb);
    // output proj + residual -> d_out (fp32)
    gemm256x128<<<256, 512, 0, stream>>>(ctxb, woT, bo, x, out, 8192, 1024, 1024, 32);
    // LN2 -> hb
    ln_to_bf16<<<8192, 256, 0, stream>>>(out, ln2g, ln2b, hb);
    // FFN1 (256^2, relu)
    gemm256<1><<<512, 512, 0, stream>>>(hb, w1T, b1, ff1b, 8192, 4096, 1024, 32);
    // FFN2 + residual
    gemm256x128<<<256, 512, 0, stream>>>(ff1b, w2T, b2, out, out, 8192, 1024, 4096, 32);
}